// Round 1
// baseline (949.642 us; speedup 1.0000x reference)
//
#include <hip/hip_runtime.h>
#include <hip/hip_bf16.h>

#define HID 128
#define DIN 192      // N_FEAT + NUM_SEM
#define NCH 65536
#define NE  1048576

typedef __bf16 bfrag __attribute__((ext_vector_type(8)));
typedef float  ffrag __attribute__((ext_vector_type(4)));

static __device__ __forceinline__ __bf16 f2bf(float x) { return (__bf16)x; }
static __device__ __forceinline__ unsigned pk2(float a, float b) {
    __bf16 b0 = f2bf(a), b1 = f2bf(b);
    return (unsigned)*(unsigned short*)&b0 | ((unsigned)*(unsigned short*)&b1 << 16);
}

struct Frags { bfrag a[5]; };

// ---------------------------------------------------------------------------
// Child encoder fused: xA[n][h] = bf16(relu(cf[n]@Wc + bc) * exists[n]),
// col-max into pmax[0..127].
// ---------------------------------------------------------------------------
__global__ __launch_bounds__(256) void k_child(
    const float* __restrict__ cf, const float* __restrict__ exists,
    const float* __restrict__ Wc, const float* __restrict__ bc,
    __bf16* __restrict__ xA, unsigned int* __restrict__ pmax)
{
    __shared__ __bf16 Wl[6 * 8 * 64 * 8];   // 48 KB, B-fragment-swizzled
    __shared__ float  bl[HID];
    __shared__ unsigned int cm[HID];
    const int t = threadIdx.x;

    for (int idx = t; idx < DIN * HID; idx += 256) {
        int k = idx >> 7, h = idx & 127;
        int kt = k >> 5, kk = k & 31;
        int lane = ((kk >> 3) << 4) | (h & 15);
        Wl[((((kt * 8) + (h >> 4)) * 64 + lane) << 3) | (kk & 7)] = f2bf(Wc[idx]);
    }
    for (int idx = t; idx < HID; idx += 256) { bl[idx] = bc[idx]; cm[idx] = 0u; }
    __syncthreads();

    const int wave = t >> 6, lane = t & 63;
    const int m = lane & 15, quad = lane >> 4;

    const int tile = blockIdx.x * 4 + wave;   // grid 1024 -> 4096 tiles
    const int r0 = tile << 4;
    const int row = r0 + m;

    ffrag acc[8];
    #pragma unroll
    for (int u = 0; u < 8; ++u)
        #pragma unroll
        for (int r = 0; r < 4; ++r) acc[u][r] = 0.f;

    const float* arow = cf + (size_t)row * DIN + quad * 8;
    #pragma unroll
    for (int kt = 0; kt < 6; ++kt) {
        float4 f0 = *(const float4*)(arow + kt * 32);
        float4 f1 = *(const float4*)(arow + kt * 32 + 4);
        bfrag a;
        a[0]=f2bf(f0.x); a[1]=f2bf(f0.y); a[2]=f2bf(f0.z); a[3]=f2bf(f0.w);
        a[4]=f2bf(f1.x); a[5]=f2bf(f1.y); a[6]=f2bf(f1.z); a[7]=f2bf(f1.w);
        #pragma unroll
        for (int u = 0; u < 8; ++u) {
            bfrag b = *(const bfrag*)(&Wl[(((kt * 8 + u) * 64 + lane) << 3)]);
            acc[u] = __builtin_amdgcn_mfma_f32_16x16x32_bf16(a, b, acc[u], 0, 0, 0);
        }
    }

    float mxu[8];
    #pragma unroll
    for (int u = 0; u < 8; ++u) mxu[u] = 0.f;

    #pragma unroll
    for (int r = 0; r < 4; ++r) {
        int er = r0 + quad * 4 + r;
        float exv = exists[er];
        __bf16* orow = xA + (size_t)er * HID;
        #pragma unroll
        for (int u = 0; u < 8; ++u) {
            int col = u * 16 + m;
            float v = fmaxf(acc[u][r] + bl[col], 0.f) * exv;
            orow[col] = f2bf(v);
            mxu[u] = fmaxf(mxu[u], v);
        }
    }
    #pragma unroll
    for (int u = 0; u < 8; ++u) {
        float v = mxu[u];
        v = fmaxf(v, __shfl_xor(v, 16));
        v = fmaxf(v, __shfl_xor(v, 32));
        if (quad == 0) atomicMax(&cm[u * 16 + m], __float_as_uint(v));
    }
    __syncthreads();
    if (t < HID) atomicMax(&pmax[t], cm[t]);
}

// ---------------------------------------------------------------------------
// CSR build
// ---------------------------------------------------------------------------
__global__ __launch_bounds__(256) void k_hist(
    const int* __restrict__ eidx, int* __restrict__ deg)
{
    int e = blockIdx.x * 256 + threadIdx.x;
    atomicAdd(&deg[eidx[2 * e]], 1);
}

__global__ __launch_bounds__(1024) void k_scan(
    const int* __restrict__ deg, int* __restrict__ off, int* __restrict__ cursor)
{
    __shared__ int sc[1024];
    const int t = threadIdx.x;
    const int base = t * 64;
    int s = 0;
    for (int i = 0; i < 64; ++i) s += deg[base + i];
    sc[t] = s;
    __syncthreads();
    for (int o = 1; o < 1024; o <<= 1) {
        int v = (t >= o) ? sc[t - o] : 0;
        __syncthreads();
        sc[t] += v;
        __syncthreads();
    }
    int run = sc[t] - s;
    for (int i = 0; i < 64; ++i) {
        int v = deg[base + i];
        off[base + i] = run;
        cursor[base + i] = run;
        run += v;
    }
    if (t == 1023) off[NCH] = run;
}

// Scatter fused with dst/ef gather: coalesced ef read, scattered 16B/4B writes.
__global__ __launch_bounds__(256) void k_scatter(
    const int* __restrict__ eidx, int* __restrict__ cursor,
    const float* __restrict__ ef,
    int* __restrict__ dsts, __bf16* __restrict__ efs)
{
    int e = blockIdx.x * 256 + threadIdx.x;
    int s = eidx[2 * e], d = eidx[2 * e + 1];
    const float4* p = (const float4*)(ef + (size_t)e * 8);
    float4 f0 = p[0], f1 = p[1];
    int pos = atomicAdd(&cursor[s], 1);
    dsts[pos] = d;
    uint4 pk;
    pk.x = pk2(f0.x, f0.y); pk.y = pk2(f0.z, f0.w);
    pk.z = pk2(f1.x, f1.y); pk.w = pk2(f1.z, f1.w);
    *(uint4*)(efs + (size_t)pos * 8) = pk;
}

// ---------------------------------------------------------------------------
// St2[n][m][u] = bf16( (x @ We[0:128])[n][u*16+m] + be[u*16+m] )
// Frag-ordered so k_edge2 reads one 16B chunk per lane per node.
// ---------------------------------------------------------------------------
__global__ __launch_bounds__(256) void k_src(
    const __bf16* __restrict__ xCur, const float* __restrict__ We,
    const float* __restrict__ be, __bf16* __restrict__ St2)
{
    __shared__ __bf16 Wl[4 * 8 * 64 * 8];   // 32 KB
    __shared__ float  bl[HID];
    const int t = threadIdx.x;
    for (int idx = t; idx < 128 * HID; idx += 256) {
        int k = idx >> 7, h = idx & 127;
        int kt = k >> 5, kk = k & 31;
        int lane = ((kk >> 3) << 4) | (h & 15);
        Wl[((((kt * 8) + (h >> 4)) * 64 + lane) << 3) | (kk & 7)] = f2bf(We[idx]);
    }
    for (int idx = t; idx < HID; idx += 256) bl[idx] = be[idx];
    __syncthreads();

    const int wave = t >> 6, lane = t & 63;
    const int m = lane & 15, quad = lane >> 4;
    const int tile = blockIdx.x * 4 + wave;   // grid 1024 -> 4096 tiles
    const int r0 = tile << 4;
    const int row = r0 + m;

    ffrag acc[8];
    #pragma unroll
    for (int u = 0; u < 8; ++u)
        #pragma unroll
        for (int r = 0; r < 4; ++r) acc[u][r] = 0.f;

    const __bf16* ar = xCur + (size_t)row * HID + quad * 8;
    #pragma unroll
    for (int kt = 0; kt < 4; ++kt) {
        bfrag a = *(const bfrag*)(ar + kt * 32);
        #pragma unroll
        for (int u = 0; u < 8; ++u) {
            bfrag b = *(const bfrag*)(&Wl[(((kt * 8 + u) * 64 + lane) << 3)]);
            acc[u] = __builtin_amdgcn_mfma_f32_16x16x32_bf16(a, b, acc[u], 0, 0, 0);
        }
    }
    #pragma unroll
    for (int r = 0; r < 4; ++r) {
        int node = r0 + quad * 4 + r;
        bfrag pk;
        #pragma unroll
        for (int u = 0; u < 8; ++u) pk[u] = f2bf(acc[u][r] + bl[u * 16 + m]);
        *(bfrag*)(St2 + ((size_t)node * 16 + m) * 8) = pk;   // 16B coalesced
    }
}

// ---------------------------------------------------------------------------
// Fused edge pass + segment_sum + col-max.  Wave owns 4 consecutive nodes =
// one contiguous sorted-edge range.  dsts preloaded into 2 regs (shfl-served),
// 1-tile-ahead frag prefetch across node boundaries, acc initialized with
// S[n]+bias.  Zero global atomics on the data path.
//
// R2: ef-block B-fragments (We rows 256..263) cached in 32 VGPRs instead of
// 8 KB of LDS -> LDS 41.5->33.3 KB -> 4 blocks/CU (16 waves, was 12); per-tile
// ds_read_b128 count 40->32.  __launch_bounds__(256,4) pins VGPR<=128 so the
// 4-block occupancy target is enforced.
// ---------------------------------------------------------------------------
__global__ __launch_bounds__(256, 4) void k_edge2(
    const __bf16* __restrict__ xCur,
    const int*    __restrict__ offs,
    const int*    __restrict__ dsts,
    const __bf16* __restrict__ efs,
    const __bf16* __restrict__ St2,
    const float*  __restrict__ We,    // 264x128 slice; rows 128..263 used
    __bf16* __restrict__ xNext,
    unsigned int* __restrict__ pmax, int stage)
{
    __shared__ __bf16 Wl[4 * 8 * 64 * 8];   // 32 KB
    __shared__ unsigned int cm[HID];
    const int t = threadIdx.x;
    const int wave = t >> 6, lane = t & 63;
    const int m = lane & 15, quad = lane >> 4;

    // phase 1: ef rows (We rows 256..263) in B-frag layout, zero-padded, into
    // the start of Wl; read into registers; then Wl is reused for dst weights.
    for (int idx = t; idx < 8 * 64 * 8; idx += 256) {
        int j = idx & 7, ln = (idx >> 3) & 63, u = idx >> 9;
        Wl[idx] = (ln < 16) ? f2bf(We[(size_t)(256 + j) * HID + u * 16 + ln])
                            : (__bf16)0.f;
    }
    if (t < HID) cm[t] = 0u;
    __syncthreads();

    bfrag bef[8];
    #pragma unroll
    for (int u = 0; u < 8; ++u)
        bef[u] = *(const bfrag*)(&Wl[(u * 64 + lane) << 3]);
    __syncthreads();

    // phase 2: dst-weight rows 128..255 in B-frag layout (full 32 KB)
    for (int idx = t; idx < 128 * HID; idx += 256) {
        int k = idx >> 7, h = idx & 127;
        int kt = k >> 5, kk = k & 31;
        int ln = ((kk >> 3) << 4) | (h & 15);
        Wl[((((kt * 8) + (h >> 4)) * 64 + ln) << 3) | (kk & 7)] = f2bf(We[(size_t)(128 + k) * HID + h]);
    }
    __syncthreads();

    const int gw = blockIdx.x * 4 + wave;    // grid 4096 -> 16384 waves
    const int n0 = gw * 4;                   // 4 nodes per wave, consecutive

    const int o0 = offs[n0],     o1 = offs[n0 + 1], o2 = offs[n0 + 2];
    const int o3 = offs[n0 + 3], o4 = offs[n0 + 4];

    auto selo = [&](int q) -> int {
        return (q <= 0) ? o0 : (q == 1) ? o1 : (q == 2) ? o2 : (q == 3) ? o3 : o4;
    };

    float mxu[8];
    #pragma unroll
    for (int u = 0; u < 8; ++u) mxu[u] = 0.f;

    if (o0 < o4) {
        const int dvA = dsts[min(o0 + lane, o4 - 1)];
        const int dvB = dsts[min(o0 + 64 + lane, o4 - 1)];

        auto LOADT = [&](int j) -> Frags {
            Frags f;
            int jl = j + m; jl = (jl < o4) ? jl : (o4 - 1);
            int rel = jl - o0;
            int dA = __shfl(dvA, rel & 63);
            int dB = __shfl(dvB, rel & 63);
            int dm;
            if (rel < 64)       dm = dA;
            else if (rel < 128) dm = dB;
            else                dm = dsts[jl];      // ultra-rare fallback
            const __bf16* rd = xCur + (size_t)dm * HID + quad * 8;
            f.a[0] = *(const bfrag*)(rd);
            f.a[1] = *(const bfrag*)(rd + 32);
            f.a[2] = *(const bfrag*)(rd + 64);
            f.a[3] = *(const bfrag*)(rd + 96);
            bfrag z;
            #pragma unroll
            for (int q = 0; q < 8; ++q) z[q] = (__bf16)0.f;
            if (quad == 0) z = *(const bfrag*)(efs + (size_t)jl * 8);
            f.a[4] = z;
            return f;
        };

        int ci = 0;
        while (selo(ci) == selo(ci + 1)) ++ci;   // first non-empty node (exists)
        int cj = selo(ci);

        bfrag sb = *(const bfrag*)(St2 + ((size_t)(n0 + ci) * 16 + m) * 8);
        float part[8];
        #pragma unroll
        for (int u = 0; u < 8; ++u) part[u] = 0.f;

        Frags aC = LOADT(cj);

        for (;;) {
            const int cEnd = selo(ci + 1);
            int ni = ci, nj = cj + 16;
            if (nj >= cEnd) {
                ni = ci + 1;
                while (ni < 4 && selo(ni) == selo(ni + 1)) ++ni;
                nj = (ni < 4) ? selo(ni) : 0;
            }
            const bool hn = (ni < 4);
            Frags aN;
            if (hn) aN = LOADT(nj);             // prefetch next tile

            ffrag acc[8];
            #pragma unroll
            for (int u = 0; u < 8; ++u) {
                float s = (float)sb[u];
                acc[u][0] = s; acc[u][1] = s; acc[u][2] = s; acc[u][3] = s;
            }
            #pragma unroll
            for (int kt = 0; kt < 4; ++kt)
                #pragma unroll
                for (int u = 0; u < 8; ++u) {
                    bfrag b = *(const bfrag*)(&Wl[(((kt * 8 + u) * 64 + lane) << 3)]);
                    acc[u] = __builtin_amdgcn_mfma_f32_16x16x32_bf16(aC.a[kt], b, acc[u], 0, 0, 0);
                }
            #pragma unroll
            for (int u = 0; u < 8; ++u)
                acc[u] = __builtin_amdgcn_mfma_f32_16x16x32_bf16(aC.a[4], bef[u], acc[u], 0, 0, 0);

            const int rb = cj + quad * 4;
            #pragma unroll
            for (int r = 0; r < 4; ++r) {
                float w = (rb + r < cEnd) ? 1.f : 0.f;
                #pragma unroll
                for (int u = 0; u < 8; ++u)
                    part[u] = fmaf(w, fmaxf(acc[u][r], 0.f), part[u]);
            }

            if (!hn || ni != ci) {
                float tot[8];
                #pragma unroll
                for (int u = 0; u < 8; ++u) {
                    float v = part[u];
                    v += __shfl_xor(v, 16);
                    v += __shfl_xor(v, 32);
                    tot[u] = v;
                    mxu[u] = fmaxf(mxu[u], v);
                }
                // static-index selection of this quad's 2 columns (no scratch)
                float sA = (quad == 0) ? tot[0] : (quad == 1) ? tot[2] : (quad == 2) ? tot[4] : tot[6];
                float sB = (quad == 0) ? tot[1] : (quad == 1) ? tot[3] : (quad == 2) ? tot[5] : tot[7];
                const int n = n0 + ci, u0 = quad * 2;
                xNext[(size_t)n * HID + u0 * 16 + m]      = f2bf(sA);
                xNext[(size_t)n * HID + u0 * 16 + 16 + m] = f2bf(sB);
                if (hn) {
                    sb = *(const bfrag*)(St2 + ((size_t)(n0 + ni) * 16 + m) * 8);
                    #pragma unroll
                    for (int u = 0; u < 8; ++u) part[u] = 0.f;
                }
            }
            if (!hn) break;
            aC = aN; ci = ni; cj = nj;
        }
    }

    // zero rows for empty nodes
    {
        const int u0 = quad * 2;
        const __bf16 zz = (__bf16)0.f;
        if (o0 == o1) { xNext[(size_t)(n0+0)*HID + u0*16 + m] = zz; xNext[(size_t)(n0+0)*HID + u0*16 + 16 + m] = zz; }
        if (o1 == o2) { xNext[(size_t)(n0+1)*HID + u0*16 + m] = zz; xNext[(size_t)(n0+1)*HID + u0*16 + 16 + m] = zz; }
        if (o2 == o3) { xNext[(size_t)(n0+2)*HID + u0*16 + m] = zz; xNext[(size_t)(n0+2)*HID + u0*16 + 16 + m] = zz; }
        if (o3 == o4) { xNext[(size_t)(n0+3)*HID + u0*16 + m] = zz; xNext[(size_t)(n0+3)*HID + u0*16 + 16 + m] = zz; }
    }

    #pragma unroll
    for (int u = 0; u < 8; ++u) {
        float v = mxu[u];
        v = fmaxf(v, __shfl_xor(v, 16));
        v = fmaxf(v, __shfl_xor(v, 32));
        if (quad == 0) atomicMax(&cm[u * 16 + m], __float_as_uint(v));
    }
    __syncthreads();
    if (t < HID) atomicMax(&pmax[stage * HID + t], cm[t]);
}

// ---------------------------------------------------------------------------
// Fallback path kernels (R1-proven, 48 MB footprint)
// ---------------------------------------------------------------------------
__global__ __launch_bounds__(256) void k_edge_at(
    const __bf16* __restrict__ xA, const int* __restrict__ eidx,
    const float* __restrict__ ef, const float* __restrict__ We,
    const float* __restrict__ be, float* __restrict__ xNew)
{
    __shared__ __bf16 Wl[9 * 8 * 64 * 8];
    __shared__ float  bl[HID];
    const int t = threadIdx.x;
    for (int idx = t; idx < 8 * 64 * 8; idx += 256) Wl[8 * 8 * 64 * 8 + idx] = (__bf16)0.f;
    __syncthreads();
    for (int idx = t; idx < 256 * HID; idx += 256) {
        int k = idx >> 7, h = idx & 127;
        int kt = k >> 5, kk = k & 31;
        int lane = ((kk >> 3) << 4) | (h & 15);
        Wl[((((kt * 8) + (h >> 4)) * 64 + lane) << 3) | (kk & 7)] = f2bf(We[idx]);
    }
    for (int idx = t; idx < 8 * HID; idx += 256) {
        int k2 = idx >> 7, h = idx & 127;
        Wl[((((8 * 8) + (h >> 4)) * 64 + (h & 15)) << 3) | k2] = f2bf(We[(256 + k2) * HID + h]);
    }
    for (int idx = t; idx < HID; idx += 256) bl[idx] = be[idx];
    __syncthreads();

    const int wave = t >> 6, lane = t & 63;
    const int m = lane & 15, quad = lane >> 4;
    for (int c = 0; c < 8; ++c) {
        const int e0 = blockIdx.x * 512 + c * 64 + wave * 16;
        const int e  = e0 + m;
        const int src = eidx[2 * e], dst = eidx[2 * e + 1];
        const __bf16* rs = xA + (size_t)src * HID;
        const __bf16* rd = xA + (size_t)dst * HID;
        bfrag a[9];
        #pragma unroll
        for (int kt = 0; kt < 4; ++kt) a[kt] = *(const bfrag*)(rs + kt * 32 + quad * 8);
        #pragma unroll
        for (int kt = 4; kt < 8; ++kt) a[kt] = *(const bfrag*)(rd + (kt - 4) * 32 + quad * 8);
        {
            bfrag z;
            #pragma unroll
            for (int q = 0; q < 8; ++q) z[q] = (__bf16)0.f;
            if (quad == 0) {
                const float4* p = (const float4*)(ef + (size_t)e * 8);
                float4 f0 = p[0], f1 = p[1];
                z[0]=f2bf(f0.x); z[1]=f2bf(f0.y); z[2]=f2bf(f0.z); z[3]=f2bf(f0.w);
                z[4]=f2bf(f1.x); z[5]=f2bf(f1.y); z[6]=f2bf(f1.z); z[7]=f2bf(f1.w);
            }
            a[8] = z;
        }
        ffrag acc[8];
        #pragma unroll
        for (int u = 0; u < 8; ++u)
            #pragma unroll
            for (int r = 0; r < 4; ++r) acc[u][r] = 0.f;
        #pragma unroll
        for (int kt = 0; kt < 9; ++kt)
            #pragma unroll
            for (int u = 0; u < 8; ++u) {
                bfrag b = *(const bfrag*)(&Wl[(((kt * 8 + u) * 64 + lane) << 3)]);
                acc[u] = __builtin_amdgcn_mfma_f32_16x16x32_bf16(a[kt], b, acc[u], 0, 0, 0);
            }
        #pragma unroll
        for (int r = 0; r < 4; ++r) {
            int er = e0 + quad * 4 + r;
            int sr = eidx[2 * er];
            float* outrow = xNew + (size_t)sr * HID;
            #pragma unroll
            for (int u = 0; u < 8; ++u) {
                int col = u * 16 + m;
                atomicAdd(outrow + col, fmaxf(acc[u][r] + bl[col], 0.f));
            }
        }
    }
}

__global__ __launch_bounds__(256) void k_fin(
    float* __restrict__ xNew, __bf16* __restrict__ xA,
    unsigned int* __restrict__ pmax, int stage, int flags)
{
    const int t = threadIdx.x;
    const size_t total  = (size_t)NCH * HID;
    const size_t stride = (size_t)gridDim.x * 256;
    float mx = 0.f;
    for (size_t i = (size_t)blockIdx.x * 256 + t; i < total; i += stride) {
        float v = xNew[i];
        mx = fmaxf(mx, v);
        if (flags & 1) xA[i] = f2bf(v);
        if (flags & 2) xNew[i] = 0.f;
    }
    __shared__ float red[256];
    red[t] = mx;
    __syncthreads();
    if (t < 128) {
        float v = fmaxf(red[t], red[t + 128]);
        atomicMax(&pmax[stage * HID + t], __float_as_uint(v));
    }
}

// ---------------------------------------------------------------------------
// Parent head: out = relu(pmax(384) @ Wp + bp)
// ---------------------------------------------------------------------------
__global__ __launch_bounds__(128) void k_parent(
    const unsigned int* __restrict__ pmaxU,
    const float* __restrict__ Wp, const float* __restrict__ bp,
    float* __restrict__ out)
{
    __shared__ float pl[384];
    const int t = threadIdx.x;
    for (int i = t; i < 384; i += 128) pl[i] = __uint_as_float(pmaxU[i]);
    __syncthreads();
    float acc = bp[t];
    for (int j = 0; j < 384; ++j) acc += pl[j] * Wp[j * HID + t];
    out[t] = fmaxf(acc, 0.f);
}

extern "C" void kernel_launch(void* const* d_in, const int* in_sizes, int n_in,
                              void* d_out, int out_size, void* d_ws, size_t ws_size,
                              hipStream_t stream)
{
    const float* cf   = (const float*)d_in[0];
    const float* ex   = (const float*)d_in[1];
    const float* ef   = (const float*)d_in[2];
    const int*   eidx = (const int*)d_in[3];
    const float* Wc   = (const float*)d_in[4];
    const float* bc   = (const float*)d_in[5];
    const float* We   = (const float*)d_in[6];
    const float* be   = (const float*)d_in[7];
    const float* Wp   = (const float*)d_in[8];
    const float* bp   = (const float*)d_in[9];
    float* out = (float*)d_out;

    char* ws = (char*)d_ws;

    // CSR-fused path layout (~69 MB)
    const size_t OFF_XA   = 0;
    const size_t OFF_XB   = OFF_XA   + (size_t)NCH * HID * 2;   // +16 MB
    const size_t OFF_ST   = OFF_XB   + (size_t)NCH * HID * 2;   // +16 MB
    const size_t OFF_EFS  = OFF_ST   + (size_t)NCH * HID * 2;   // +16 MB
    const size_t OFF_DST  = OFF_EFS  + (size_t)NE * 8 * 2;      // +16 MB
    const size_t OFF_OFFS = OFF_DST  + (size_t)NE * 4;          // +4 MB
    const size_t OFF_DEG  = OFF_OFFS + 262400;
    const size_t OFF_CUR  = OFF_DEG  + 262144;
    const size_t OFF_PMAX = OFF_CUR  + 262144;
    const size_t NEED     = OFF_PMAX + 2048;

    if (ws_size >= NEED) {
        __bf16*       xA   = (__bf16*)(ws + OFF_XA);
        __bf16*       xB   = (__bf16*)(ws + OFF_XB);
        __bf16*       St2  = (__bf16*)(ws + OFF_ST);
        __bf16*       efs  = (__bf16*)(ws + OFF_EFS);
        int*          dsts = (int*)   (ws + OFF_DST);
        int*          offs = (int*)   (ws + OFF_OFFS);
        int*          deg  = (int*)   (ws + OFF_DEG);
        int*          cur  = (int*)   (ws + OFF_CUR);
        unsigned int* pmax = (unsigned int*)(ws + OFF_PMAX);

        hipMemsetAsync(pmax, 0, 384 * sizeof(unsigned int), stream);
        hipMemsetAsync(deg, 0, NCH * sizeof(int), stream);

        k_child  <<<1024, 256, 0, stream>>>(cf, ex, Wc, bc, xA, pmax);
        k_hist   <<<4096, 256, 0, stream>>>(eidx, deg);
        k_scan   <<<1,   1024, 0, stream>>>(deg, offs, cur);
        k_scatter<<<4096, 256, 0, stream>>>(eidx, cur, ef, dsts, efs);

        k_src    <<<1024, 256, 0, stream>>>(xA, We, be, St2);
        k_edge2  <<<4096, 256, 0, stream>>>(xA, offs, dsts, efs, St2, We, xB, pmax, 1);
        k_src    <<<1024, 256, 0, stream>>>(xB, We + 264 * HID, be + HID, St2);
        k_edge2  <<<4096, 256, 0, stream>>>(xB, offs, dsts, efs, St2, We + 264 * HID, xA, pmax, 2);
        k_parent <<<1,    128, 0, stream>>>(pmax, Wp, bp, out);
    } else {
        // fallback: R1 atomic path (48 MB)
        float*        xNew = (float*)ws;
        __bf16*       xA   = (__bf16*)(ws + (size_t)NCH * HID * 4);
        unsigned int* pmax = (unsigned int*)(ws + (size_t)NCH * HID * 6);

        hipMemsetAsync(pmax, 0, 384 * sizeof(unsigned int), stream);
        hipMemsetAsync(xNew, 0, (size_t)NCH * HID * 4, stream);

        k_child  <<<1024, 256, 0, stream>>>(cf, ex, Wc, bc, xA, pmax);
        k_edge_at<<<2048, 256, 0, stream>>>(xA, eidx, ef, We,             be,       xNew);
        k_fin    <<<512,  256, 0, stream>>>(xNew, xA, pmax, 1, 3);
        k_edge_at<<<2048, 256, 0, stream>>>(xA, eidx, ef, We + 264 * HID, be + HID, xNew);
        k_fin    <<<512,  256, 0, stream>>>(xNew, xA, pmax, 2, 0);
        k_parent <<<1,    128, 0, stream>>>(pmax, Wp, bp, out);
    }
}

// Round 2
// 638.016 us; speedup vs baseline: 1.4884x; 1.4884x over previous
//
#include <hip/hip_runtime.h>
#include <hip/hip_bf16.h>

#define HID 128
#define DIN 192      // N_FEAT + NUM_SEM
#define NCH 65536
#define NE  1048576

typedef __bf16 bfrag __attribute__((ext_vector_type(8)));
typedef float  ffrag __attribute__((ext_vector_type(4)));

static __device__ __forceinline__ __bf16 f2bf(float x) { return (__bf16)x; }
static __device__ __forceinline__ unsigned pk2(float a, float b) {
    __bf16 b0 = f2bf(a), b1 = f2bf(b);
    return (unsigned)*(unsigned short*)&b0 | ((unsigned)*(unsigned short*)&b1 << 16);
}

struct Frags { bfrag a[5]; };

// ---------------------------------------------------------------------------
// Child encoder fused: xA[n][h] = bf16(relu(cf[n]@Wc + bc) * exists[n]),
// col-max into pmax[0..127].
// ---------------------------------------------------------------------------
__global__ __launch_bounds__(256) void k_child(
    const float* __restrict__ cf, const float* __restrict__ exists,
    const float* __restrict__ Wc, const float* __restrict__ bc,
    __bf16* __restrict__ xA, unsigned int* __restrict__ pmax)
{
    __shared__ __bf16 Wl[6 * 8 * 64 * 8];   // 48 KB, B-fragment-swizzled
    __shared__ float  bl[HID];
    __shared__ unsigned int cm[HID];
    const int t = threadIdx.x;

    for (int idx = t; idx < DIN * HID; idx += 256) {
        int k = idx >> 7, h = idx & 127;
        int kt = k >> 5, kk = k & 31;
        int lane = ((kk >> 3) << 4) | (h & 15);
        Wl[((((kt * 8) + (h >> 4)) * 64 + lane) << 3) | (kk & 7)] = f2bf(Wc[idx]);
    }
    for (int idx = t; idx < HID; idx += 256) { bl[idx] = bc[idx]; cm[idx] = 0u; }
    __syncthreads();

    const int wave = t >> 6, lane = t & 63;
    const int m = lane & 15, quad = lane >> 4;

    const int tile = blockIdx.x * 4 + wave;   // grid 1024 -> 4096 tiles
    const int r0 = tile << 4;
    const int row = r0 + m;

    ffrag acc[8];
    #pragma unroll
    for (int u = 0; u < 8; ++u)
        #pragma unroll
        for (int r = 0; r < 4; ++r) acc[u][r] = 0.f;

    const float* arow = cf + (size_t)row * DIN + quad * 8;
    #pragma unroll
    for (int kt = 0; kt < 6; ++kt) {
        float4 f0 = *(const float4*)(arow + kt * 32);
        float4 f1 = *(const float4*)(arow + kt * 32 + 4);
        bfrag a;
        a[0]=f2bf(f0.x); a[1]=f2bf(f0.y); a[2]=f2bf(f0.z); a[3]=f2bf(f0.w);
        a[4]=f2bf(f1.x); a[5]=f2bf(f1.y); a[6]=f2bf(f1.z); a[7]=f2bf(f1.w);
        #pragma unroll
        for (int u = 0; u < 8; ++u) {
            bfrag b = *(const bfrag*)(&Wl[(((kt * 8 + u) * 64 + lane) << 3)]);
            acc[u] = __builtin_amdgcn_mfma_f32_16x16x32_bf16(a, b, acc[u], 0, 0, 0);
        }
    }

    float mxu[8];
    #pragma unroll
    for (int u = 0; u < 8; ++u) mxu[u] = 0.f;

    #pragma unroll
    for (int r = 0; r < 4; ++r) {
        int er = r0 + quad * 4 + r;
        float exv = exists[er];
        __bf16* orow = xA + (size_t)er * HID;
        #pragma unroll
        for (int u = 0; u < 8; ++u) {
            int col = u * 16 + m;
            float v = fmaxf(acc[u][r] + bl[col], 0.f) * exv;
            orow[col] = f2bf(v);
            mxu[u] = fmaxf(mxu[u], v);
        }
    }
    #pragma unroll
    for (int u = 0; u < 8; ++u) {
        float v = mxu[u];
        v = fmaxf(v, __shfl_xor(v, 16));
        v = fmaxf(v, __shfl_xor(v, 32));
        if (quad == 0) atomicMax(&cm[u * 16 + m], __float_as_uint(v));
    }
    __syncthreads();
    if (t < HID) atomicMax(&pmax[t], cm[t]);
}

// ---------------------------------------------------------------------------
// CSR build
// ---------------------------------------------------------------------------
__global__ __launch_bounds__(256) void k_hist(
    const int* __restrict__ eidx, int* __restrict__ deg)
{
    int e = blockIdx.x * 256 + threadIdx.x;
    atomicAdd(&deg[eidx[2 * e]], 1);
}

__global__ __launch_bounds__(1024) void k_scan(
    const int* __restrict__ deg, int* __restrict__ off, int* __restrict__ cursor)
{
    __shared__ int sc[1024];
    const int t = threadIdx.x;
    const int base = t * 64;
    int s = 0;
    for (int i = 0; i < 64; ++i) s += deg[base + i];
    sc[t] = s;
    __syncthreads();
    for (int o = 1; o < 1024; o <<= 1) {
        int v = (t >= o) ? sc[t - o] : 0;
        __syncthreads();
        sc[t] += v;
        __syncthreads();
    }
    int run = sc[t] - s;
    for (int i = 0; i < 64; ++i) {
        int v = deg[base + i];
        off[base + i] = run;
        cursor[base + i] = run;
        run += v;
    }
    if (t == 1023) off[NCH] = run;
}

// Scatter fused with dst/ef gather: coalesced ef read, scattered 16B/4B writes.
__global__ __launch_bounds__(256) void k_scatter(
    const int* __restrict__ eidx, int* __restrict__ cursor,
    const float* __restrict__ ef,
    int* __restrict__ dsts, __bf16* __restrict__ efs)
{
    int e = blockIdx.x * 256 + threadIdx.x;
    int s = eidx[2 * e], d = eidx[2 * e + 1];
    const float4* p = (const float4*)(ef + (size_t)e * 8);
    float4 f0 = p[0], f1 = p[1];
    int pos = atomicAdd(&cursor[s], 1);
    dsts[pos] = d;
    uint4 pk;
    pk.x = pk2(f0.x, f0.y); pk.y = pk2(f0.z, f0.w);
    pk.z = pk2(f1.x, f1.y); pk.w = pk2(f1.z, f1.w);
    *(uint4*)(efs + (size_t)pos * 8) = pk;
}

// ---------------------------------------------------------------------------
// St2[n][m][u] = bf16( (x @ We[0:128])[n][u*16+m] + be[u*16+m] )
// Frag-ordered so k_edge2 reads one 16B chunk per lane per node.
// ---------------------------------------------------------------------------
__global__ __launch_bounds__(256) void k_src(
    const __bf16* __restrict__ xCur, const float* __restrict__ We,
    const float* __restrict__ be, __bf16* __restrict__ St2)
{
    __shared__ __bf16 Wl[4 * 8 * 64 * 8];   // 32 KB
    __shared__ float  bl[HID];
    const int t = threadIdx.x;
    for (int idx = t; idx < 128 * HID; idx += 256) {
        int k = idx >> 7, h = idx & 127;
        int kt = k >> 5, kk = k & 31;
        int lane = ((kk >> 3) << 4) | (h & 15);
        Wl[((((kt * 8) + (h >> 4)) * 64 + lane) << 3) | (kk & 7)] = f2bf(We[idx]);
    }
    for (int idx = t; idx < HID; idx += 256) bl[idx] = be[idx];
    __syncthreads();

    const int wave = t >> 6, lane = t & 63;
    const int m = lane & 15, quad = lane >> 4;
    const int tile = blockIdx.x * 4 + wave;   // grid 1024 -> 4096 tiles
    const int r0 = tile << 4;
    const int row = r0 + m;

    ffrag acc[8];
    #pragma unroll
    for (int u = 0; u < 8; ++u)
        #pragma unroll
        for (int r = 0; r < 4; ++r) acc[u][r] = 0.f;

    const __bf16* ar = xCur + (size_t)row * HID + quad * 8;
    #pragma unroll
    for (int kt = 0; kt < 4; ++kt) {
        bfrag a = *(const bfrag*)(ar + kt * 32);
        #pragma unroll
        for (int u = 0; u < 8; ++u) {
            bfrag b = *(const bfrag*)(&Wl[(((kt * 8 + u) * 64 + lane) << 3)]);
            acc[u] = __builtin_amdgcn_mfma_f32_16x16x32_bf16(a, b, acc[u], 0, 0, 0);
        }
    }
    #pragma unroll
    for (int r = 0; r < 4; ++r) {
        int node = r0 + quad * 4 + r;
        bfrag pk;
        #pragma unroll
        for (int u = 0; u < 8; ++u) pk[u] = f2bf(acc[u][r] + bl[u * 16 + m]);
        *(bfrag*)(St2 + ((size_t)node * 16 + m) * 8) = pk;   // 16B coalesced
    }
}

// ---------------------------------------------------------------------------
// Fused edge pass + segment_sum + col-max.  Wave owns 4 consecutive nodes =
// one contiguous sorted-edge range.  dsts preloaded into 2 regs (shfl-served),
// 1-tile-ahead frag prefetch across node boundaries, acc initialized with
// S[n]+bias.  Zero global atomics on the data path.
//
// R3: ef weight block stored COMPACT (8 u x 16 lanes x 8 = 2 KB) instead of
// zero-padded to 64 lanes (8 KB).  All 64 lanes read at (lane & 15): lanes
// 16..63 get duplicate finite weights that multiply the zero A-elements of
// quads 1..3, contributing 0.  LDS 41472 -> 35328 B => 4 blocks/CU (16
// waves/CU, was 12).  No VGPR change, no launch_bounds min-wave pin (the
// R2 pin forced 64 VGPRs and massive scratch spill: FETCH 127->658 MB).
// ---------------------------------------------------------------------------
#define EFW_OFF (4 * 8 * 64 * 8)   // element offset of compact ef block

__global__ __launch_bounds__(256) void k_edge2(
    const __bf16* __restrict__ xCur,
    const int*    __restrict__ offs,
    const int*    __restrict__ dsts,
    const __bf16* __restrict__ efs,
    const __bf16* __restrict__ St2,
    const float*  __restrict__ We,    // 264x128 slice; rows 128..263 used
    __bf16* __restrict__ xNext,
    unsigned int* __restrict__ pmax, int stage)
{
    __shared__ __bf16 Wl[4 * 8 * 64 * 8 + 8 * 16 * 8];   // 32 KB + 2 KB
    __shared__ unsigned int cm[HID];
    const int t = threadIdx.x;

    if (t < HID) cm[t] = 0u;
    // dst-weight rows 128..255 in B-frag layout (32 KB)
    for (int idx = t; idx < 128 * HID; idx += 256) {
        int k = idx >> 7, h = idx & 127;
        int kt = k >> 5, kk = k & 31;
        int lane = ((kk >> 3) << 4) | (h & 15);
        Wl[((((kt * 8) + (h >> 4)) * 64 + lane) << 3) | (kk & 7)] = f2bf(We[(size_t)(128 + k) * HID + h]);
    }
    // ef rows 256..263, compact: [u][ln<16][j]  (2 KB)
    for (int idx = t; idx < 8 * HID; idx += 256) {
        int k2 = idx >> 7, h = idx & 127;
        Wl[EFW_OFF + ((((h >> 4) * 16) + (h & 15)) << 3) + k2] = f2bf(We[(size_t)(256 + k2) * HID + h]);
    }
    __syncthreads();

    const int wave = t >> 6, lane = t & 63;
    const int m = lane & 15, quad = lane >> 4;
    const int gw = blockIdx.x * 4 + wave;    // grid 4096 -> 16384 waves
    const int n0 = gw * 4;                   // 4 nodes per wave, consecutive
    const int lc16 = (lane & 15) << 3;       // compact ef read offset

    const int o0 = offs[n0],     o1 = offs[n0 + 1], o2 = offs[n0 + 2];
    const int o3 = offs[n0 + 3], o4 = offs[n0 + 4];

    auto selo = [&](int q) -> int {
        return (q <= 0) ? o0 : (q == 1) ? o1 : (q == 2) ? o2 : (q == 3) ? o3 : o4;
    };

    float mxu[8];
    #pragma unroll
    for (int u = 0; u < 8; ++u) mxu[u] = 0.f;

    if (o0 < o4) {
        const int dvA = dsts[min(o0 + lane, o4 - 1)];
        const int dvB = dsts[min(o0 + 64 + lane, o4 - 1)];

        auto LOADT = [&](int j) -> Frags {
            Frags f;
            int jl = j + m; jl = (jl < o4) ? jl : (o4 - 1);
            int rel = jl - o0;
            int dA = __shfl(dvA, rel & 63);
            int dB = __shfl(dvB, rel & 63);
            int dm;
            if (rel < 64)       dm = dA;
            else if (rel < 128) dm = dB;
            else                dm = dsts[jl];      // ultra-rare fallback
            const __bf16* rd = xCur + (size_t)dm * HID + quad * 8;
            f.a[0] = *(const bfrag*)(rd);
            f.a[1] = *(const bfrag*)(rd + 32);
            f.a[2] = *(const bfrag*)(rd + 64);
            f.a[3] = *(const bfrag*)(rd + 96);
            bfrag z;
            #pragma unroll
            for (int q = 0; q < 8; ++q) z[q] = (__bf16)0.f;
            if (quad == 0) z = *(const bfrag*)(efs + (size_t)jl * 8);
            f.a[4] = z;
            return f;
        };

        int ci = 0;
        while (selo(ci) == selo(ci + 1)) ++ci;   // first non-empty node (exists)
        int cj = selo(ci);

        bfrag sb = *(const bfrag*)(St2 + ((size_t)(n0 + ci) * 16 + m) * 8);
        float part[8];
        #pragma unroll
        for (int u = 0; u < 8; ++u) part[u] = 0.f;

        Frags aC = LOADT(cj);

        for (;;) {
            const int cEnd = selo(ci + 1);
            int ni = ci, nj = cj + 16;
            if (nj >= cEnd) {
                ni = ci + 1;
                while (ni < 4 && selo(ni) == selo(ni + 1)) ++ni;
                nj = (ni < 4) ? selo(ni) : 0;
            }
            const bool hn = (ni < 4);
            Frags aN;
            if (hn) aN = LOADT(nj);             // prefetch next tile

            ffrag acc[8];
            #pragma unroll
            for (int u = 0; u < 8; ++u) {
                float s = (float)sb[u];
                acc[u][0] = s; acc[u][1] = s; acc[u][2] = s; acc[u][3] = s;
            }
            #pragma unroll
            for (int kt = 0; kt < 4; ++kt)
                #pragma unroll
                for (int u = 0; u < 8; ++u) {
                    bfrag b = *(const bfrag*)(&Wl[(((kt * 8 + u) * 64 + lane) << 3)]);
                    acc[u] = __builtin_amdgcn_mfma_f32_16x16x32_bf16(aC.a[kt], b, acc[u], 0, 0, 0);
                }
            #pragma unroll
            for (int u = 0; u < 8; ++u) {
                bfrag b = *(const bfrag*)(&Wl[EFW_OFF + (u << 7) + lc16]);
                acc[u] = __builtin_amdgcn_mfma_f32_16x16x32_bf16(aC.a[4], b, acc[u], 0, 0, 0);
            }

            const int rb = cj + quad * 4;
            #pragma unroll
            for (int r = 0; r < 4; ++r) {
                if (rb + r < cEnd) {
                    #pragma unroll
                    for (int u = 0; u < 8; ++u)
                        part[u] += fmaxf(acc[u][r], 0.f);
                }
            }

            if (!hn || ni != ci) {
                float tot[8];
                #pragma unroll
                for (int u = 0; u < 8; ++u) {
                    float v = part[u];
                    v += __shfl_xor(v, 16);
                    v += __shfl_xor(v, 32);
                    tot[u] = v;
                    mxu[u] = fmaxf(mxu[u], v);
                }
                // static-index selection of this quad's 2 columns (no scratch)
                float sA = (quad == 0) ? tot[0] : (quad == 1) ? tot[2] : (quad == 2) ? tot[4] : tot[6];
                float sB = (quad == 0) ? tot[1] : (quad == 1) ? tot[3] : (quad == 2) ? tot[5] : tot[7];
                const int n = n0 + ci, u0 = quad * 2;
                xNext[(size_t)n * HID + u0 * 16 + m]      = f2bf(sA);
                xNext[(size_t)n * HID + u0 * 16 + 16 + m] = f2bf(sB);
                if (hn) {
                    sb = *(const bfrag*)(St2 + ((size_t)(n0 + ni) * 16 + m) * 8);
                    #pragma unroll
                    for (int u = 0; u < 8; ++u) part[u] = 0.f;
                }
            }
            if (!hn) break;
            aC = aN; ci = ni; cj = nj;
        }
    }

    // zero rows for empty nodes
    {
        const int u0 = quad * 2;
        const __bf16 zz = (__bf16)0.f;
        if (o0 == o1) { xNext[(size_t)(n0+0)*HID + u0*16 + m] = zz; xNext[(size_t)(n0+0)*HID + u0*16 + 16 + m] = zz; }
        if (o1 == o2) { xNext[(size_t)(n0+1)*HID + u0*16 + m] = zz; xNext[(size_t)(n0+1)*HID + u0*16 + 16 + m] = zz; }
        if (o2 == o3) { xNext[(size_t)(n0+2)*HID + u0*16 + m] = zz; xNext[(size_t)(n0+2)*HID + u0*16 + 16 + m] = zz; }
        if (o3 == o4) { xNext[(size_t)(n0+3)*HID + u0*16 + m] = zz; xNext[(size_t)(n0+3)*HID + u0*16 + 16 + m] = zz; }
    }

    #pragma unroll
    for (int u = 0; u < 8; ++u) {
        float v = mxu[u];
        v = fmaxf(v, __shfl_xor(v, 16));
        v = fmaxf(v, __shfl_xor(v, 32));
        if (quad == 0) atomicMax(&cm[u * 16 + m], __float_as_uint(v));
    }
    __syncthreads();
    if (t < HID) atomicMax(&pmax[stage * HID + t], cm[t]);
}

// ---------------------------------------------------------------------------
// Fallback path kernels (R1-proven, 48 MB footprint)
// ---------------------------------------------------------------------------
__global__ __launch_bounds__(256) void k_edge_at(
    const __bf16* __restrict__ xA, const int* __restrict__ eidx,
    const float* __restrict__ ef, const float* __restrict__ We,
    const float* __restrict__ be, float* __restrict__ xNew)
{
    __shared__ __bf16 Wl[9 * 8 * 64 * 8];
    __shared__ float  bl[HID];
    const int t = threadIdx.x;
    for (int idx = t; idx < 8 * 64 * 8; idx += 256) Wl[8 * 8 * 64 * 8 + idx] = (__bf16)0.f;
    __syncthreads();
    for (int idx = t; idx < 256 * HID; idx += 256) {
        int k = idx >> 7, h = idx & 127;
        int kt = k >> 5, kk = k & 31;
        int lane = ((kk >> 3) << 4) | (h & 15);
        Wl[((((kt * 8) + (h >> 4)) * 64 + lane) << 3) | (kk & 7)] = f2bf(We[idx]);
    }
    for (int idx = t; idx < 8 * HID; idx += 256) {
        int k2 = idx >> 7, h = idx & 127;
        Wl[((((8 * 8) + (h >> 4)) * 64 + (h & 15)) << 3) | k2] = f2bf(We[(256 + k2) * HID + h]);
    }
    for (int idx = t; idx < HID; idx += 256) bl[idx] = be[idx];
    __syncthreads();

    const int wave = t >> 6, lane = t & 63;
    const int m = lane & 15, quad = lane >> 4;
    for (int c = 0; c < 8; ++c) {
        const int e0 = blockIdx.x * 512 + c * 64 + wave * 16;
        const int e  = e0 + m;
        const int src = eidx[2 * e], dst = eidx[2 * e + 1];
        const __bf16* rs = xA + (size_t)src * HID;
        const __bf16* rd = xA + (size_t)dst * HID;
        bfrag a[9];
        #pragma unroll
        for (int kt = 0; kt < 4; ++kt) a[kt] = *(const bfrag*)(rs + kt * 32 + quad * 8);
        #pragma unroll
        for (int kt = 4; kt < 8; ++kt) a[kt] = *(const bfrag*)(rd + (kt - 4) * 32 + quad * 8);
        {
            bfrag z;
            #pragma unroll
            for (int q = 0; q < 8; ++q) z[q] = (__bf16)0.f;
            if (quad == 0) {
                const float4* p = (const float4*)(ef + (size_t)e * 8);
                float4 f0 = p[0], f1 = p[1];
                z[0]=f2bf(f0.x); z[1]=f2bf(f0.y); z[2]=f2bf(f0.z); z[3]=f2bf(f0.w);
                z[4]=f2bf(f1.x); z[5]=f2bf(f1.y); z[6]=f2bf(f1.z); z[7]=f2bf(f1.w);
            }
            a[8] = z;
        }
        ffrag acc[8];
        #pragma unroll
        for (int u = 0; u < 8; ++u)
            #pragma unroll
            for (int r = 0; r < 4; ++r) acc[u][r] = 0.f;
        #pragma unroll
        for (int kt = 0; kt < 9; ++kt)
            #pragma unroll
            for (int u = 0; u < 8; ++u) {
                bfrag b = *(const bfrag*)(&Wl[(((kt * 8 + u) * 64 + lane) << 3)]);
                acc[u] = __builtin_amdgcn_mfma_f32_16x16x32_bf16(a[kt], b, acc[u], 0, 0, 0);
            }
        #pragma unroll
        for (int r = 0; r < 4; ++r) {
            int er = e0 + quad * 4 + r;
            int sr = eidx[2 * er];
            float* outrow = xNew + (size_t)sr * HID;
            #pragma unroll
            for (int u = 0; u < 8; ++u) {
                int col = u * 16 + m;
                atomicAdd(outrow + col, fmaxf(acc[u][r] + bl[col], 0.f));
            }
        }
    }
}

__global__ __launch_bounds__(256) void k_fin(
    float* __restrict__ xNew, __bf16* __restrict__ xA,
    unsigned int* __restrict__ pmax, int stage, int flags)
{
    const int t = threadIdx.x;
    const size_t total  = (size_t)NCH * HID;
    const size_t stride = (size_t)gridDim.x * 256;
    float mx = 0.f;
    for (size_t i = (size_t)blockIdx.x * 256 + t; i < total; i += stride) {
        float v = xNew[i];
        mx = fmaxf(mx, v);
        if (flags & 1) xA[i] = f2bf(v);
        if (flags & 2) xNew[i] = 0.f;
    }
    __shared__ float red[256];
    red[t] = mx;
    __syncthreads();
    if (t < 128) {
        float v = fmaxf(red[t], red[t + 128]);
        atomicMax(&pmax[stage * HID + t], __float_as_uint(v));
    }
}

// ---------------------------------------------------------------------------
// Parent head: out = relu(pmax(384) @ Wp + bp)
// ---------------------------------------------------------------------------
__global__ __launch_bounds__(128) void k_parent(
    const unsigned int* __restrict__ pmaxU,
    const float* __restrict__ Wp, const float* __restrict__ bp,
    float* __restrict__ out)
{
    __shared__ float pl[384];
    const int t = threadIdx.x;
    for (int i = t; i < 384; i += 128) pl[i] = __uint_as_float(pmaxU[i]);
    __syncthreads();
    float acc = bp[t];
    for (int j = 0; j < 384; ++j) acc += pl[j] * Wp[j * HID + t];
    out[t] = fmaxf(acc, 0.f);
}

extern "C" void kernel_launch(void* const* d_in, const int* in_sizes, int n_in,
                              void* d_out, int out_size, void* d_ws, size_t ws_size,
                              hipStream_t stream)
{
    const float* cf   = (const float*)d_in[0];
    const float* ex   = (const float*)d_in[1];
    const float* ef   = (const float*)d_in[2];
    const int*   eidx = (const int*)d_in[3];
    const float* Wc   = (const float*)d_in[4];
    const float* bc   = (const float*)d_in[5];
    const float* We   = (const float*)d_in[6];
    const float* be   = (const float*)d_in[7];
    const float* Wp   = (const float*)d_in[8];
    const float* bp   = (const float*)d_in[9];
    float* out = (float*)d_out;

    char* ws = (char*)d_ws;

    // CSR-fused path layout (~69 MB)
    const size_t OFF_XA   = 0;
    const size_t OFF_XB   = OFF_XA   + (size_t)NCH * HID * 2;   // +16 MB
    const size_t OFF_ST   = OFF_XB   + (size_t)NCH * HID * 2;   // +16 MB
    const size_t OFF_EFS  = OFF_ST   + (size_t)NCH * HID * 2;   // +16 MB
    const size_t OFF_DST  = OFF_EFS  + (size_t)NE * 8 * 2;      // +16 MB
    const size_t OFF_OFFS = OFF_DST  + (size_t)NE * 4;          // +4 MB
    const size_t OFF_DEG  = OFF_OFFS + 262400;
    const size_t OFF_CUR  = OFF_DEG  + 262144;
    const size_t OFF_PMAX = OFF_CUR  + 262144;
    const size_t NEED     = OFF_PMAX + 2048;

    if (ws_size >= NEED) {
        __bf16*       xA   = (__bf16*)(ws + OFF_XA);
        __bf16*       xB   = (__bf16*)(ws + OFF_XB);
        __bf16*       St2  = (__bf16*)(ws + OFF_ST);
        __bf16*       efs  = (__bf16*)(ws + OFF_EFS);
        int*          dsts = (int*)   (ws + OFF_DST);
        int*          offs = (int*)   (ws + OFF_OFFS);
        int*          deg  = (int*)   (ws + OFF_DEG);
        int*          cur  = (int*)   (ws + OFF_CUR);
        unsigned int* pmax = (unsigned int*)(ws + OFF_PMAX);

        hipMemsetAsync(pmax, 0, 384 * sizeof(unsigned int), stream);
        hipMemsetAsync(deg, 0, NCH * sizeof(int), stream);

        k_child  <<<1024, 256, 0, stream>>>(cf, ex, Wc, bc, xA, pmax);
        k_hist   <<<4096, 256, 0, stream>>>(eidx, deg);
        k_scan   <<<1,   1024, 0, stream>>>(deg, offs, cur);
        k_scatter<<<4096, 256, 0, stream>>>(eidx, cur, ef, dsts, efs);

        k_src    <<<1024, 256, 0, stream>>>(xA, We, be, St2);
        k_edge2  <<<4096, 256, 0, stream>>>(xA, offs, dsts, efs, St2, We, xB, pmax, 1);
        k_src    <<<1024, 256, 0, stream>>>(xB, We + 264 * HID, be + HID, St2);
        k_edge2  <<<4096, 256, 0, stream>>>(xB, offs, dsts, efs, St2, We + 264 * HID, xA, pmax, 2);
        k_parent <<<1,    128, 0, stream>>>(pmax, Wp, bp, out);
    } else {
        // fallback: R1 atomic path (48 MB)
        float*        xNew = (float*)ws;
        __bf16*       xA   = (__bf16*)(ws + (size_t)NCH * HID * 4);
        unsigned int* pmax = (unsigned int*)(ws + (size_t)NCH * HID * 6);

        hipMemsetAsync(pmax, 0, 384 * sizeof(unsigned int), stream);
        hipMemsetAsync(xNew, 0, (size_t)NCH * HID * 4, stream);

        k_child  <<<1024, 256, 0, stream>>>(cf, ex, Wc, bc, xA, pmax);
        k_edge_at<<<2048, 256, 0, stream>>>(xA, eidx, ef, We,             be,       xNew);
        k_fin    <<<512,  256, 0, stream>>>(xNew, xA, pmax, 1, 3);
        k_edge_at<<<2048, 256, 0, stream>>>(xA, eidx, ef, We + 264 * HID, be + HID, xNew);
        k_fin    <<<512,  256, 0, stream>>>(xNew, xA, pmax, 2, 0);
        k_parent <<<1,    128, 0, stream>>>(pmax, Wp, bp, out);
    }
}

// Round 3
// 611.447 us; speedup vs baseline: 1.5531x; 1.0435x over previous
//
#include <hip/hip_runtime.h>
#include <hip/hip_bf16.h>

#define HID 128
#define DIN 192      // N_FEAT + NUM_SEM
#define NCH 65536
#define NE  1048576

typedef __bf16 bfrag __attribute__((ext_vector_type(8)));
typedef float  ffrag __attribute__((ext_vector_type(4)));

static __device__ __forceinline__ __bf16 f2bf(float x) { return (__bf16)x; }
static __device__ __forceinline__ unsigned pk2(float a, float b) {
    __bf16 b0 = f2bf(a), b1 = f2bf(b);
    return (unsigned)*(unsigned short*)&b0 | ((unsigned)*(unsigned short*)&b1 << 16);
}

struct Frags { bfrag a[5]; };

// ---------------------------------------------------------------------------
// Child encoder fused: xA[n][h] = bf16(relu(cf[n]@Wc + bc) * exists[n]),
// col-max into pmax[0..127].
// ---------------------------------------------------------------------------
__global__ __launch_bounds__(256) void k_child(
    const float* __restrict__ cf, const float* __restrict__ exists,
    const float* __restrict__ Wc, const float* __restrict__ bc,
    __bf16* __restrict__ xA, unsigned int* __restrict__ pmax)
{
    __shared__ __bf16 Wl[6 * 8 * 64 * 8];   // 48 KB, B-fragment-swizzled
    __shared__ float  bl[HID];
    __shared__ unsigned int cm[HID];
    const int t = threadIdx.x;

    for (int idx = t; idx < DIN * HID; idx += 256) {
        int k = idx >> 7, h = idx & 127;
        int kt = k >> 5, kk = k & 31;
        int lane = ((kk >> 3) << 4) | (h & 15);
        Wl[((((kt * 8) + (h >> 4)) * 64 + lane) << 3) | (kk & 7)] = f2bf(Wc[idx]);
    }
    for (int idx = t; idx < HID; idx += 256) { bl[idx] = bc[idx]; cm[idx] = 0u; }
    __syncthreads();

    const int wave = t >> 6, lane = t & 63;
    const int m = lane & 15, quad = lane >> 4;

    const int tile = blockIdx.x * 4 + wave;   // grid 1024 -> 4096 tiles
    const int r0 = tile << 4;
    const int row = r0 + m;

    ffrag acc[8];
    #pragma unroll
    for (int u = 0; u < 8; ++u)
        #pragma unroll
        for (int r = 0; r < 4; ++r) acc[u][r] = 0.f;

    const float* arow = cf + (size_t)row * DIN + quad * 8;
    #pragma unroll
    for (int kt = 0; kt < 6; ++kt) {
        float4 f0 = *(const float4*)(arow + kt * 32);
        float4 f1 = *(const float4*)(arow + kt * 32 + 4);
        bfrag a;
        a[0]=f2bf(f0.x); a[1]=f2bf(f0.y); a[2]=f2bf(f0.z); a[3]=f2bf(f0.w);
        a[4]=f2bf(f1.x); a[5]=f2bf(f1.y); a[6]=f2bf(f1.z); a[7]=f2bf(f1.w);
        #pragma unroll
        for (int u = 0; u < 8; ++u) {
            bfrag b = *(const bfrag*)(&Wl[(((kt * 8 + u) * 64 + lane) << 3)]);
            acc[u] = __builtin_amdgcn_mfma_f32_16x16x32_bf16(a, b, acc[u], 0, 0, 0);
        }
    }

    float mxu[8];
    #pragma unroll
    for (int u = 0; u < 8; ++u) mxu[u] = 0.f;

    #pragma unroll
    for (int r = 0; r < 4; ++r) {
        int er = r0 + quad * 4 + r;
        float exv = exists[er];
        __bf16* orow = xA + (size_t)er * HID;
        #pragma unroll
        for (int u = 0; u < 8; ++u) {
            int col = u * 16 + m;
            float v = fmaxf(acc[u][r] + bl[col], 0.f) * exv;
            orow[col] = f2bf(v);
            mxu[u] = fmaxf(mxu[u], v);
        }
    }
    #pragma unroll
    for (int u = 0; u < 8; ++u) {
        float v = mxu[u];
        v = fmaxf(v, __shfl_xor(v, 16));
        v = fmaxf(v, __shfl_xor(v, 32));
        if (quad == 0) atomicMax(&cm[u * 16 + m], __float_as_uint(v));
    }
    __syncthreads();
    if (t < HID) atomicMax(&pmax[t], cm[t]);
}

// ---------------------------------------------------------------------------
// CSR build
// ---------------------------------------------------------------------------
__global__ __launch_bounds__(256) void k_hist(
    const int* __restrict__ eidx, int* __restrict__ deg)
{
    int e = blockIdx.x * 256 + threadIdx.x;
    atomicAdd(&deg[eidx[2 * e]], 1);
}

__global__ __launch_bounds__(1024) void k_scan(
    const int* __restrict__ deg, int* __restrict__ off, int* __restrict__ cursor)
{
    __shared__ int sc[1024];
    const int t = threadIdx.x;
    const int base = t * 64;
    int s = 0;
    for (int i = 0; i < 64; ++i) s += deg[base + i];
    sc[t] = s;
    __syncthreads();
    for (int o = 1; o < 1024; o <<= 1) {
        int v = (t >= o) ? sc[t - o] : 0;
        __syncthreads();
        sc[t] += v;
        __syncthreads();
    }
    int run = sc[t] - s;
    for (int i = 0; i < 64; ++i) {
        int v = deg[base + i];
        off[base + i] = run;
        cursor[base + i] = run;
        run += v;
    }
    if (t == 1023) off[NCH] = run;
}

// Scatter fused with dst/ef gather: coalesced ef read, scattered 16B/4B writes.
__global__ __launch_bounds__(256) void k_scatter(
    const int* __restrict__ eidx, int* __restrict__ cursor,
    const float* __restrict__ ef,
    int* __restrict__ dsts, __bf16* __restrict__ efs)
{
    int e = blockIdx.x * 256 + threadIdx.x;
    int s = eidx[2 * e], d = eidx[2 * e + 1];
    const float4* p = (const float4*)(ef + (size_t)e * 8);
    float4 f0 = p[0], f1 = p[1];
    int pos = atomicAdd(&cursor[s], 1);
    dsts[pos] = d;
    uint4 pk;
    pk.x = pk2(f0.x, f0.y); pk.y = pk2(f0.z, f0.w);
    pk.z = pk2(f1.x, f1.y); pk.w = pk2(f1.z, f1.w);
    *(uint4*)(efs + (size_t)pos * 8) = pk;
}

// ---------------------------------------------------------------------------
// R4: k_src computes BOTH per-node projections from x:
//   St2[n]  = bf16( x[n] @ We[0:128]   + be )   (frag-ordered, as before)
//   D[n]    = bf16( x[n] @ We[128:256] )        (row-major, IN-PLACE over x!)
// k_edge2 then needs no weight matmul at all: the gathered D row is moved
// into MFMA C-layout via an identity-B MFMA (8 per tile, constant B in regs).
// In-place is safe: each wave's read row set == its write row set, and all
// reads complete (dataflow through acc) before its stores.
// ---------------------------------------------------------------------------
__global__ __launch_bounds__(256) void k_src(
    __bf16* __restrict__ xCur, const float* __restrict__ We,
    const float* __restrict__ be, __bf16* __restrict__ St2)
{
    __shared__ __bf16 Wl[4 * 8 * 64 * 8];   // 32 KB, reused for src then dst
    __shared__ float  bl[HID];
    const int t = threadIdx.x;
    const int wave = t >> 6, lane = t & 63;
    const int m = lane & 15, quad = lane >> 4;
    const int tile = blockIdx.x * 4 + wave;   // grid 1024 -> 4096 tiles
    const int r0 = tile << 4;
    const int row = r0 + m;

    // ---- phase 1: W_src ----
    for (int idx = t; idx < 128 * HID; idx += 256) {
        int k = idx >> 7, h = idx & 127;
        int kt = k >> 5, kk = k & 31;
        int ln = ((kk >> 3) << 4) | (h & 15);
        Wl[((((kt * 8) + (h >> 4)) * 64 + ln) << 3) | (kk & 7)] = f2bf(We[idx]);
    }
    for (int idx = t; idx < HID; idx += 256) bl[idx] = be[idx];
    __syncthreads();

    // A-frags loaded once, reused for both projections
    bfrag a[4];
    const __bf16* ar = xCur + (size_t)row * HID + quad * 8;
    #pragma unroll
    for (int kt = 0; kt < 4; ++kt) a[kt] = *(const bfrag*)(ar + kt * 32);

    ffrag acc[8];
    #pragma unroll
    for (int u = 0; u < 8; ++u)
        #pragma unroll
        for (int r = 0; r < 4; ++r) acc[u][r] = 0.f;

    #pragma unroll
    for (int kt = 0; kt < 4; ++kt)
        #pragma unroll
        for (int u = 0; u < 8; ++u) {
            bfrag b = *(const bfrag*)(&Wl[(((kt * 8 + u) * 64 + lane) << 3)]);
            acc[u] = __builtin_amdgcn_mfma_f32_16x16x32_bf16(a[kt], b, acc[u], 0, 0, 0);
        }
    #pragma unroll
    for (int r = 0; r < 4; ++r) {
        int node = r0 + quad * 4 + r;
        bfrag pk;
        #pragma unroll
        for (int u = 0; u < 8; ++u) pk[u] = f2bf(acc[u][r] + bl[u * 16 + m]);
        *(bfrag*)(St2 + ((size_t)node * 16 + m) * 8) = pk;   // 16B coalesced
    }
    __syncthreads();   // all waves done reading Wl(src)

    // ---- phase 2: W_dst (rows 128..255), reuse LDS ----
    for (int idx = t; idx < 128 * HID; idx += 256) {
        int k = idx >> 7, h = idx & 127;
        int kt = k >> 5, kk = k & 31;
        int ln = ((kk >> 3) << 4) | (h & 15);
        Wl[((((kt * 8) + (h >> 4)) * 64 + ln) << 3) | (kk & 7)] = f2bf(We[(size_t)(128 + k) * HID + h]);
    }
    __syncthreads();

    #pragma unroll
    for (int u = 0; u < 8; ++u)
        #pragma unroll
        for (int r = 0; r < 4; ++r) acc[u][r] = 0.f;

    #pragma unroll
    for (int kt = 0; kt < 4; ++kt)
        #pragma unroll
        for (int u = 0; u < 8; ++u) {
            bfrag b = *(const bfrag*)(&Wl[(((kt * 8 + u) * 64 + lane) << 3)]);
            acc[u] = __builtin_amdgcn_mfma_f32_16x16x32_bf16(a[kt], b, acc[u], 0, 0, 0);
        }
    // D written row-major, in place, NO bias (bias lives in St2)
    #pragma unroll
    for (int r = 0; r < 4; ++r) {
        int node = r0 + quad * 4 + r;
        __bf16* orow = xCur + (size_t)node * HID;
        #pragma unroll
        for (int u = 0; u < 8; ++u) orow[u * 16 + m] = f2bf(acc[u][r]);
    }
}

// ---------------------------------------------------------------------------
// Fused edge pass + segment_sum + col-max.  Wave owns 4 consecutive nodes =
// one contiguous sorted-edge range.  dsts preloaded into 2 regs (shfl-served),
// 1-tile-ahead frag prefetch across node boundaries, acc initialized with
// S[n]+bias.  Zero global atomics on the data path.
//
// R4: xCur holds precomputed D = x@W_dst (from k_src).  The gathered D row
// is placed into MFMA C-layout via identity-B MFMAs: for output col block u,
// only k == col contributes, so B is a constant one-hot fragment (Bev/Bod,
// 8 VGPRs total).  8 identity MFMAs + 8 ef MFMAs per tile (was 40); zero
// LDS weight reads in the loop (was 32); LDS shrinks to ~2.8 KB.
// ---------------------------------------------------------------------------
__global__ __launch_bounds__(256) void k_edge2(
    const __bf16* __restrict__ xCur,   // = D rows
    const int*    __restrict__ offs,
    const int*    __restrict__ dsts,
    const __bf16* __restrict__ efs,
    const __bf16* __restrict__ St2,
    const float*  __restrict__ We,    // 264x128 slice; rows 256..263 used
    __bf16* __restrict__ xNext,
    unsigned int* __restrict__ pmax, int stage)
{
    __shared__ __bf16 Wl[8 * 16 * 8];   // 2 KB: compact ef weight block
    __shared__ unsigned int cm[HID];
    const int t = threadIdx.x;

    if (t < HID) cm[t] = 0u;
    // ef rows 256..263, compact: [u][ln<16][j]  (2 KB)
    for (int idx = t; idx < 8 * HID; idx += 256) {
        int k2 = idx >> 7, h = idx & 127;
        Wl[((((h >> 4) * 16) + (h & 15)) << 3) + k2] = f2bf(We[(size_t)(256 + k2) * HID + h]);
    }
    __syncthreads();

    const int wave = t >> 6, lane = t & 63;
    const int m = lane & 15, quad = lane >> 4;
    const int gw = blockIdx.x * 4 + wave;    // grid 4096 -> 16384 waves
    const int n0 = gw * 4;                   // 4 nodes per wave, consecutive
    const int lc16 = (lane & 15) << 3;       // compact ef read offset

    // constant identity B-fragments: B[k][c] = (k==c) one-hot per col block.
    // u even: k_local = m -> quad == m>>3 holds the 1 at elem m&7.
    // u odd : k_local = 16+m -> quad == 2+(m>>3).
    bfrag Bev, Bod;
    #pragma unroll
    for (int j = 0; j < 8; ++j) {
        Bev[j] = (quad == (m >> 3)     && j == (m & 7)) ? (__bf16)1.f : (__bf16)0.f;
        Bod[j] = (quad == 2 + (m >> 3) && j == (m & 7)) ? (__bf16)1.f : (__bf16)0.f;
    }

    const int o0 = offs[n0],     o1 = offs[n0 + 1], o2 = offs[n0 + 2];
    const int o3 = offs[n0 + 3], o4 = offs[n0 + 4];

    auto selo = [&](int q) -> int {
        return (q <= 0) ? o0 : (q == 1) ? o1 : (q == 2) ? o2 : (q == 3) ? o3 : o4;
    };

    float mxu[8];
    #pragma unroll
    for (int u = 0; u < 8; ++u) mxu[u] = 0.f;

    if (o0 < o4) {
        const int dvA = dsts[min(o0 + lane, o4 - 1)];
        const int dvB = dsts[min(o0 + 64 + lane, o4 - 1)];

        auto LOADT = [&](int j) -> Frags {
            Frags f;
            int jl = j + m; jl = (jl < o4) ? jl : (o4 - 1);
            int rel = jl - o0;
            int dA = __shfl(dvA, rel & 63);
            int dB = __shfl(dvB, rel & 63);
            int dm;
            if (rel < 64)       dm = dA;
            else if (rel < 128) dm = dB;
            else                dm = dsts[jl];      // ultra-rare fallback
            const __bf16* rd = xCur + (size_t)dm * HID + quad * 8;
            f.a[0] = *(const bfrag*)(rd);
            f.a[1] = *(const bfrag*)(rd + 32);
            f.a[2] = *(const bfrag*)(rd + 64);
            f.a[3] = *(const bfrag*)(rd + 96);
            bfrag z;
            #pragma unroll
            for (int q = 0; q < 8; ++q) z[q] = (__bf16)0.f;
            if (quad == 0) z = *(const bfrag*)(efs + (size_t)jl * 8);
            f.a[4] = z;
            return f;
        };

        int ci = 0;
        while (selo(ci) == selo(ci + 1)) ++ci;   // first non-empty node (exists)
        int cj = selo(ci);

        bfrag sb = *(const bfrag*)(St2 + ((size_t)(n0 + ci) * 16 + m) * 8);
        float part[8];
        #pragma unroll
        for (int u = 0; u < 8; ++u) part[u] = 0.f;

        Frags aC = LOADT(cj);

        for (;;) {
            const int cEnd = selo(ci + 1);
            int ni = ci, nj = cj + 16;
            if (nj >= cEnd) {
                ni = ci + 1;
                while (ni < 4 && selo(ni) == selo(ni + 1)) ++ni;
                nj = (ni < 4) ? selo(ni) : 0;
            }
            const bool hn = (ni < 4);
            Frags aN;
            if (hn) aN = LOADT(nj);             // prefetch next tile

            ffrag acc[8];
            #pragma unroll
            for (int u = 0; u < 8; ++u) {
                float s = (float)sb[u];
                acc[u][0] = s; acc[u][1] = s; acc[u][2] = s; acc[u][3] = s;
            }
            // identity transpose: acc[u] += D-rows into C-layout
            #pragma unroll
            for (int u = 0; u < 8; ++u)
                acc[u] = __builtin_amdgcn_mfma_f32_16x16x32_bf16(
                    aC.a[u >> 1], (u & 1) ? Bod : Bev, acc[u], 0, 0, 0);
            // ef projection
            #pragma unroll
            for (int u = 0; u < 8; ++u) {
                bfrag b = *(const bfrag*)(&Wl[(u << 7) + lc16]);
                acc[u] = __builtin_amdgcn_mfma_f32_16x16x32_bf16(aC.a[4], b, acc[u], 0, 0, 0);
            }

            const int rb = cj + quad * 4;
            #pragma unroll
            for (int r = 0; r < 4; ++r) {
                if (rb + r < cEnd) {
                    #pragma unroll
                    for (int u = 0; u < 8; ++u)
                        part[u] += fmaxf(acc[u][r], 0.f);
                }
            }

            if (!hn || ni != ci) {
                float tot[8];
                #pragma unroll
                for (int u = 0; u < 8; ++u) {
                    float v = part[u];
                    v += __shfl_xor(v, 16);
                    v += __shfl_xor(v, 32);
                    tot[u] = v;
                    mxu[u] = fmaxf(mxu[u], v);
                }
                // static-index selection of this quad's 2 columns (no scratch)
                float sA = (quad == 0) ? tot[0] : (quad == 1) ? tot[2] : (quad == 2) ? tot[4] : tot[6];
                float sB = (quad == 0) ? tot[1] : (quad == 1) ? tot[3] : (quad == 2) ? tot[5] : tot[7];
                const int n = n0 + ci, u0 = quad * 2;
                xNext[(size_t)n * HID + u0 * 16 + m]      = f2bf(sA);
                xNext[(size_t)n * HID + u0 * 16 + 16 + m] = f2bf(sB);
                if (hn) {
                    sb = *(const bfrag*)(St2 + ((size_t)(n0 + ni) * 16 + m) * 8);
                    #pragma unroll
                    for (int u = 0; u < 8; ++u) part[u] = 0.f;
                }
            }
            if (!hn) break;
            aC = aN; ci = ni; cj = nj;
        }
    }

    // zero rows for empty nodes
    {
        const int u0 = quad * 2;
        const __bf16 zz = (__bf16)0.f;
        if (o0 == o1) { xNext[(size_t)(n0+0)*HID + u0*16 + m] = zz; xNext[(size_t)(n0+0)*HID + u0*16 + 16 + m] = zz; }
        if (o1 == o2) { xNext[(size_t)(n0+1)*HID + u0*16 + m] = zz; xNext[(size_t)(n0+1)*HID + u0*16 + 16 + m] = zz; }
        if (o2 == o3) { xNext[(size_t)(n0+2)*HID + u0*16 + m] = zz; xNext[(size_t)(n0+2)*HID + u0*16 + 16 + m] = zz; }
        if (o3 == o4) { xNext[(size_t)(n0+3)*HID + u0*16 + m] = zz; xNext[(size_t)(n0+3)*HID + u0*16 + 16 + m] = zz; }
    }

    #pragma unroll
    for (int u = 0; u < 8; ++u) {
        float v = mxu[u];
        v = fmaxf(v, __shfl_xor(v, 16));
        v = fmaxf(v, __shfl_xor(v, 32));
        if (quad == 0) atomicMax(&cm[u * 16 + m], __float_as_uint(v));
    }
    __syncthreads();
    if (t < HID) atomicMax(&pmax[stage * HID + t], cm[t]);
}

// ---------------------------------------------------------------------------
// Fallback path kernels (R1-proven, 48 MB footprint)
// ---------------------------------------------------------------------------
__global__ __launch_bounds__(256) void k_edge_at(
    const __bf16* __restrict__ xA, const int* __restrict__ eidx,
    const float* __restrict__ ef, const float* __restrict__ We,
    const float* __restrict__ be, float* __restrict__ xNew)
{
    __shared__ __bf16 Wl[9 * 8 * 64 * 8];
    __shared__ float  bl[HID];
    const int t = threadIdx.x;
    for (int idx = t; idx < 8 * 64 * 8; idx += 256) Wl[8 * 8 * 64 * 8 + idx] = (__bf16)0.f;
    __syncthreads();
    for (int idx = t; idx < 256 * HID; idx += 256) {
        int k = idx >> 7, h = idx & 127;
        int kt = k >> 5, kk = k & 31;
        int lane = ((kk >> 3) << 4) | (h & 15);
        Wl[((((kt * 8) + (h >> 4)) * 64 + lane) << 3) | (kk & 7)] = f2bf(We[idx]);
    }
    for (int idx = t; idx < 8 * HID; idx += 256) {
        int k2 = idx >> 7, h = idx & 127;
        Wl[((((8 * 8) + (h >> 4)) * 64 + (h & 15)) << 3) | k2] = f2bf(We[(256 + k2) * HID + h]);
    }
    for (int idx = t; idx < HID; idx += 256) bl[idx] = be[idx];
    __syncthreads();

    const int wave = t >> 6, lane = t & 63;
    const int m = lane & 15, quad = lane >> 4;
    for (int c = 0; c < 8; ++c) {
        const int e0 = blockIdx.x * 512 + c * 64 + wave * 16;
        const int e  = e0 + m;
        const int src = eidx[2 * e], dst = eidx[2 * e + 1];
        const __bf16* rs = xA + (size_t)src * HID;
        const __bf16* rd = xA + (size_t)dst * HID;
        bfrag a[9];
        #pragma unroll
        for (int kt = 0; kt < 4; ++kt) a[kt] = *(const bfrag*)(rs + kt * 32 + quad * 8);
        #pragma unroll
        for (int kt = 4; kt < 8; ++kt) a[kt] = *(const bfrag*)(rd + (kt - 4) * 32 + quad * 8);
        {
            bfrag z;
            #pragma unroll
            for (int q = 0; q < 8; ++q) z[q] = (__bf16)0.f;
            if (quad == 0) {
                const float4* p = (const float4*)(ef + (size_t)e * 8);
                float4 f0 = p[0], f1 = p[1];
                z[0]=f2bf(f0.x); z[1]=f2bf(f0.y); z[2]=f2bf(f0.z); z[3]=f2bf(f0.w);
                z[4]=f2bf(f1.x); z[5]=f2bf(f1.y); z[6]=f2bf(f1.z); z[7]=f2bf(f1.w);
            }
            a[8] = z;
        }
        ffrag acc[8];
        #pragma unroll
        for (int u = 0; u < 8; ++u)
            #pragma unroll
            for (int r = 0; r < 4; ++r) acc[u][r] = 0.f;
        #pragma unroll
        for (int kt = 0; kt < 9; ++kt)
            #pragma unroll
            for (int u = 0; u < 8; ++u) {
                bfrag b = *(const bfrag*)(&Wl[(((kt * 8 + u) * 64 + lane) << 3)]);
                acc[u] = __builtin_amdgcn_mfma_f32_16x16x32_bf16(a[kt], b, acc[u], 0, 0, 0);
            }
        #pragma unroll
        for (int r = 0; r < 4; ++r) {
            int er = e0 + quad * 4 + r;
            int sr = eidx[2 * er];
            float* outrow = xNew + (size_t)sr * HID;
            #pragma unroll
            for (int u = 0; u < 8; ++u) {
                int col = u * 16 + m;
                atomicAdd(outrow + col, fmaxf(acc[u][r] + bl[col], 0.f));
            }
        }
    }
}

__global__ __launch_bounds__(256) void k_fin(
    float* __restrict__ xNew, __bf16* __restrict__ xA,
    unsigned int* __restrict__ pmax, int stage, int flags)
{
    const int t = threadIdx.x;
    const size_t total  = (size_t)NCH * HID;
    const size_t stride = (size_t)gridDim.x * 256;
    float mx = 0.f;
    for (size_t i = (size_t)blockIdx.x * 256 + t; i < total; i += stride) {
        float v = xNew[i];
        mx = fmaxf(mx, v);
        if (flags & 1) xA[i] = f2bf(v);
        if (flags & 2) xNew[i] = 0.f;
    }
    __shared__ float red[256];
    red[t] = mx;
    __syncthreads();
    if (t < 128) {
        float v = fmaxf(red[t], red[t + 128]);
        atomicMax(&pmax[stage * HID + t], __float_as_uint(v));
    }
}

// ---------------------------------------------------------------------------
// Parent head: out = relu(pmax(384) @ Wp + bp)
// ---------------------------------------------------------------------------
__global__ __launch_bounds__(128) void k_parent(
    const unsigned int* __restrict__ pmaxU,
    const float* __restrict__ Wp, const float* __restrict__ bp,
    float* __restrict__ out)
{
    __shared__ float pl[384];
    const int t = threadIdx.x;
    for (int i = t; i < 384; i += 128) pl[i] = __uint_as_float(pmaxU[i]);
    __syncthreads();
    float acc = bp[t];
    for (int j = 0; j < 384; ++j) acc += pl[j] * Wp[j * HID + t];
    out[t] = fmaxf(acc, 0.f);
}

extern "C" void kernel_launch(void* const* d_in, const int* in_sizes, int n_in,
                              void* d_out, int out_size, void* d_ws, size_t ws_size,
                              hipStream_t stream)
{
    const float* cf   = (const float*)d_in[0];
    const float* ex   = (const float*)d_in[1];
    const float* ef   = (const float*)d_in[2];
    const int*   eidx = (const int*)d_in[3];
    const float* Wc   = (const float*)d_in[4];
    const float* bc   = (const float*)d_in[5];
    const float* We   = (const float*)d_in[6];
    const float* be   = (const float*)d_in[7];
    const float* Wp   = (const float*)d_in[8];
    const float* bp   = (const float*)d_in[9];
    float* out = (float*)d_out;

    char* ws = (char*)d_ws;

    // CSR-fused path layout (~69 MB)
    const size_t OFF_XA   = 0;
    const size_t OFF_XB   = OFF_XA   + (size_t)NCH * HID * 2;   // +16 MB
    const size_t OFF_ST   = OFF_XB   + (size_t)NCH * HID * 2;   // +16 MB
    const size_t OFF_EFS  = OFF_ST   + (size_t)NCH * HID * 2;   // +16 MB
    const size_t OFF_DST  = OFF_EFS  + (size_t)NE * 8 * 2;      // +16 MB
    const size_t OFF_OFFS = OFF_DST  + (size_t)NE * 4;          // +4 MB
    const size_t OFF_DEG  = OFF_OFFS + 262400;
    const size_t OFF_CUR  = OFF_DEG  + 262144;
    const size_t OFF_PMAX = OFF_CUR  + 262144;
    const size_t NEED     = OFF_PMAX + 2048;

    if (ws_size >= NEED) {
        __bf16*       xA   = (__bf16*)(ws + OFF_XA);
        __bf16*       xB   = (__bf16*)(ws + OFF_XB);
        __bf16*       St2  = (__bf16*)(ws + OFF_ST);
        __bf16*       efs  = (__bf16*)(ws + OFF_EFS);
        int*          dsts = (int*)   (ws + OFF_DST);
        int*          offs = (int*)   (ws + OFF_OFFS);
        int*          deg  = (int*)   (ws + OFF_DEG);
        int*          cur  = (int*)   (ws + OFF_CUR);
        unsigned int* pmax = (unsigned int*)(ws + OFF_PMAX);

        hipMemsetAsync(pmax, 0, 384 * sizeof(unsigned int), stream);
        hipMemsetAsync(deg, 0, NCH * sizeof(int), stream);

        k_child  <<<1024, 256, 0, stream>>>(cf, ex, Wc, bc, xA, pmax);
        k_hist   <<<4096, 256, 0, stream>>>(eidx, deg);
        k_scan   <<<1,   1024, 0, stream>>>(deg, offs, cur);
        k_scatter<<<4096, 256, 0, stream>>>(eidx, cur, ef, dsts, efs);

        k_src    <<<1024, 256, 0, stream>>>(xA, We, be, St2);              // xA -> D in place
        k_edge2  <<<4096, 256, 0, stream>>>(xA, offs, dsts, efs, St2, We, xB, pmax, 1);
        k_src    <<<1024, 256, 0, stream>>>(xB, We + 264 * HID, be + HID, St2);
        k_edge2  <<<4096, 256, 0, stream>>>(xB, offs, dsts, efs, St2, We + 264 * HID, xA, pmax, 2);
        k_parent <<<1,    128, 0, stream>>>(pmax, Wp, bp, out);
    } else {
        // fallback: R1 atomic path (48 MB)
        float*        xNew = (float*)ws;
        __bf16*       xA   = (__bf16*)(ws + (size_t)NCH * HID * 4);
        unsigned int* pmax = (unsigned int*)(ws + (size_t)NCH * HID * 6);

        hipMemsetAsync(pmax, 0, 384 * sizeof(unsigned int), stream);
        hipMemsetAsync(xNew, 0, (size_t)NCH * HID * 4, stream);

        k_child  <<<1024, 256, 0, stream>>>(cf, ex, Wc, bc, xA, pmax);
        k_edge_at<<<2048, 256, 0, stream>>>(xA, eidx, ef, We,             be,       xNew);
        k_fin    <<<512,  256, 0, stream>>>(xNew, xA, pmax, 1, 3);
        k_edge_at<<<2048, 256, 0, stream>>>(xA, eidx, ef, We + 264 * HID, be + HID, xNew);
        k_fin    <<<512,  256, 0, stream>>>(xNew, xA, pmax, 2, 0);
        k_parent <<<1,    128, 0, stream>>>(pmax, Wp, bp, out);
    }
}

// Round 4
// 611.134 us; speedup vs baseline: 1.5539x; 1.0005x over previous
//
#include <hip/hip_runtime.h>
#include <hip/hip_bf16.h>

#define HID 128
#define DIN 192      // N_FEAT + NUM_SEM
#define NCH 65536
#define NE  1048576

typedef __bf16 bfrag __attribute__((ext_vector_type(8)));
typedef float  ffrag __attribute__((ext_vector_type(4)));

static __device__ __forceinline__ __bf16 f2bf(float x) { return (__bf16)x; }
static __device__ __forceinline__ unsigned pk2(float a, float b) {
    __bf16 b0 = f2bf(a), b1 = f2bf(b);
    return (unsigned)*(unsigned short*)&b0 | ((unsigned)*(unsigned short*)&b1 << 16);
}

struct Frags { bfrag a[5]; };

// ---------------------------------------------------------------------------
// Child encoder fused: xA[n][h] = bf16(relu(cf[n]@Wc + bc) * exists[n]),
// col-max into pmax[0..127].
// ---------------------------------------------------------------------------
__global__ __launch_bounds__(256) void k_child(
    const float* __restrict__ cf, const float* __restrict__ exists,
    const float* __restrict__ Wc, const float* __restrict__ bc,
    __bf16* __restrict__ xA, unsigned int* __restrict__ pmax)
{
    __shared__ __bf16 Wl[6 * 8 * 64 * 8];   // 48 KB, B-fragment-swizzled
    __shared__ float  bl[HID];
    __shared__ unsigned int cm[HID];
    const int t = threadIdx.x;

    for (int idx = t; idx < DIN * HID; idx += 256) {
        int k = idx >> 7, h = idx & 127;
        int kt = k >> 5, kk = k & 31;
        int lane = ((kk >> 3) << 4) | (h & 15);
        Wl[((((kt * 8) + (h >> 4)) * 64 + lane) << 3) | (kk & 7)] = f2bf(Wc[idx]);
    }
    for (int idx = t; idx < HID; idx += 256) { bl[idx] = bc[idx]; cm[idx] = 0u; }
    __syncthreads();

    const int wave = t >> 6, lane = t & 63;
    const int m = lane & 15, quad = lane >> 4;

    const int tile = blockIdx.x * 4 + wave;   // grid 1024 -> 4096 tiles
    const int r0 = tile << 4;
    const int row = r0 + m;

    ffrag acc[8];
    #pragma unroll
    for (int u = 0; u < 8; ++u)
        #pragma unroll
        for (int r = 0; r < 4; ++r) acc[u][r] = 0.f;

    const float* arow = cf + (size_t)row * DIN + quad * 8;
    #pragma unroll
    for (int kt = 0; kt < 6; ++kt) {
        float4 f0 = *(const float4*)(arow + kt * 32);
        float4 f1 = *(const float4*)(arow + kt * 32 + 4);
        bfrag a;
        a[0]=f2bf(f0.x); a[1]=f2bf(f0.y); a[2]=f2bf(f0.z); a[3]=f2bf(f0.w);
        a[4]=f2bf(f1.x); a[5]=f2bf(f1.y); a[6]=f2bf(f1.z); a[7]=f2bf(f1.w);
        #pragma unroll
        for (int u = 0; u < 8; ++u) {
            bfrag b = *(const bfrag*)(&Wl[(((kt * 8 + u) * 64 + lane) << 3)]);
            acc[u] = __builtin_amdgcn_mfma_f32_16x16x32_bf16(a, b, acc[u], 0, 0, 0);
        }
    }

    float mxu[8];
    #pragma unroll
    for (int u = 0; u < 8; ++u) mxu[u] = 0.f;

    #pragma unroll
    for (int r = 0; r < 4; ++r) {
        int er = r0 + quad * 4 + r;
        float exv = exists[er];
        __bf16* orow = xA + (size_t)er * HID;
        #pragma unroll
        for (int u = 0; u < 8; ++u) {
            int col = u * 16 + m;
            float v = fmaxf(acc[u][r] + bl[col], 0.f) * exv;
            orow[col] = f2bf(v);
            mxu[u] = fmaxf(mxu[u], v);
        }
    }
    #pragma unroll
    for (int u = 0; u < 8; ++u) {
        float v = mxu[u];
        v = fmaxf(v, __shfl_xor(v, 16));
        v = fmaxf(v, __shfl_xor(v, 32));
        if (quad == 0) atomicMax(&cm[u * 16 + m], __float_as_uint(v));
    }
    __syncthreads();
    if (t < HID) atomicMax(&pmax[t], cm[t]);
}

// ---------------------------------------------------------------------------
// CSR build
// ---------------------------------------------------------------------------
__global__ __launch_bounds__(256) void k_hist(
    const int* __restrict__ eidx, int* __restrict__ deg)
{
    int e = blockIdx.x * 256 + threadIdx.x;
    atomicAdd(&deg[eidx[2 * e]], 1);
}

__global__ __launch_bounds__(1024) void k_scan(
    const int* __restrict__ deg, int* __restrict__ off, int* __restrict__ cursor)
{
    __shared__ int sc[1024];
    const int t = threadIdx.x;
    const int base = t * 64;
    int s = 0;
    for (int i = 0; i < 64; ++i) s += deg[base + i];
    sc[t] = s;
    __syncthreads();
    for (int o = 1; o < 1024; o <<= 1) {
        int v = (t >= o) ? sc[t - o] : 0;
        __syncthreads();
        sc[t] += v;
        __syncthreads();
    }
    int run = sc[t] - s;
    for (int i = 0; i < 64; ++i) {
        int v = deg[base + i];
        off[base + i] = run;
        cursor[base + i] = run;
        run += v;
    }
    if (t == 1023) off[NCH] = run;
}

// Scatter fused with dst/ef gather: coalesced ef read, scattered 16B/4B writes.
__global__ __launch_bounds__(256) void k_scatter(
    const int* __restrict__ eidx, int* __restrict__ cursor,
    const float* __restrict__ ef,
    int* __restrict__ dsts, __bf16* __restrict__ efs)
{
    int e = blockIdx.x * 256 + threadIdx.x;
    int s = eidx[2 * e], d = eidx[2 * e + 1];
    const float4* p = (const float4*)(ef + (size_t)e * 8);
    float4 f0 = p[0], f1 = p[1];
    int pos = atomicAdd(&cursor[s], 1);
    dsts[pos] = d;
    uint4 pk;
    pk.x = pk2(f0.x, f0.y); pk.y = pk2(f0.z, f0.w);
    pk.z = pk2(f1.x, f1.y); pk.w = pk2(f1.z, f1.w);
    *(uint4*)(efs + (size_t)pos * 8) = pk;
}

// ---------------------------------------------------------------------------
// k_src computes BOTH per-node projections from x:
//   St2[n]  = bf16( x[n] @ We[0:128]   + be )   (frag-ordered)
//   D[n]    = bf16( x[n] @ We[128:256] )        (row-major, IN-PLACE over x)
// ---------------------------------------------------------------------------
__global__ __launch_bounds__(256) void k_src(
    __bf16* __restrict__ xCur, const float* __restrict__ We,
    const float* __restrict__ be, __bf16* __restrict__ St2)
{
    __shared__ __bf16 Wl[4 * 8 * 64 * 8];   // 32 KB, reused for src then dst
    __shared__ float  bl[HID];
    const int t = threadIdx.x;
    const int wave = t >> 6, lane = t & 63;
    const int m = lane & 15, quad = lane >> 4;
    const int tile = blockIdx.x * 4 + wave;   // grid 1024 -> 4096 tiles
    const int r0 = tile << 4;
    const int row = r0 + m;

    // ---- phase 1: W_src ----
    for (int idx = t; idx < 128 * HID; idx += 256) {
        int k = idx >> 7, h = idx & 127;
        int kt = k >> 5, kk = k & 31;
        int ln = ((kk >> 3) << 4) | (h & 15);
        Wl[((((kt * 8) + (h >> 4)) * 64 + ln) << 3) | (kk & 7)] = f2bf(We[idx]);
    }
    for (int idx = t; idx < HID; idx += 256) bl[idx] = be[idx];
    __syncthreads();

    // A-frags loaded once, reused for both projections
    bfrag a[4];
    const __bf16* ar = xCur + (size_t)row * HID + quad * 8;
    #pragma unroll
    for (int kt = 0; kt < 4; ++kt) a[kt] = *(const bfrag*)(ar + kt * 32);

    ffrag acc[8];
    #pragma unroll
    for (int u = 0; u < 8; ++u)
        #pragma unroll
        for (int r = 0; r < 4; ++r) acc[u][r] = 0.f;

    #pragma unroll
    for (int kt = 0; kt < 4; ++kt)
        #pragma unroll
        for (int u = 0; u < 8; ++u) {
            bfrag b = *(const bfrag*)(&Wl[(((kt * 8 + u) * 64 + lane) << 3)]);
            acc[u] = __builtin_amdgcn_mfma_f32_16x16x32_bf16(a[kt], b, acc[u], 0, 0, 0);
        }
    #pragma unroll
    for (int r = 0; r < 4; ++r) {
        int node = r0 + quad * 4 + r;
        bfrag pk;
        #pragma unroll
        for (int u = 0; u < 8; ++u) pk[u] = f2bf(acc[u][r] + bl[u * 16 + m]);
        *(bfrag*)(St2 + ((size_t)node * 16 + m) * 8) = pk;   // 16B coalesced
    }
    __syncthreads();   // all waves done reading Wl(src)

    // ---- phase 2: W_dst (rows 128..255), reuse LDS ----
    for (int idx = t; idx < 128 * HID; idx += 256) {
        int k = idx >> 7, h = idx & 127;
        int kt = k >> 5, kk = k & 31;
        int ln = ((kk >> 3) << 4) | (h & 15);
        Wl[((((kt * 8) + (h >> 4)) * 64 + ln) << 3) | (kk & 7)] = f2bf(We[(size_t)(128 + k) * HID + h]);
    }
    __syncthreads();

    #pragma unroll
    for (int u = 0; u < 8; ++u)
        #pragma unroll
        for (int r = 0; r < 4; ++r) acc[u][r] = 0.f;

    #pragma unroll
    for (int kt = 0; kt < 4; ++kt)
        #pragma unroll
        for (int u = 0; u < 8; ++u) {
            bfrag b = *(const bfrag*)(&Wl[(((kt * 8 + u) * 64 + lane) << 3)]);
            acc[u] = __builtin_amdgcn_mfma_f32_16x16x32_bf16(a[kt], b, acc[u], 0, 0, 0);
        }
    // D written row-major, in place, NO bias (bias lives in St2)
    #pragma unroll
    for (int r = 0; r < 4; ++r) {
        int node = r0 + quad * 4 + r;
        __bf16* orow = xCur + (size_t)node * HID;
        #pragma unroll
        for (int u = 0; u < 8; ++u) orow[u * 16 + m] = f2bf(acc[u][r]);
    }
}

// ---------------------------------------------------------------------------
// Fused edge pass + segment_sum + col-max.  Wave owns 4 consecutive nodes =
// one contiguous sorted-edge range.  dsts preloaded into 2 regs (shfl-served),
// acc initialized with S[n]+bias.  Zero global atomics on the data path.
//
// R5: 3-stage rotating software pipeline — 2 gather tiles in flight (a0
// compute / a1 arriving / a2 issued this step).  Manually 3-fold rotated
// loop body: zero frag register copies, all static indexing.  ~2 tiles of
// compute (~600 cy) now cover the ~500-900 cy L2-miss gather latency.
// ---------------------------------------------------------------------------
__global__ __launch_bounds__(256) void k_edge2(
    const __bf16* __restrict__ xCur,   // = D rows
    const int*    __restrict__ offs,
    const int*    __restrict__ dsts,
    const __bf16* __restrict__ efs,
    const __bf16* __restrict__ St2,
    const float*  __restrict__ We,    // 264x128 slice; rows 256..263 used
    __bf16* __restrict__ xNext,
    unsigned int* __restrict__ pmax, int stage)
{
    __shared__ __bf16 Wl[8 * 16 * 8];   // 2 KB: compact ef weight block
    __shared__ unsigned int cm[HID];
    const int t = threadIdx.x;

    if (t < HID) cm[t] = 0u;
    // ef rows 256..263, compact: [u][ln<16][j]  (2 KB)
    for (int idx = t; idx < 8 * HID; idx += 256) {
        int k2 = idx >> 7, h = idx & 127;
        Wl[((((h >> 4) * 16) + (h & 15)) << 3) + k2] = f2bf(We[(size_t)(256 + k2) * HID + h]);
    }
    __syncthreads();

    const int wave = t >> 6, lane = t & 63;
    const int m = lane & 15, quad = lane >> 4;
    const int gw = blockIdx.x * 4 + wave;    // grid 4096 -> 16384 waves
    const int n0 = gw * 4;                   // 4 nodes per wave, consecutive
    const int lc16 = (lane & 15) << 3;       // compact ef read offset

    // constant identity B-fragments: B[k][c] = (k==c) one-hot per col block.
    bfrag Bev, Bod;
    #pragma unroll
    for (int j = 0; j < 8; ++j) {
        Bev[j] = (quad == (m >> 3)     && j == (m & 7)) ? (__bf16)1.f : (__bf16)0.f;
        Bod[j] = (quad == 2 + (m >> 3) && j == (m & 7)) ? (__bf16)1.f : (__bf16)0.f;
    }

    const int o0 = offs[n0],     o1 = offs[n0 + 1], o2 = offs[n0 + 2];
    const int o3 = offs[n0 + 3], o4 = offs[n0 + 4];

    auto selo = [&](int q) -> int {
        return (q <= 0) ? o0 : (q == 1) ? o1 : (q == 2) ? o2 : (q == 3) ? o3 : o4;
    };

    float mxu[8];
    #pragma unroll
    for (int u = 0; u < 8; ++u) mxu[u] = 0.f;

    if (o0 < o4) {
        const int dvA = dsts[min(o0 + lane, o4 - 1)];
        const int dvB = dsts[min(o0 + 64 + lane, o4 - 1)];

        auto LOADT = [&](int j) -> Frags {
            Frags f;
            int jl = j + m; jl = (jl < o4) ? jl : (o4 - 1);
            int rel = jl - o0;
            int dA = __shfl(dvA, rel & 63);
            int dB = __shfl(dvB, rel & 63);
            int dm;
            if (rel < 64)       dm = dA;
            else if (rel < 128) dm = dB;
            else                dm = dsts[jl];      // ultra-rare fallback
            const __bf16* rd = xCur + (size_t)dm * HID + quad * 8;
            f.a[0] = *(const bfrag*)(rd);
            f.a[1] = *(const bfrag*)(rd + 32);
            f.a[2] = *(const bfrag*)(rd + 64);
            f.a[3] = *(const bfrag*)(rd + 96);
            bfrag z;
            #pragma unroll
            for (int q = 0; q < 8; ++q) z[q] = (__bf16)0.f;
            if (quad == 0) z = *(const bfrag*)(efs + (size_t)jl * 8);
            f.a[4] = z;
            return f;
        };

        // advance (i,j) -> next tile position; io=4 when exhausted
        auto adv = [&](int i, int j, int& io, int& jo) {
            int cEnd = selo(i + 1);
            int j2 = j + 16;
            if (j2 < cEnd) { io = i; jo = j2; return; }
            int i2 = i + 1;
            while (i2 < 4 && selo(i2) == selo(i2 + 1)) ++i2;
            io = i2; jo = (i2 < 4) ? selo(i2) : 0;
        };

        int i0 = 0;
        while (selo(i0) == selo(i0 + 1)) ++i0;   // first non-empty node
        int j0 = selo(i0);
        int i1, j1;
        adv(i0, j0, i1, j1);

        Frags a0, a1, a2;
        a0 = LOADT(j0);
        if (i1 < 4) a1 = LOADT(j1);

        bfrag sbc = *(const bfrag*)(St2 + ((size_t)(n0 + i0) * 16 + m) * 8);
        float part[8];
        #pragma unroll
        for (int u = 0; u < 8; ++u) part[u] = 0.f;

#define STEP(aCUR, aNXT, aFAR)                                               \
        {                                                                    \
            int i2 = 4, j2 = 0;                                              \
            if (i1 < 4) adv(i1, j1, i2, j2);                                 \
            if (i2 < 4) aFAR = LOADT(j2);                                    \
                                                                             \
            const int cEnd = selo(i0 + 1);                                   \
            ffrag acc[8];                                                    \
            _Pragma("unroll")                                                \
            for (int u = 0; u < 8; ++u) {                                    \
                float s = (float)sbc[u];                                     \
                acc[u][0] = s; acc[u][1] = s; acc[u][2] = s; acc[u][3] = s;  \
            }                                                                \
            _Pragma("unroll")                                                \
            for (int u = 0; u < 8; ++u)                                      \
                acc[u] = __builtin_amdgcn_mfma_f32_16x16x32_bf16(            \
                    aCUR.a[u >> 1], (u & 1) ? Bod : Bev, acc[u], 0, 0, 0);   \
            _Pragma("unroll")                                                \
            for (int u = 0; u < 8; ++u) {                                    \
                bfrag b = *(const bfrag*)(&Wl[(u << 7) + lc16]);             \
                acc[u] = __builtin_amdgcn_mfma_f32_16x16x32_bf16(            \
                    aCUR.a[4], b, acc[u], 0, 0, 0);                          \
            }                                                                \
            const int rb = j0 + quad * 4;                                    \
            _Pragma("unroll")                                                \
            for (int r = 0; r < 4; ++r) {                                    \
                if (rb + r < cEnd) {                                         \
                    _Pragma("unroll")                                        \
                    for (int u = 0; u < 8; ++u)                              \
                        part[u] += fmaxf(acc[u][r], 0.f);                    \
                }                                                            \
            }                                                                \
            if (i1 != i0) {                                                  \
                float tot[8];                                                \
                _Pragma("unroll")                                            \
                for (int u = 0; u < 8; ++u) {                                \
                    float v = part[u];                                       \
                    v += __shfl_xor(v, 16);                                  \
                    v += __shfl_xor(v, 32);                                  \
                    tot[u] = v;                                              \
                    mxu[u] = fmaxf(mxu[u], v);                               \
                }                                                            \
                float sA = (quad == 0) ? tot[0] : (quad == 1) ? tot[2]       \
                         : (quad == 2) ? tot[4] : tot[6];                    \
                float sB = (quad == 0) ? tot[1] : (quad == 1) ? tot[3]       \
                         : (quad == 2) ? tot[5] : tot[7];                    \
                const int n = n0 + i0, u0 = quad * 2;                        \
                xNext[(size_t)n * HID + u0 * 16 + m]      = f2bf(sA);        \
                xNext[(size_t)n * HID + u0 * 16 + 16 + m] = f2bf(sB);        \
                if (i1 < 4) {                                                \
                    sbc = *(const bfrag*)(St2 + ((size_t)(n0 + i1) * 16 + m) * 8); \
                    _Pragma("unroll")                                        \
                    for (int u = 0; u < 8; ++u) part[u] = 0.f;               \
                }                                                            \
            }                                                                \
            if (i1 >= 4) break;                                              \
            i0 = i1; j0 = j1; i1 = i2; j1 = j2;                              \
        }

        for (;;) {
            STEP(a0, a1, a2)
            STEP(a1, a2, a0)
            STEP(a2, a0, a1)
        }
#undef STEP
    }

    // zero rows for empty nodes
    {
        const int u0 = quad * 2;
        const __bf16 zz = (__bf16)0.f;
        if (o0 == o1) { xNext[(size_t)(n0+0)*HID + u0*16 + m] = zz; xNext[(size_t)(n0+0)*HID + u0*16 + 16 + m] = zz; }
        if (o1 == o2) { xNext[(size_t)(n0+1)*HID + u0*16 + m] = zz; xNext[(size_t)(n0+1)*HID + u0*16 + 16 + m] = zz; }
        if (o2 == o3) { xNext[(size_t)(n0+2)*HID + u0*16 + m] = zz; xNext[(size_t)(n0+2)*HID + u0*16 + 16 + m] = zz; }
        if (o3 == o4) { xNext[(size_t)(n0+3)*HID + u0*16 + m] = zz; xNext[(size_t)(n0+3)*HID + u0*16 + 16 + m] = zz; }
    }

    #pragma unroll
    for (int u = 0; u < 8; ++u) {
        float v = mxu[u];
        v = fmaxf(v, __shfl_xor(v, 16));
        v = fmaxf(v, __shfl_xor(v, 32));
        if (quad == 0) atomicMax(&cm[u * 16 + m], __float_as_uint(v));
    }
    __syncthreads();
    if (t < HID) atomicMax(&pmax[stage * HID + t], cm[t]);
}

// ---------------------------------------------------------------------------
// Fallback path kernels (R1-proven, 48 MB footprint)
// ---------------------------------------------------------------------------
__global__ __launch_bounds__(256) void k_edge_at(
    const __bf16* __restrict__ xA, const int* __restrict__ eidx,
    const float* __restrict__ ef, const float* __restrict__ We,
    const float* __restrict__ be, float* __restrict__ xNew)
{
    __shared__ __bf16 Wl[9 * 8 * 64 * 8];
    __shared__ float  bl[HID];
    const int t = threadIdx.x;
    for (int idx = t; idx < 8 * 64 * 8; idx += 256) Wl[8 * 8 * 64 * 8 + idx] = (__bf16)0.f;
    __syncthreads();
    for (int idx = t; idx < 256 * HID; idx += 256) {
        int k = idx >> 7, h = idx & 127;
        int kt = k >> 5, kk = k & 31;
        int lane = ((kk >> 3) << 4) | (h & 15);
        Wl[((((kt * 8) + (h >> 4)) * 64 + lane) << 3) | (kk & 7)] = f2bf(We[idx]);
    }
    for (int idx = t; idx < 8 * HID; idx += 256) {
        int k2 = idx >> 7, h = idx & 127;
        Wl[((((8 * 8) + (h >> 4)) * 64 + (h & 15)) << 3) | k2] = f2bf(We[(256 + k2) * HID + h]);
    }
    for (int idx = t; idx < HID; idx += 256) bl[idx] = be[idx];
    __syncthreads();

    const int wave = t >> 6, lane = t & 63;
    const int m = lane & 15, quad = lane >> 4;
    for (int c = 0; c < 8; ++c) {
        const int e0 = blockIdx.x * 512 + c * 64 + wave * 16;
        const int e  = e0 + m;
        const int src = eidx[2 * e], dst = eidx[2 * e + 1];
        const __bf16* rs = xA + (size_t)src * HID;
        const __bf16* rd = xA + (size_t)dst * HID;
        bfrag a[9];
        #pragma unroll
        for (int kt = 0; kt < 4; ++kt) a[kt] = *(const bfrag*)(rs + kt * 32 + quad * 8);
        #pragma unroll
        for (int kt = 4; kt < 8; ++kt) a[kt] = *(const bfrag*)(rd + (kt - 4) * 32 + quad * 8);
        {
            bfrag z;
            #pragma unroll
            for (int q = 0; q < 8; ++q) z[q] = (__bf16)0.f;
            if (quad == 0) {
                const float4* p = (const float4*)(ef + (size_t)e * 8);
                float4 f0 = p[0], f1 = p[1];
                z[0]=f2bf(f0.x); z[1]=f2bf(f0.y); z[2]=f2bf(f0.z); z[3]=f2bf(f0.w);
                z[4]=f2bf(f1.x); z[5]=f2bf(f1.y); z[6]=f2bf(f1.z); z[7]=f2bf(f1.w);
            }
            a[8] = z;
        }
        ffrag acc[8];
        #pragma unroll
        for (int u = 0; u < 8; ++u)
            #pragma unroll
            for (int r = 0; r < 4; ++r) acc[u][r] = 0.f;
        #pragma unroll
        for (int kt = 0; kt < 9; ++kt)
            #pragma unroll
            for (int u = 0; u < 8; ++u) {
                bfrag b = *(const bfrag*)(&Wl[(((kt * 8 + u) * 64 + lane) << 3)]);
                acc[u] = __builtin_amdgcn_mfma_f32_16x16x32_bf16(a[kt], b, acc[u], 0, 0, 0);
            }
        #pragma unroll
        for (int r = 0; r < 4; ++r) {
            int er = e0 + quad * 4 + r;
            int sr = eidx[2 * er];
            float* outrow = xNew + (size_t)sr * HID;
            #pragma unroll
            for (int u = 0; u < 8; ++u) {
                int col = u * 16 + m;
                atomicAdd(outrow + col, fmaxf(acc[u][r] + bl[col], 0.f));
            }
        }
    }
}

__global__ __launch_bounds__(256) void k_fin(
    float* __restrict__ xNew, __bf16* __restrict__ xA,
    unsigned int* __restrict__ pmax, int stage, int flags)
{
    const int t = threadIdx.x;
    const size_t total  = (size_t)NCH * HID;
    const size_t stride = (size_t)gridDim.x * 256;
    float mx = 0.f;
    for (size_t i = (size_t)blockIdx.x * 256 + t; i < total; i += stride) {
        float v = xNew[i];
        mx = fmaxf(mx, v);
        if (flags & 1) xA[i] = f2bf(v);
        if (flags & 2) xNew[i] = 0.f;
    }
    __shared__ float red[256];
    red[t] = mx;
    __syncthreads();
    if (t < 128) {
        float v = fmaxf(red[t], red[t + 128]);
        atomicMax(&pmax[stage * HID + t], __float_as_uint(v));
    }
}

// ---------------------------------------------------------------------------
// Parent head: out = relu(pmax(384) @ Wp + bp)
// ---------------------------------------------------------------------------
__global__ __launch_bounds__(128) void k_parent(
    const unsigned int* __restrict__ pmaxU,
    const float* __restrict__ Wp, const float* __restrict__ bp,
    float* __restrict__ out)
{
    __shared__ float pl[384];
    const int t = threadIdx.x;
    for (int i = t; i < 384; i += 128) pl[i] = __uint_as_float(pmaxU[i]);
    __syncthreads();
    float acc = bp[t];
    for (int j = 0; j < 384; ++j) acc += pl[j] * Wp[j * HID + t];
    out[t] = fmaxf(acc, 0.f);
}

extern "C" void kernel_launch(void* const* d_in, const int* in_sizes, int n_in,
                              void* d_out, int out_size, void* d_ws, size_t ws_size,
                              hipStream_t stream)
{
    const float* cf   = (const float*)d_in[0];
    const float* ex   = (const float*)d_in[1];
    const float* ef   = (const float*)d_in[2];
    const int*   eidx = (const int*)d_in[3];
    const float* Wc   = (const float*)d_in[4];
    const float* bc   = (const float*)d_in[5];
    const float* We   = (const float*)d_in[6];
    const float* be   = (const float*)d_in[7];
    const float* Wp   = (const float*)d_in[8];
    const float* bp   = (const float*)d_in[9];
    float* out = (float*)d_out;

    char* ws = (char*)d_ws;

    // CSR-fused path layout (~69 MB)
    const size_t OFF_XA   = 0;
    const size_t OFF_XB   = OFF_XA   + (size_t)NCH * HID * 2;   // +16 MB
    const size_t OFF_ST   = OFF_XB   + (size_t)NCH * HID * 2;   // +16 MB
    const size_t OFF_EFS  = OFF_ST   + (size_t)NCH * HID * 2;   // +16 MB
    const size_t OFF_DST  = OFF_EFS  + (size_t)NE * 8 * 2;      // +16 MB
    const size_t OFF_OFFS = OFF_DST  + (size_t)NE * 4;          // +4 MB
    const size_t OFF_DEG  = OFF_OFFS + 262400;
    const size_t OFF_CUR  = OFF_DEG  + 262144;
    const size_t OFF_PMAX = OFF_CUR  + 262144;
    const size_t NEED     = OFF_PMAX + 2048;

    if (ws_size >= NEED) {
        __bf16*       xA   = (__bf16*)(ws + OFF_XA);
        __bf16*       xB   = (__bf16*)(ws + OFF_XB);
        __bf16*       St2  = (__bf16*)(ws + OFF_ST);
        __bf16*       efs  = (__bf16*)(ws + OFF_EFS);
        int*          dsts = (int*)   (ws + OFF_DST);
        int*          offs = (int*)   (ws + OFF_OFFS);
        int*          deg  = (int*)   (ws + OFF_DEG);
        int*          cur  = (int*)   (ws + OFF_CUR);
        unsigned int* pmax = (unsigned int*)(ws + OFF_PMAX);

        hipMemsetAsync(pmax, 0, 384 * sizeof(unsigned int), stream);
        hipMemsetAsync(deg, 0, NCH * sizeof(int), stream);

        k_child  <<<1024, 256, 0, stream>>>(cf, ex, Wc, bc, xA, pmax);
        k_hist   <<<4096, 256, 0, stream>>>(eidx, deg);
        k_scan   <<<1,   1024, 0, stream>>>(deg, offs, cur);
        k_scatter<<<4096, 256, 0, stream>>>(eidx, cur, ef, dsts, efs);

        k_src    <<<1024, 256, 0, stream>>>(xA, We, be, St2);              // xA -> D in place
        k_edge2  <<<4096, 256, 0, stream>>>(xA, offs, dsts, efs, St2, We, xB, pmax, 1);
        k_src    <<<1024, 256, 0, stream>>>(xB, We + 264 * HID, be + HID, St2);
        k_edge2  <<<4096, 256, 0, stream>>>(xB, offs, dsts, efs, St2, We + 264 * HID, xA, pmax, 2);
        k_parent <<<1,    128, 0, stream>>>(pmax, Wp, bp, out);
    } else {
        // fallback: R1 atomic path (48 MB)
        float*        xNew = (float*)ws;
        __bf16*       xA   = (__bf16*)(ws + (size_t)NCH * HID * 4);
        unsigned int* pmax = (unsigned int*)(ws + (size_t)NCH * HID * 6);

        hipMemsetAsync(pmax, 0, 384 * sizeof(unsigned int), stream);
        hipMemsetAsync(xNew, 0, (size_t)NCH * HID * 4, stream);

        k_child  <<<1024, 256, 0, stream>>>(cf, ex, Wc, bc, xA, pmax);
        k_edge_at<<<2048, 256, 0, stream>>>(xA, eidx, ef, We,             be,       xNew);
        k_fin    <<<512,  256, 0, stream>>>(xNew, xA, pmax, 1, 3);
        k_edge_at<<<2048, 256, 0, stream>>>(xA, eidx, ef, We + 264 * HID, be + HID, xNew);
        k_fin    <<<512,  256, 0, stream>>>(xNew, xA, pmax, 2, 0);
        k_parent <<<1,    128, 0, stream>>>(pmax, Wp, bp, out);
    }
}

// Round 5
// 570.904 us; speedup vs baseline: 1.6634x; 1.0705x over previous
//
#include <hip/hip_runtime.h>
#include <hip/hip_bf16.h>

#define HID 128
#define DIN 192      // N_FEAT + NUM_SEM
#define NCH 65536
#define NE  1048576

typedef __bf16 bfrag __attribute__((ext_vector_type(8)));
typedef float  ffrag __attribute__((ext_vector_type(4)));

static __device__ __forceinline__ __bf16 f2bf(float x) { return (__bf16)x; }
static __device__ __forceinline__ unsigned pk2(float a, float b) {
    __bf16 b0 = f2bf(a), b1 = f2bf(b);
    return (unsigned)*(unsigned short*)&b0 | ((unsigned)*(unsigned short*)&b1 << 16);
}

struct Frags { bfrag a[5]; };

// ---------------------------------------------------------------------------
// R6: child encoder FUSED with edge histogram.  Blocks 0..1023: child GEMM
// (xA = bf16(relu(cf@Wc+bc)*exists), col-max into pmax).  Blocks 1024..2047:
// histogram of edge sources (4 edges/thread, coalesced eidx reads).
// ---------------------------------------------------------------------------
__global__ __launch_bounds__(256) void k_childhist(
    const float* __restrict__ cf, const float* __restrict__ exists,
    const float* __restrict__ Wc, const float* __restrict__ bc,
    __bf16* __restrict__ xA, unsigned int* __restrict__ pmax,
    const int* __restrict__ eidx, int* __restrict__ deg)
{
    if (blockIdx.x >= 1024) {
        const int base = (blockIdx.x - 1024) * 1024 + threadIdx.x;
        #pragma unroll
        for (int k = 0; k < 4; ++k)
            atomicAdd(&deg[eidx[2 * (base + k * 256)]], 1);
        return;
    }

    __shared__ __bf16 Wl[6 * 8 * 64 * 8];   // 48 KB, B-fragment-swizzled
    __shared__ float  bl[HID];
    __shared__ unsigned int cm[HID];
    const int t = threadIdx.x;

    for (int idx = t; idx < DIN * HID; idx += 256) {
        int k = idx >> 7, h = idx & 127;
        int kt = k >> 5, kk = k & 31;
        int lane = ((kk >> 3) << 4) | (h & 15);
        Wl[((((kt * 8) + (h >> 4)) * 64 + lane) << 3) | (kk & 7)] = f2bf(Wc[idx]);
    }
    for (int idx = t; idx < HID; idx += 256) { bl[idx] = bc[idx]; cm[idx] = 0u; }
    __syncthreads();

    const int wave = t >> 6, lane = t & 63;
    const int m = lane & 15, quad = lane >> 4;

    const int tile = blockIdx.x * 4 + wave;   // 1024 blocks -> 4096 tiles
    const int r0 = tile << 4;
    const int row = r0 + m;

    ffrag acc[8];
    #pragma unroll
    for (int u = 0; u < 8; ++u)
        #pragma unroll
        for (int r = 0; r < 4; ++r) acc[u][r] = 0.f;

    const float* arow = cf + (size_t)row * DIN + quad * 8;
    #pragma unroll
    for (int kt = 0; kt < 6; ++kt) {
        float4 f0 = *(const float4*)(arow + kt * 32);
        float4 f1 = *(const float4*)(arow + kt * 32 + 4);
        bfrag a;
        a[0]=f2bf(f0.x); a[1]=f2bf(f0.y); a[2]=f2bf(f0.z); a[3]=f2bf(f0.w);
        a[4]=f2bf(f1.x); a[5]=f2bf(f1.y); a[6]=f2bf(f1.z); a[7]=f2bf(f1.w);
        #pragma unroll
        for (int u = 0; u < 8; ++u) {
            bfrag b = *(const bfrag*)(&Wl[(((kt * 8 + u) * 64 + lane) << 3)]);
            acc[u] = __builtin_amdgcn_mfma_f32_16x16x32_bf16(a, b, acc[u], 0, 0, 0);
        }
    }

    float mxu[8];
    #pragma unroll
    for (int u = 0; u < 8; ++u) mxu[u] = 0.f;

    #pragma unroll
    for (int r = 0; r < 4; ++r) {
        int er = r0 + quad * 4 + r;
        float exv = exists[er];
        __bf16* orow = xA + (size_t)er * HID;
        #pragma unroll
        for (int u = 0; u < 8; ++u) {
            int col = u * 16 + m;
            float v = fmaxf(acc[u][r] + bl[col], 0.f) * exv;
            orow[col] = f2bf(v);
            mxu[u] = fmaxf(mxu[u], v);
        }
    }
    #pragma unroll
    for (int u = 0; u < 8; ++u) {
        float v = mxu[u];
        v = fmaxf(v, __shfl_xor(v, 16));
        v = fmaxf(v, __shfl_xor(v, 32));
        if (quad == 0) atomicMax(&cm[u * 16 + m], __float_as_uint(v));
    }
    __syncthreads();
    if (t < HID) atomicMax(&pmax[t], cm[t]);
}

// ---------------------------------------------------------------------------
// R6: parallel coalesced 3-phase scan (replaces single-block k_scan whose
// wave-loads were 64-way uncoalesced on ONE CU).
// ---------------------------------------------------------------------------
__global__ __launch_bounds__(256) void k_scan1(
    const int* __restrict__ deg, int* __restrict__ bsum)
{
    const int b = blockIdx.x, t = threadIdx.x;
    int v = deg[b * 256 + t];
    #pragma unroll
    for (int o = 1; o < 64; o <<= 1) v += __shfl_xor(v, o);
    __shared__ int ws[4];
    if ((t & 63) == 0) ws[t >> 6] = v;
    __syncthreads();
    if (t == 0) bsum[b] = ws[0] + ws[1] + ws[2] + ws[3];
}

__global__ __launch_bounds__(256) void k_scan2(
    const int* __restrict__ bsum, int* __restrict__ bbase)
{
    __shared__ int sc[256];
    const int t = threadIdx.x;
    int v = bsum[t];
    sc[t] = v;
    __syncthreads();
    for (int o = 1; o < 256; o <<= 1) {
        int u = (t >= o) ? sc[t - o] : 0;
        __syncthreads();
        sc[t] += u;
        __syncthreads();
    }
    bbase[t] = sc[t] - v;   // exclusive
}

__global__ __launch_bounds__(256) void k_scan3(
    const int* __restrict__ deg, const int* __restrict__ bbase,
    int* __restrict__ off, int* __restrict__ cursor)
{
    __shared__ int sc[256];
    const int b = blockIdx.x, t = threadIdx.x;
    int v = deg[b * 256 + t];
    sc[t] = v;
    __syncthreads();
    for (int o = 1; o < 256; o <<= 1) {
        int u = (t >= o) ? sc[t - o] : 0;
        __syncthreads();
        sc[t] += u;
        __syncthreads();
    }
    int excl = bbase[b] + sc[t] - v;
    off[b * 256 + t] = excl;
    cursor[b * 256 + t] = excl;
    if (b == 255 && t == 255) off[NCH] = excl + v;
}

// Scatter fused with dst/ef gather: coalesced ef read, scattered 16B/4B writes.
__global__ __launch_bounds__(256) void k_scatter(
    const int* __restrict__ eidx, int* __restrict__ cursor,
    const float* __restrict__ ef,
    int* __restrict__ dsts, __bf16* __restrict__ efs)
{
    int e = blockIdx.x * 256 + threadIdx.x;
    int s = eidx[2 * e], d = eidx[2 * e + 1];
    const float4* p = (const float4*)(ef + (size_t)e * 8);
    float4 f0 = p[0], f1 = p[1];
    int pos = atomicAdd(&cursor[s], 1);
    dsts[pos] = d;
    uint4 pk;
    pk.x = pk2(f0.x, f0.y); pk.y = pk2(f0.z, f0.w);
    pk.z = pk2(f1.x, f1.y); pk.w = pk2(f1.z, f1.w);
    *(uint4*)(efs + (size_t)pos * 8) = pk;
}

// ---------------------------------------------------------------------------
// k_src computes BOTH per-node projections from x:
//   St2[n]  = bf16( x[n] @ We[0:128]   + be )   (frag-ordered)
//   D[n]    = bf16( x[n] @ We[128:256] )        (row-major, IN-PLACE over x)
// ---------------------------------------------------------------------------
__global__ __launch_bounds__(256) void k_src(
    __bf16* __restrict__ xCur, const float* __restrict__ We,
    const float* __restrict__ be, __bf16* __restrict__ St2)
{
    __shared__ __bf16 Wl[4 * 8 * 64 * 8];   // 32 KB, reused for src then dst
    __shared__ float  bl[HID];
    const int t = threadIdx.x;
    const int wave = t >> 6, lane = t & 63;
    const int m = lane & 15, quad = lane >> 4;
    const int tile = blockIdx.x * 4 + wave;   // grid 1024 -> 4096 tiles
    const int r0 = tile << 4;
    const int row = r0 + m;

    // ---- phase 1: W_src ----
    for (int idx = t; idx < 128 * HID; idx += 256) {
        int k = idx >> 7, h = idx & 127;
        int kt = k >> 5, kk = k & 31;
        int ln = ((kk >> 3) << 4) | (h & 15);
        Wl[((((kt * 8) + (h >> 4)) * 64 + ln) << 3) | (kk & 7)] = f2bf(We[idx]);
    }
    for (int idx = t; idx < HID; idx += 256) bl[idx] = be[idx];
    __syncthreads();

    // A-frags loaded once, reused for both projections
    bfrag a[4];
    const __bf16* ar = xCur + (size_t)row * HID + quad * 8;
    #pragma unroll
    for (int kt = 0; kt < 4; ++kt) a[kt] = *(const bfrag*)(ar + kt * 32);

    ffrag acc[8];
    #pragma unroll
    for (int u = 0; u < 8; ++u)
        #pragma unroll
        for (int r = 0; r < 4; ++r) acc[u][r] = 0.f;

    #pragma unroll
    for (int kt = 0; kt < 4; ++kt)
        #pragma unroll
        for (int u = 0; u < 8; ++u) {
            bfrag b = *(const bfrag*)(&Wl[(((kt * 8 + u) * 64 + lane) << 3)]);
            acc[u] = __builtin_amdgcn_mfma_f32_16x16x32_bf16(a[kt], b, acc[u], 0, 0, 0);
        }
    #pragma unroll
    for (int r = 0; r < 4; ++r) {
        int node = r0 + quad * 4 + r;
        bfrag pk;
        #pragma unroll
        for (int u = 0; u < 8; ++u) pk[u] = f2bf(acc[u][r] + bl[u * 16 + m]);
        *(bfrag*)(St2 + ((size_t)node * 16 + m) * 8) = pk;   // 16B coalesced
    }
    __syncthreads();   // all waves done reading Wl(src)

    // ---- phase 2: W_dst (rows 128..255), reuse LDS ----
    for (int idx = t; idx < 128 * HID; idx += 256) {
        int k = idx >> 7, h = idx & 127;
        int kt = k >> 5, kk = k & 31;
        int ln = ((kk >> 3) << 4) | (h & 15);
        Wl[((((kt * 8) + (h >> 4)) * 64 + ln) << 3) | (kk & 7)] = f2bf(We[(size_t)(128 + k) * HID + h]);
    }
    __syncthreads();

    #pragma unroll
    for (int u = 0; u < 8; ++u)
        #pragma unroll
        for (int r = 0; r < 4; ++r) acc[u][r] = 0.f;

    #pragma unroll
    for (int kt = 0; kt < 4; ++kt)
        #pragma unroll
        for (int u = 0; u < 8; ++u) {
            bfrag b = *(const bfrag*)(&Wl[(((kt * 8 + u) * 64 + lane) << 3)]);
            acc[u] = __builtin_amdgcn_mfma_f32_16x16x32_bf16(a[kt], b, acc[u], 0, 0, 0);
        }
    // D written row-major, in place, NO bias (bias lives in St2)
    #pragma unroll
    for (int r = 0; r < 4; ++r) {
        int node = r0 + quad * 4 + r;
        __bf16* orow = xCur + (size_t)node * HID;
        #pragma unroll
        for (int u = 0; u < 8; ++u) orow[u * 16 + m] = f2bf(acc[u][r]);
    }
}

// ---------------------------------------------------------------------------
// Fused edge pass + segment_sum + col-max (R4 form: 1-deep prefetch; R5's
// 2-deep pipeline was a measured null — gather path is TCP-miss-queue
// throughput-limited, not wave-latency-limited).
// ---------------------------------------------------------------------------
__global__ __launch_bounds__(256) void k_edge2(
    const __bf16* __restrict__ xCur,   // = D rows
    const int*    __restrict__ offs,
    const int*    __restrict__ dsts,
    const __bf16* __restrict__ efs,
    const __bf16* __restrict__ St2,
    const float*  __restrict__ We,    // 264x128 slice; rows 256..263 used
    __bf16* __restrict__ xNext,
    unsigned int* __restrict__ pmax, int stage)
{
    __shared__ __bf16 Wl[8 * 16 * 8];   // 2 KB: compact ef weight block
    __shared__ unsigned int cm[HID];
    const int t = threadIdx.x;

    if (t < HID) cm[t] = 0u;
    // ef rows 256..263, compact: [u][ln<16][j]  (2 KB)
    for (int idx = t; idx < 8 * HID; idx += 256) {
        int k2 = idx >> 7, h = idx & 127;
        Wl[((((h >> 4) * 16) + (h & 15)) << 3) + k2] = f2bf(We[(size_t)(256 + k2) * HID + h]);
    }
    __syncthreads();

    const int wave = t >> 6, lane = t & 63;
    const int m = lane & 15, quad = lane >> 4;
    const int gw = blockIdx.x * 4 + wave;    // grid 4096 -> 16384 waves
    const int n0 = gw * 4;                   // 4 nodes per wave, consecutive
    const int lc16 = (lane & 15) << 3;       // compact ef read offset

    // constant identity B-fragments: B[k][c] = (k==c) one-hot per col block.
    bfrag Bev, Bod;
    #pragma unroll
    for (int j = 0; j < 8; ++j) {
        Bev[j] = (quad == (m >> 3)     && j == (m & 7)) ? (__bf16)1.f : (__bf16)0.f;
        Bod[j] = (quad == 2 + (m >> 3) && j == (m & 7)) ? (__bf16)1.f : (__bf16)0.f;
    }

    const int o0 = offs[n0],     o1 = offs[n0 + 1], o2 = offs[n0 + 2];
    const int o3 = offs[n0 + 3], o4 = offs[n0 + 4];

    auto selo = [&](int q) -> int {
        return (q <= 0) ? o0 : (q == 1) ? o1 : (q == 2) ? o2 : (q == 3) ? o3 : o4;
    };

    float mxu[8];
    #pragma unroll
    for (int u = 0; u < 8; ++u) mxu[u] = 0.f;

    if (o0 < o4) {
        const int dvA = dsts[min(o0 + lane, o4 - 1)];
        const int dvB = dsts[min(o0 + 64 + lane, o4 - 1)];

        auto LOADT = [&](int j) -> Frags {
            Frags f;
            int jl = j + m; jl = (jl < o4) ? jl : (o4 - 1);
            int rel = jl - o0;
            int dA = __shfl(dvA, rel & 63);
            int dB = __shfl(dvB, rel & 63);
            int dm;
            if (rel < 64)       dm = dA;
            else if (rel < 128) dm = dB;
            else                dm = dsts[jl];      // ultra-rare fallback
            const __bf16* rd = xCur + (size_t)dm * HID + quad * 8;
            f.a[0] = *(const bfrag*)(rd);
            f.a[1] = *(const bfrag*)(rd + 32);
            f.a[2] = *(const bfrag*)(rd + 64);
            f.a[3] = *(const bfrag*)(rd + 96);
            bfrag z;
            #pragma unroll
            for (int q = 0; q < 8; ++q) z[q] = (__bf16)0.f;
            if (quad == 0) z = *(const bfrag*)(efs + (size_t)jl * 8);
            f.a[4] = z;
            return f;
        };

        int ci = 0;
        while (selo(ci) == selo(ci + 1)) ++ci;   // first non-empty node (exists)
        int cj = selo(ci);

        bfrag sb = *(const bfrag*)(St2 + ((size_t)(n0 + ci) * 16 + m) * 8);
        float part[8];
        #pragma unroll
        for (int u = 0; u < 8; ++u) part[u] = 0.f;

        Frags aC = LOADT(cj);

        for (;;) {
            const int cEnd = selo(ci + 1);
            int ni = ci, nj = cj + 16;
            if (nj >= cEnd) {
                ni = ci + 1;
                while (ni < 4 && selo(ni) == selo(ni + 1)) ++ni;
                nj = (ni < 4) ? selo(ni) : 0;
            }
            const bool hn = (ni < 4);
            Frags aN;
            if (hn) aN = LOADT(nj);             // prefetch next tile

            ffrag acc[8];
            #pragma unroll
            for (int u = 0; u < 8; ++u) {
                float s = (float)sb[u];
                acc[u][0] = s; acc[u][1] = s; acc[u][2] = s; acc[u][3] = s;
            }
            // identity transpose: acc[u] += D-rows into C-layout
            #pragma unroll
            for (int u = 0; u < 8; ++u)
                acc[u] = __builtin_amdgcn_mfma_f32_16x16x32_bf16(
                    aC.a[u >> 1], (u & 1) ? Bod : Bev, acc[u], 0, 0, 0);
            // ef projection
            #pragma unroll
            for (int u = 0; u < 8; ++u) {
                bfrag b = *(const bfrag*)(&Wl[(u << 7) + lc16]);
                acc[u] = __builtin_amdgcn_mfma_f32_16x16x32_bf16(aC.a[4], b, acc[u], 0, 0, 0);
            }

            const int rb = cj + quad * 4;
            #pragma unroll
            for (int r = 0; r < 4; ++r) {
                if (rb + r < cEnd) {
                    #pragma unroll
                    for (int u = 0; u < 8; ++u)
                        part[u] += fmaxf(acc[u][r], 0.f);
                }
            }

            if (!hn || ni != ci) {
                float tot[8];
                #pragma unroll
                for (int u = 0; u < 8; ++u) {
                    float v = part[u];
                    v += __shfl_xor(v, 16);
                    v += __shfl_xor(v, 32);
                    tot[u] = v;
                    mxu[u] = fmaxf(mxu[u], v);
                }
                // static-index selection of this quad's 2 columns (no scratch)
                float sA = (quad == 0) ? tot[0] : (quad == 1) ? tot[2] : (quad == 2) ? tot[4] : tot[6];
                float sB = (quad == 0) ? tot[1] : (quad == 1) ? tot[3] : (quad == 2) ? tot[5] : tot[7];
                const int n = n0 + ci, u0 = quad * 2;
                xNext[(size_t)n * HID + u0 * 16 + m]      = f2bf(sA);
                xNext[(size_t)n * HID + u0 * 16 + 16 + m] = f2bf(sB);
                if (hn) {
                    sb = *(const bfrag*)(St2 + ((size_t)(n0 + ni) * 16 + m) * 8);
                    #pragma unroll
                    for (int u = 0; u < 8; ++u) part[u] = 0.f;
                }
            }
            if (!hn) break;
            aC = aN; ci = ni; cj = nj;
        }
    }

    // zero rows for empty nodes
    {
        const int u0 = quad * 2;
        const __bf16 zz = (__bf16)0.f;
        if (o0 == o1) { xNext[(size_t)(n0+0)*HID + u0*16 + m] = zz; xNext[(size_t)(n0+0)*HID + u0*16 + 16 + m] = zz; }
        if (o1 == o2) { xNext[(size_t)(n0+1)*HID + u0*16 + m] = zz; xNext[(size_t)(n0+1)*HID + u0*16 + 16 + m] = zz; }
        if (o2 == o3) { xNext[(size_t)(n0+2)*HID + u0*16 + m] = zz; xNext[(size_t)(n0+2)*HID + u0*16 + 16 + m] = zz; }
        if (o3 == o4) { xNext[(size_t)(n0+3)*HID + u0*16 + m] = zz; xNext[(size_t)(n0+3)*HID + u0*16 + 16 + m] = zz; }
    }

    #pragma unroll
    for (int u = 0; u < 8; ++u) {
        float v = mxu[u];
        v = fmaxf(v, __shfl_xor(v, 16));
        v = fmaxf(v, __shfl_xor(v, 32));
        if (quad == 0) atomicMax(&cm[u * 16 + m], __float_as_uint(v));
    }
    __syncthreads();
    if (t < HID) atomicMax(&pmax[stage * HID + t], cm[t]);
}

// ---------------------------------------------------------------------------
// Fallback path kernels (R1-proven, 48 MB footprint)
// ---------------------------------------------------------------------------
__global__ __launch_bounds__(256) void k_edge_at(
    const __bf16* __restrict__ xA, const int* __restrict__ eidx,
    const float* __restrict__ ef, const float* __restrict__ We,
    const float* __restrict__ be, float* __restrict__ xNew)
{
    __shared__ __bf16 Wl[9 * 8 * 64 * 8];
    __shared__ float  bl[HID];
    const int t = threadIdx.x;
    for (int idx = t; idx < 8 * 64 * 8; idx += 256) Wl[8 * 8 * 64 * 8 + idx] = (__bf16)0.f;
    __syncthreads();
    for (int idx = t; idx < 256 * HID; idx += 256) {
        int k = idx >> 7, h = idx & 127;
        int kt = k >> 5, kk = k & 31;
        int lane = ((kk >> 3) << 4) | (h & 15);
        Wl[((((kt * 8) + (h >> 4)) * 64 + lane) << 3) | (kk & 7)] = f2bf(We[idx]);
    }
    for (int idx = t; idx < 8 * HID; idx += 256) {
        int k2 = idx >> 7, h = idx & 127;
        Wl[((((8 * 8) + (h >> 4)) * 64 + (h & 15)) << 3) | k2] = f2bf(We[(256 + k2) * HID + h]);
    }
    for (int idx = t; idx < HID; idx += 256) bl[idx] = be[idx];
    __syncthreads();

    const int wave = t >> 6, lane = t & 63;
    const int m = lane & 15, quad = lane >> 4;
    for (int c = 0; c < 8; ++c) {
        const int e0 = blockIdx.x * 512 + c * 64 + wave * 16;
        const int e  = e0 + m;
        const int src = eidx[2 * e], dst = eidx[2 * e + 1];
        const __bf16* rs = xA + (size_t)src * HID;
        const __bf16* rd = xA + (size_t)dst * HID;
        bfrag a[9];
        #pragma unroll
        for (int kt = 0; kt < 4; ++kt) a[kt] = *(const bfrag*)(rs + kt * 32 + quad * 8);
        #pragma unroll
        for (int kt = 4; kt < 8; ++kt) a[kt] = *(const bfrag*)(rd + (kt - 4) * 32 + quad * 8);
        {
            bfrag z;
            #pragma unroll
            for (int q = 0; q < 8; ++q) z[q] = (__bf16)0.f;
            if (quad == 0) {
                const float4* p = (const float4*)(ef + (size_t)e * 8);
                float4 f0 = p[0], f1 = p[1];
                z[0]=f2bf(f0.x); z[1]=f2bf(f0.y); z[2]=f2bf(f0.z); z[3]=f2bf(f0.w);
                z[4]=f2bf(f1.x); z[5]=f2bf(f1.y); z[6]=f2bf(f1.z); z[7]=f2bf(f1.w);
            }
            a[8] = z;
        }
        ffrag acc[8];
        #pragma unroll
        for (int u = 0; u < 8; ++u)
            #pragma unroll
            for (int r = 0; r < 4; ++r) acc[u][r] = 0.f;
        #pragma unroll
        for (int kt = 0; kt < 9; ++kt)
            #pragma unroll
            for (int u = 0; u < 8; ++u) {
                bfrag b = *(const bfrag*)(&Wl[(((kt * 8 + u) * 64 + lane) << 3)]);
                acc[u] = __builtin_amdgcn_mfma_f32_16x16x32_bf16(a[kt], b, acc[u], 0, 0, 0);
            }
        #pragma unroll
        for (int r = 0; r < 4; ++r) {
            int er = e0 + quad * 4 + r;
            int sr = eidx[2 * er];
            float* outrow = xNew + (size_t)sr * HID;
            #pragma unroll
            for (int u = 0; u < 8; ++u) {
                int col = u * 16 + m;
                atomicAdd(outrow + col, fmaxf(acc[u][r] + bl[col], 0.f));
            }
        }
    }
}

__global__ __launch_bounds__(256) void k_fin(
    float* __restrict__ xNew, __bf16* __restrict__ xA,
    unsigned int* __restrict__ pmax, int stage, int flags)
{
    const int t = threadIdx.x;
    const size_t total  = (size_t)NCH * HID;
    const size_t stride = (size_t)gridDim.x * 256;
    float mx = 0.f;
    for (size_t i = (size_t)blockIdx.x * 256 + t; i < total; i += stride) {
        float v = xNew[i];
        mx = fmaxf(mx, v);
        if (flags & 1) xA[i] = f2bf(v);
        if (flags & 2) xNew[i] = 0.f;
    }
    __shared__ float red[256];
    red[t] = mx;
    __syncthreads();
    if (t < 128) {
        float v = fmaxf(red[t], red[t + 128]);
        atomicMax(&pmax[stage * HID + t], __float_as_uint(v));
    }
}

// ---------------------------------------------------------------------------
// Parent head: out = relu(pmax(384) @ Wp + bp)
// ---------------------------------------------------------------------------
__global__ __launch_bounds__(128) void k_parent(
    const unsigned int* __restrict__ pmaxU,
    const float* __restrict__ Wp, const float* __restrict__ bp,
    float* __restrict__ out)
{
    __shared__ float pl[384];
    const int t = threadIdx.x;
    for (int i = t; i < 384; i += 128) pl[i] = __uint_as_float(pmaxU[i]);
    __syncthreads();
    float acc = bp[t];
    for (int j = 0; j < 384; ++j) acc += pl[j] * Wp[j * HID + t];
    out[t] = fmaxf(acc, 0.f);
}

extern "C" void kernel_launch(void* const* d_in, const int* in_sizes, int n_in,
                              void* d_out, int out_size, void* d_ws, size_t ws_size,
                              hipStream_t stream)
{
    const float* cf   = (const float*)d_in[0];
    const float* ex   = (const float*)d_in[1];
    const float* ef   = (const float*)d_in[2];
    const int*   eidx = (const int*)d_in[3];
    const float* Wc   = (const float*)d_in[4];
    const float* bc   = (const float*)d_in[5];
    const float* We   = (const float*)d_in[6];
    const float* be   = (const float*)d_in[7];
    const float* Wp   = (const float*)d_in[8];
    const float* bp   = (const float*)d_in[9];
    float* out = (float*)d_out;

    char* ws = (char*)d_ws;

    // CSR-fused path layout (~69 MB)
    const size_t OFF_XA   = 0;
    const size_t OFF_XB   = OFF_XA   + (size_t)NCH * HID * 2;   // +16 MB
    const size_t OFF_ST   = OFF_XB   + (size_t)NCH * HID * 2;   // +16 MB
    const size_t OFF_EFS  = OFF_ST   + (size_t)NCH * HID * 2;   // +16 MB
    const size_t OFF_DST  = OFF_EFS  + (size_t)NE * 8 * 2;      // +16 MB
    const size_t OFF_OFFS = OFF_DST  + (size_t)NE * 4;          // +4 MB
    const size_t OFF_DEG  = OFF_OFFS + 262400;
    const size_t OFF_CUR  = OFF_DEG  + 262144;
    const size_t OFF_PMAX = OFF_CUR  + 262144;
    const size_t OFF_BS   = OFF_PMAX + 2048;     // bsum[256]
    const size_t OFF_BB   = OFF_BS   + 1024;     // bbase[256]
    const size_t NEED     = OFF_BB   + 1024;

    if (ws_size >= NEED) {
        __bf16*       xA   = (__bf16*)(ws + OFF_XA);
        __bf16*       xB   = (__bf16*)(ws + OFF_XB);
        __bf16*       St2  = (__bf16*)(ws + OFF_ST);
        __bf16*       efs  = (__bf16*)(ws + OFF_EFS);
        int*          dsts = (int*)   (ws + OFF_DST);
        int*          offs = (int*)   (ws + OFF_OFFS);
        int*          deg  = (int*)   (ws + OFF_DEG);
        int*          cur  = (int*)   (ws + OFF_CUR);
        unsigned int* pmax = (unsigned int*)(ws + OFF_PMAX);
        int*          bsum = (int*)   (ws + OFF_BS);
        int*          bbas = (int*)   (ws + OFF_BB);

        hipMemsetAsync(pmax, 0, 384 * sizeof(unsigned int), stream);
        hipMemsetAsync(deg, 0, NCH * sizeof(int), stream);

        k_childhist<<<2048, 256, 0, stream>>>(cf, ex, Wc, bc, xA, pmax, eidx, deg);
        k_scan1  <<<256,  256, 0, stream>>>(deg, bsum);
        k_scan2  <<<1,    256, 0, stream>>>(bsum, bbas);
        k_scan3  <<<256,  256, 0, stream>>>(deg, bbas, offs, cur);
        k_scatter<<<4096, 256, 0, stream>>>(eidx, cur, ef, dsts, efs);

        k_src    <<<1024, 256, 0, stream>>>(xA, We, be, St2);              // xA -> D in place
        k_edge2  <<<4096, 256, 0, stream>>>(xA, offs, dsts, efs, St2, We, xB, pmax, 1);
        k_src    <<<1024, 256, 0, stream>>>(xB, We + 264 * HID, be + HID, St2);
        k_edge2  <<<4096, 256, 0, stream>>>(xB, offs, dsts, efs, St2, We + 264 * HID, xA, pmax, 2);
        k_parent <<<1,    128, 0, stream>>>(pmax, Wp, bp, out);
    } else {
        // fallback: R1 atomic path (48 MB)
        float*        xNew = (float*)ws;
        __bf16*       xA   = (__bf16*)(ws + (size_t)NCH * HID * 4);
        unsigned int* pmax = (unsigned int*)(ws + (size_t)NCH * HID * 6);

        hipMemsetAsync(pmax, 0, 384 * sizeof(unsigned int), stream);
        hipMemsetAsync(xNew, 0, (size_t)NCH * HID * 4, stream);

        k_childhist<<<1024, 256, 0, stream>>>(cf, ex, Wc, bc, xA, pmax, eidx, (int*)nullptr);
        k_edge_at<<<2048, 256, 0, stream>>>(xA, eidx, ef, We,             be,       xNew);
        k_fin    <<<512,  256, 0, stream>>>(xNew, xA, pmax, 1, 3);
        k_edge_at<<<2048, 256, 0, stream>>>(xA, eidx, ef, We + 264 * HID, be + HID, xNew);
        k_fin    <<<512,  256, 0, stream>>>(xNew, xA, pmax, 2, 0);
        k_parent <<<1,    128, 0, stream>>>(pmax, Wp, bp, out);
    }
}

// Round 6
// 538.634 us; speedup vs baseline: 1.7631x; 1.0599x over previous
//
#include <hip/hip_runtime.h>
#include <hip/hip_bf16.h>

#define HID 128
#define DIN 192      // N_FEAT + NUM_SEM
#define NCH 65536
#define NE  1048576

typedef __bf16 bfrag __attribute__((ext_vector_type(8)));
typedef float  ffrag __attribute__((ext_vector_type(4)));

static __device__ __forceinline__ __bf16 f2bf(float x) { return (__bf16)x; }
static __device__ __forceinline__ unsigned pk2(float a, float b) {
    __bf16 b0 = f2bf(a), b1 = f2bf(b);
    return (unsigned)*(unsigned short*)&b0 | ((unsigned)*(unsigned short*)&b1 << 16);
}
// f32 -> OCP e4m3 byte (gfx950 hw cvt)
static __device__ __forceinline__ unsigned char f2q(float x) {
    return (unsigned char)(__builtin_amdgcn_cvt_pk_fp8_f32(x, x, 0, false) & 0xff);
}

struct FragsQ { long d[4]; long ef; };

// ---------------------------------------------------------------------------
// Child encoder FUSED with edge histogram (R6).
// ---------------------------------------------------------------------------
__global__ __launch_bounds__(256) void k_childhist(
    const float* __restrict__ cf, const float* __restrict__ exists,
    const float* __restrict__ Wc, const float* __restrict__ bc,
    __bf16* __restrict__ xA, unsigned int* __restrict__ pmax,
    const int* __restrict__ eidx, int* __restrict__ deg)
{
    if (blockIdx.x >= 1024) {
        const int base = (blockIdx.x - 1024) * 1024 + threadIdx.x;
        #pragma unroll
        for (int k = 0; k < 4; ++k)
            atomicAdd(&deg[eidx[2 * (base + k * 256)]], 1);
        return;
    }

    __shared__ __bf16 Wl[6 * 8 * 64 * 8];   // 48 KB, B-fragment-swizzled
    __shared__ float  bl[HID];
    __shared__ unsigned int cm[HID];
    const int t = threadIdx.x;

    for (int idx = t; idx < DIN * HID; idx += 256) {
        int k = idx >> 7, h = idx & 127;
        int kt = k >> 5, kk = k & 31;
        int lane = ((kk >> 3) << 4) | (h & 15);
        Wl[((((kt * 8) + (h >> 4)) * 64 + lane) << 3) | (kk & 7)] = f2bf(Wc[idx]);
    }
    for (int idx = t; idx < HID; idx += 256) { bl[idx] = bc[idx]; cm[idx] = 0u; }
    __syncthreads();

    const int wave = t >> 6, lane = t & 63;
    const int m = lane & 15, quad = lane >> 4;

    const int tile = blockIdx.x * 4 + wave;   // 1024 blocks -> 4096 tiles
    const int r0 = tile << 4;
    const int row = r0 + m;

    ffrag acc[8];
    #pragma unroll
    for (int u = 0; u < 8; ++u)
        #pragma unroll
        for (int r = 0; r < 4; ++r) acc[u][r] = 0.f;

    const float* arow = cf + (size_t)row * DIN + quad * 8;
    #pragma unroll
    for (int kt = 0; kt < 6; ++kt) {
        float4 f0 = *(const float4*)(arow + kt * 32);
        float4 f1 = *(const float4*)(arow + kt * 32 + 4);
        bfrag a;
        a[0]=f2bf(f0.x); a[1]=f2bf(f0.y); a[2]=f2bf(f0.z); a[3]=f2bf(f0.w);
        a[4]=f2bf(f1.x); a[5]=f2bf(f1.y); a[6]=f2bf(f1.z); a[7]=f2bf(f1.w);
        #pragma unroll
        for (int u = 0; u < 8; ++u) {
            bfrag b = *(const bfrag*)(&Wl[(((kt * 8 + u) * 64 + lane) << 3)]);
            acc[u] = __builtin_amdgcn_mfma_f32_16x16x32_bf16(a, b, acc[u], 0, 0, 0);
        }
    }

    float mxu[8];
    #pragma unroll
    for (int u = 0; u < 8; ++u) mxu[u] = 0.f;

    #pragma unroll
    for (int r = 0; r < 4; ++r) {
        int er = r0 + quad * 4 + r;
        float exv = exists[er];
        __bf16* orow = xA + (size_t)er * HID;
        #pragma unroll
        for (int u = 0; u < 8; ++u) {
            int col = u * 16 + m;
            float v = fmaxf(acc[u][r] + bl[col], 0.f) * exv;
            orow[col] = f2bf(v);
            mxu[u] = fmaxf(mxu[u], v);
        }
    }
    #pragma unroll
    for (int u = 0; u < 8; ++u) {
        float v = mxu[u];
        v = fmaxf(v, __shfl_xor(v, 16));
        v = fmaxf(v, __shfl_xor(v, 32));
        if (quad == 0) atomicMax(&cm[u * 16 + m], __float_as_uint(v));
    }
    __syncthreads();
    if (t < HID) atomicMax(&pmax[t], cm[t]);
}

// ---------------------------------------------------------------------------
// Parallel coalesced 3-phase scan (R6).
// ---------------------------------------------------------------------------
__global__ __launch_bounds__(256) void k_scan1(
    const int* __restrict__ deg, int* __restrict__ bsum)
{
    const int b = blockIdx.x, t = threadIdx.x;
    int v = deg[b * 256 + t];
    #pragma unroll
    for (int o = 1; o < 64; o <<= 1) v += __shfl_xor(v, o);
    __shared__ int ws[4];
    if ((t & 63) == 0) ws[t >> 6] = v;
    __syncthreads();
    if (t == 0) bsum[b] = ws[0] + ws[1] + ws[2] + ws[3];
}

__global__ __launch_bounds__(256) void k_scan2(
    const int* __restrict__ bsum, int* __restrict__ bbase)
{
    __shared__ int sc[256];
    const int t = threadIdx.x;
    int v = bsum[t];
    sc[t] = v;
    __syncthreads();
    for (int o = 1; o < 256; o <<= 1) {
        int u = (t >= o) ? sc[t - o] : 0;
        __syncthreads();
        sc[t] += u;
        __syncthreads();
    }
    bbase[t] = sc[t] - v;   // exclusive
}

__global__ __launch_bounds__(256) void k_scan3(
    const int* __restrict__ deg, const int* __restrict__ bbase,
    int* __restrict__ off, int* __restrict__ cursor)
{
    __shared__ int sc[256];
    const int b = blockIdx.x, t = threadIdx.x;
    int v = deg[b * 256 + t];
    sc[t] = v;
    __syncthreads();
    for (int o = 1; o < 256; o <<= 1) {
        int u = (t >= o) ? sc[t - o] : 0;
        __syncthreads();
        sc[t] += u;
        __syncthreads();
    }
    int excl = bbase[b] + sc[t] - v;
    off[b * 256 + t] = excl;
    cursor[b * 256 + t] = excl;
    if (b == 255 && t == 255) off[NCH] = excl + v;
}

// Scatter: R7 packs ef to 8 fp8 bytes (half the scattered write bytes).
__global__ __launch_bounds__(256) void k_scatter(
    const int* __restrict__ eidx, int* __restrict__ cursor,
    const float* __restrict__ ef,
    int* __restrict__ dsts, unsigned char* __restrict__ efs8)
{
    int e = blockIdx.x * 256 + threadIdx.x;
    int s = eidx[2 * e], d = eidx[2 * e + 1];
    const float4* p = (const float4*)(ef + (size_t)e * 8);
    float4 f0 = p[0], f1 = p[1];
    int pos = atomicAdd(&cursor[s], 1);
    dsts[pos] = d;
    unsigned p01 = __builtin_amdgcn_cvt_pk_fp8_f32(f0.x, f0.y, 0, false) & 0xffff;
    unsigned p23 = __builtin_amdgcn_cvt_pk_fp8_f32(f0.z, f0.w, 0, false) & 0xffff;
    unsigned p45 = __builtin_amdgcn_cvt_pk_fp8_f32(f1.x, f1.y, 0, false) & 0xffff;
    unsigned p67 = __builtin_amdgcn_cvt_pk_fp8_f32(f1.z, f1.w, 0, false) & 0xffff;
    unsigned long long v = (unsigned long long)(p01 | (p23 << 16))
                         | ((unsigned long long)(p45 | (p67 << 16)) << 32);
    *(unsigned long long*)(efs8 + (size_t)pos * 8) = v;
}

// ---------------------------------------------------------------------------
// k_src: per-node projections from x:
//   St2[n] = bf16( x[n] @ We[0:128] + be )    (frag-ordered)
//   Dq[n]  = fp8e4m3( x[n] @ We[128:256] )    (row-major compact, 128 B/row)
// ---------------------------------------------------------------------------
__global__ __launch_bounds__(256) void k_src(
    const __bf16* __restrict__ xCur, const float* __restrict__ We,
    const float* __restrict__ be, __bf16* __restrict__ St2,
    unsigned char* __restrict__ Dq)
{
    __shared__ __bf16 Wl[4 * 8 * 64 * 8];   // 32 KB, reused for src then dst
    __shared__ float  bl[HID];
    const int t = threadIdx.x;
    const int wave = t >> 6, lane = t & 63;
    const int m = lane & 15, quad = lane >> 4;
    const int tile = blockIdx.x * 4 + wave;   // grid 1024 -> 4096 tiles
    const int r0 = tile << 4;
    const int row = r0 + m;

    // ---- phase 1: W_src ----
    for (int idx = t; idx < 128 * HID; idx += 256) {
        int k = idx >> 7, h = idx & 127;
        int kt = k >> 5, kk = k & 31;
        int ln = ((kk >> 3) << 4) | (h & 15);
        Wl[((((kt * 8) + (h >> 4)) * 64 + ln) << 3) | (kk & 7)] = f2bf(We[idx]);
    }
    for (int idx = t; idx < HID; idx += 256) bl[idx] = be[idx];
    __syncthreads();

    bfrag a[4];
    const __bf16* ar = xCur + (size_t)row * HID + quad * 8;
    #pragma unroll
    for (int kt = 0; kt < 4; ++kt) a[kt] = *(const bfrag*)(ar + kt * 32);

    ffrag acc[8];
    #pragma unroll
    for (int u = 0; u < 8; ++u)
        #pragma unroll
        for (int r = 0; r < 4; ++r) acc[u][r] = 0.f;

    #pragma unroll
    for (int kt = 0; kt < 4; ++kt)
        #pragma unroll
        for (int u = 0; u < 8; ++u) {
            bfrag b = *(const bfrag*)(&Wl[(((kt * 8 + u) * 64 + lane) << 3)]);
            acc[u] = __builtin_amdgcn_mfma_f32_16x16x32_bf16(a[kt], b, acc[u], 0, 0, 0);
        }
    #pragma unroll
    for (int r = 0; r < 4; ++r) {
        int node = r0 + quad * 4 + r;
        bfrag pk;
        #pragma unroll
        for (int u = 0; u < 8; ++u) pk[u] = f2bf(acc[u][r] + bl[u * 16 + m]);
        *(bfrag*)(St2 + ((size_t)node * 16 + m) * 8) = pk;   // 16B coalesced
    }
    __syncthreads();   // all waves done reading Wl(src)

    // ---- phase 2: W_dst (rows 128..255), reuse LDS ----
    for (int idx = t; idx < 128 * HID; idx += 256) {
        int k = idx >> 7, h = idx & 127;
        int kt = k >> 5, kk = k & 31;
        int ln = ((kk >> 3) << 4) | (h & 15);
        Wl[((((kt * 8) + (h >> 4)) * 64 + ln) << 3) | (kk & 7)] = f2bf(We[(size_t)(128 + k) * HID + h]);
    }
    __syncthreads();

    #pragma unroll
    for (int u = 0; u < 8; ++u)
        #pragma unroll
        for (int r = 0; r < 4; ++r) acc[u][r] = 0.f;

    #pragma unroll
    for (int kt = 0; kt < 4; ++kt)
        #pragma unroll
        for (int u = 0; u < 8; ++u) {
            bfrag b = *(const bfrag*)(&Wl[(((kt * 8 + u) * 64 + lane) << 3)]);
            acc[u] = __builtin_amdgcn_mfma_f32_16x16x32_bf16(a[kt], b, acc[u], 0, 0, 0);
        }
    // D written row-major compact fp8, NO bias (bias lives in St2)
    #pragma unroll
    for (int r = 0; r < 4; ++r) {
        int node = r0 + quad * 4 + r;
        unsigned char* orow = Dq + (size_t)node * 128;
        #pragma unroll
        for (int u = 0; u < 8; ++u) orow[u * 16 + m] = f2q(acc[u][r]);
    }
}

// ---------------------------------------------------------------------------
// Fused edge pass + segment_sum + col-max.  R7: D gathered as fp8 e4m3
// (128 B/row -> 2x64B lines, was 4) and fed DIRECTLY into fp8 MFMAs with
// fp8 one-hot identity B (1.0 = 0x38).  ef path also fp8 (A=ef bytes,
// B=compact fp8 weight block, 1 KB LDS).  No conversion VALU anywhere.
// ---------------------------------------------------------------------------
__global__ __launch_bounds__(256) void k_edge2(
    const unsigned char* __restrict__ Dq,    // fp8 D rows, 128 B each
    const int*    __restrict__ offs,
    const int*    __restrict__ dsts,
    const unsigned char* __restrict__ efs8,  // fp8 ef, 8 B per edge
    const __bf16* __restrict__ St2,
    const float*  __restrict__ We,    // 264x128 slice; rows 256..263 used
    __bf16* __restrict__ xNext,
    unsigned int* __restrict__ pmax, int stage)
{
    __shared__ unsigned char Wf[8 * 16 * 8];   // 1 KB: compact fp8 ef weights
    __shared__ unsigned int cm[HID];
    const int t = threadIdx.x;

    if (t < HID) cm[t] = 0u;
    // ef rows 256..263, compact fp8: [u][ln<16][j]
    for (int idx = t; idx < 8 * HID; idx += 256) {
        int k2 = idx >> 7, h = idx & 127;
        Wf[((((h >> 4) * 16) + (h & 15)) << 3) + k2] = f2q(We[(size_t)(256 + k2) * HID + h]);
    }
    __syncthreads();

    const int wave = t >> 6, lane = t & 63;
    const int m = lane & 15, quad = lane >> 4;
    const int gw = blockIdx.x * 4 + wave;    // grid 4096 -> 16384 waves
    const int n0 = gw * 4;                   // 4 nodes per wave, consecutive

    // fp8 one-hot identity B-fragments (e4m3 1.0 = 0x38)
    const long BevQ = (quad == (m >> 3))     ? ((long)0x38 << (8 * (m & 7))) : 0L;
    const long BodQ = (quad == 2 + (m >> 3)) ? ((long)0x38 << (8 * (m & 7))) : 0L;

    const int o0 = offs[n0],     o1 = offs[n0 + 1], o2 = offs[n0 + 2];
    const int o3 = offs[n0 + 3], o4 = offs[n0 + 4];

    auto selo = [&](int q) -> int {
        return (q <= 0) ? o0 : (q == 1) ? o1 : (q == 2) ? o2 : (q == 3) ? o3 : o4;
    };

    float mxu[8];
    #pragma unroll
    for (int u = 0; u < 8; ++u) mxu[u] = 0.f;

    if (o0 < o4) {
        const int dvA = dsts[min(o0 + lane, o4 - 1)];
        const int dvB = dsts[min(o0 + 64 + lane, o4 - 1)];

        auto LOADT = [&](int j) -> FragsQ {
            FragsQ f;
            int jl = j + m; jl = (jl < o4) ? jl : (o4 - 1);
            int rel = jl - o0;
            int dA = __shfl(dvA, rel & 63);
            int dB = __shfl(dvB, rel & 63);
            int dm;
            if (rel < 64)       dm = dA;
            else if (rel < 128) dm = dB;
            else                dm = dsts[jl];      // ultra-rare fallback
            const unsigned char* rd = Dq + (size_t)dm * 128 + quad * 8;
            f.d[0] = *(const long*)(rd);
            f.d[1] = *(const long*)(rd + 32);
            f.d[2] = *(const long*)(rd + 64);
            f.d[3] = *(const long*)(rd + 96);
            f.ef = (quad == 0) ? *(const long*)(efs8 + (size_t)jl * 8) : 0L;
            return f;
        };

        int ci = 0;
        while (selo(ci) == selo(ci + 1)) ++ci;   // first non-empty node (exists)
        int cj = selo(ci);

        bfrag sb = *(const bfrag*)(St2 + ((size_t)(n0 + ci) * 16 + m) * 8);
        float part[8];
        #pragma unroll
        for (int u = 0; u < 8; ++u) part[u] = 0.f;

        FragsQ aC = LOADT(cj);

        for (;;) {
            const int cEnd = selo(ci + 1);
            int ni = ci, nj = cj + 16;
            if (nj >= cEnd) {
                ni = ci + 1;
                while (ni < 4 && selo(ni) == selo(ni + 1)) ++ni;
                nj = (ni < 4) ? selo(ni) : 0;
            }
            const bool hn = (ni < 4);
            FragsQ aN;
            if (hn) aN = LOADT(nj);             // prefetch next tile

            ffrag acc[8];
            #pragma unroll
            for (int u = 0; u < 8; ++u) {
                float s = (float)sb[u];
                acc[u][0] = s; acc[u][1] = s; acc[u][2] = s; acc[u][3] = s;
            }
            // identity transpose: fp8 D rows -> C-layout
            #pragma unroll
            for (int u = 0; u < 8; ++u)
                acc[u] = __builtin_amdgcn_mfma_f32_16x16x32_fp8_fp8(
                    aC.d[u >> 1], (u & 1) ? BodQ : BevQ, acc[u], 0, 0, 0);
            // ef projection (fp8 x fp8)
            #pragma unroll
            for (int u = 0; u < 8; ++u) {
                long b = *(const long*)(&Wf[((u << 4) + m) << 3]);
                acc[u] = __builtin_amdgcn_mfma_f32_16x16x32_fp8_fp8(aC.ef, b, acc[u], 0, 0, 0);
            }

            const int rb = cj + quad * 4;
            #pragma unroll
            for (int r = 0; r < 4; ++r) {
                if (rb + r < cEnd) {
                    #pragma unroll
                    for (int u = 0; u < 8; ++u)
                        part[u] += fmaxf(acc[u][r], 0.f);
                }
            }

            if (!hn || ni != ci) {
                float tot[8];
                #pragma unroll
                for (int u = 0; u < 8; ++u) {
                    float v = part[u];
                    v += __shfl_xor(v, 16);
                    v += __shfl_xor(v, 32);
                    tot[u] = v;
                    mxu[u] = fmaxf(mxu[u], v);
                }
                // static-index selection of this quad's 2 columns (no scratch)
                float sA = (quad == 0) ? tot[0] : (quad == 1) ? tot[2] : (quad == 2) ? tot[4] : tot[6];
                float sB = (quad == 0) ? tot[1] : (quad == 1) ? tot[3] : (quad == 2) ? tot[5] : tot[7];
                const int n = n0 + ci, u0 = quad * 2;
                xNext[(size_t)n * HID + u0 * 16 + m]      = f2bf(sA);
                xNext[(size_t)n * HID + u0 * 16 + 16 + m] = f2bf(sB);
                if (hn) {
                    sb = *(const bfrag*)(St2 + ((size_t)(n0 + ni) * 16 + m) * 8);
                    #pragma unroll
                    for (int u = 0; u < 8; ++u) part[u] = 0.f;
                }
            }
            if (!hn) break;
            aC = aN; ci = ni; cj = nj;
        }
    }

    // zero rows for empty nodes
    {
        const int u0 = quad * 2;
        const __bf16 zz = (__bf16)0.f;
        if (o0 == o1) { xNext[(size_t)(n0+0)*HID + u0*16 + m] = zz; xNext[(size_t)(n0+0)*HID + u0*16 + 16 + m] = zz; }
        if (o1 == o2) { xNext[(size_t)(n0+1)*HID + u0*16 + m] = zz; xNext[(size_t)(n0+1)*HID + u0*16 + 16 + m] = zz; }
        if (o2 == o3) { xNext[(size_t)(n0+2)*HID + u0*16 + m] = zz; xNext[(size_t)(n0+2)*HID + u0*16 + 16 + m] = zz; }
        if (o3 == o4) { xNext[(size_t)(n0+3)*HID + u0*16 + m] = zz; xNext[(size_t)(n0+3)*HID + u0*16 + 16 + m] = zz; }
    }

    #pragma unroll
    for (int u = 0; u < 8; ++u) {
        float v = mxu[u];
        v = fmaxf(v, __shfl_xor(v, 16));
        v = fmaxf(v, __shfl_xor(v, 32));
        if (quad == 0) atomicMax(&cm[u * 16 + m], __float_as_uint(v));
    }
    __syncthreads();
    if (t < HID) atomicMax(&pmax[stage * HID + t], cm[t]);
}

// ---------------------------------------------------------------------------
// Fallback path kernels (R1-proven, 48 MB footprint)
// ---------------------------------------------------------------------------
__global__ __launch_bounds__(256) void k_edge_at(
    const __bf16* __restrict__ xA, const int* __restrict__ eidx,
    const float* __restrict__ ef, const float* __restrict__ We,
    const float* __restrict__ be, float* __restrict__ xNew)
{
    __shared__ __bf16 Wl[9 * 8 * 64 * 8];
    __shared__ float  bl[HID];
    const int t = threadIdx.x;
    for (int idx = t; idx < 8 * 64 * 8; idx += 256) Wl[8 * 8 * 64 * 8 + idx] = (__bf16)0.f;
    __syncthreads();
    for (int idx = t; idx < 256 * HID; idx += 256) {
        int k = idx >> 7, h = idx & 127;
        int kt = k >> 5, kk = k & 31;
        int lane = ((kk >> 3) << 4) | (h & 15);
        Wl[((((kt * 8) + (h >> 4)) * 64 + lane) << 3) | (kk & 7)] = f2bf(We[idx]);
    }
    for (int idx = t; idx < 8 * HID; idx += 256) {
        int k2 = idx >> 7, h = idx & 127;
        Wl[((((8 * 8) + (h >> 4)) * 64 + (h & 15)) << 3) | k2] = f2bf(We[(256 + k2) * HID + h]);
    }
    for (int idx = t; idx < HID; idx += 256) bl[idx] = be[idx];
    __syncthreads();

    const int wave = t >> 6, lane = t & 63;
    const int m = lane & 15, quad = lane >> 4;
    for (int c = 0; c < 8; ++c) {
        const int e0 = blockIdx.x * 512 + c * 64 + wave * 16;
        const int e  = e0 + m;
        const int src = eidx[2 * e], dst = eidx[2 * e + 1];
        const __bf16* rs = xA + (size_t)src * HID;
        const __bf16* rd = xA + (size_t)dst * HID;
        bfrag a[9];
        #pragma unroll
        for (int kt = 0; kt < 4; ++kt) a[kt] = *(const bfrag*)(rs + kt * 32 + quad * 8);
        #pragma unroll
        for (int kt = 4; kt < 8; ++kt) a[kt] = *(const bfrag*)(rd + (kt - 4) * 32 + quad * 8);
        {
            bfrag z;
            #pragma unroll
            for (int q = 0; q < 8; ++q) z[q] = (__bf16)0.f;
            if (quad == 0) {
                const float4* p = (const float4*)(ef + (size_t)e * 8);
                float4 f0 = p[0], f1 = p[1];
                z[0]=f2bf(f0.x); z[1]=f2bf(f0.y); z[2]=f2bf(f0.z); z[3]=f2bf(f0.w);
                z[4]=f2bf(f1.x); z[5]=f2bf(f1.y); z[6]=f2bf(f1.z); z[7]=f2bf(f1.w);
            }
            a[8] = z;
        }
        ffrag acc[8];
        #pragma unroll
        for (int u = 0; u < 8; ++u)
            #pragma unroll
            for (int r = 0; r < 4; ++r) acc[u][r] = 0.f;
        #pragma unroll
        for (int kt = 0; kt < 9; ++kt)
            #pragma unroll
            for (int u = 0; u < 8; ++u) {
                bfrag b = *(const bfrag*)(&Wl[(((kt * 8 + u) * 64 + lane) << 3)]);
                acc[u] = __builtin_amdgcn_mfma_f32_16x16x32_bf16(a[kt], b, acc[u], 0, 0, 0);
            }
        #pragma unroll
        for (int r = 0; r < 4; ++r) {
            int er = e0 + quad * 4 + r;
            int sr = eidx[2 * er];
            float* outrow = xNew + (size_t)sr * HID;
            #pragma unroll
            for (int u = 0; u < 8; ++u) {
                int col = u * 16 + m;
                atomicAdd(outrow + col, fmaxf(acc[u][r] + bl[col], 0.f));
            }
        }
    }
}

__global__ __launch_bounds__(256) void k_fin(
    float* __restrict__ xNew, __bf16* __restrict__ xA,
    unsigned int* __restrict__ pmax, int stage, int flags)
{
    const int t = threadIdx.x;
    const size_t total  = (size_t)NCH * HID;
    const size_t stride = (size_t)gridDim.x * 256;
    float mx = 0.f;
    for (size_t i = (size_t)blockIdx.x * 256 + t; i < total; i += stride) {
        float v = xNew[i];
        mx = fmaxf(mx, v);
        if (flags & 1) xA[i] = f2bf(v);
        if (flags & 2) xNew[i] = 0.f;
    }
    __shared__ float red[256];
    red[t] = mx;
    __syncthreads();
    if (t < 128) {
        float v = fmaxf(red[t], red[t + 128]);
        atomicMax(&pmax[stage * HID + t], __float_as_uint(v));
    }
}

// ---------------------------------------------------------------------------
// Parent head: out = relu(pmax(384) @ Wp + bp)
// ---------------------------------------------------------------------------
__global__ __launch_bounds__(128) void k_parent(
    const unsigned int* __restrict__ pmaxU,
    const float* __restrict__ Wp, const float* __restrict__ bp,
    float* __restrict__ out)
{
    __shared__ float pl[384];
    const int t = threadIdx.x;
    for (int i = t; i < 384; i += 128) pl[i] = __uint_as_float(pmaxU[i]);
    __syncthreads();
    float acc = bp[t];
    for (int j = 0; j < 384; ++j) acc += pl[j] * Wp[j * HID + t];
    out[t] = fmaxf(acc, 0.f);
}

extern "C" void kernel_launch(void* const* d_in, const int* in_sizes, int n_in,
                              void* d_out, int out_size, void* d_ws, size_t ws_size,
                              hipStream_t stream)
{
    const float* cf   = (const float*)d_in[0];
    const float* ex   = (const float*)d_in[1];
    const float* ef   = (const float*)d_in[2];
    const int*   eidx = (const int*)d_in[3];
    const float* Wc   = (const float*)d_in[4];
    const float* bc   = (const float*)d_in[5];
    const float* We   = (const float*)d_in[6];
    const float* be   = (const float*)d_in[7];
    const float* Wp   = (const float*)d_in[8];
    const float* bp   = (const float*)d_in[9];
    float* out = (float*)d_out;

    char* ws = (char*)d_ws;

    // CSR-fused path layout (~69 MB, unchanged NEED vs R6: fp8 efs (8 MB)
    // + fp8 D (8 MB) share the old 16 MB efs slot)
    const size_t OFF_XA   = 0;
    const size_t OFF_XB   = OFF_XA   + (size_t)NCH * HID * 2;   // +16 MB
    const size_t OFF_ST   = OFF_XB   + (size_t)NCH * HID * 2;   // +16 MB
    const size_t OFF_EFS  = OFF_ST   + (size_t)NCH * HID * 2;   // +16 MB
    const size_t OFF_DQ   = OFF_EFS  + (size_t)NE * 8;          // +8 MB (fp8 ef)
    const size_t OFF_DST  = OFF_DQ   + (size_t)NCH * 128;       // +8 MB (fp8 D)
    const size_t OFF_OFFS = OFF_DST  + (size_t)NE * 4;          // +4 MB
    const size_t OFF_DEG  = OFF_OFFS + 262400;
    const size_t OFF_CUR  = OFF_DEG  + 262144;
    const size_t OFF_PMAX = OFF_CUR  + 262144;
    const size_t OFF_BS   = OFF_PMAX + 2048;     // bsum[256]
    const size_t OFF_BB   = OFF_BS   + 1024;     // bbase[256]
    const size_t NEED     = OFF_BB   + 1024;

    if (ws_size >= NEED) {
        __bf16*        xA   = (__bf16*)(ws + OFF_XA);
        __bf16*        xB   = (__bf16*)(ws + OFF_XB);
        __bf16*        St2  = (__bf16*)(ws + OFF_ST);
        unsigned char* efs8 = (unsigned char*)(ws + OFF_EFS);
        unsigned char* Dq   = (unsigned char*)(ws + OFF_DQ);
        int*           dsts = (int*)   (ws + OFF_DST);
        int*           offs = (int*)   (ws + OFF_OFFS);
        int*           deg  = (int*)   (ws + OFF_DEG);
        int*           cur  = (int*)   (ws + OFF_CUR);
        unsigned int*  pmax = (unsigned int*)(ws + OFF_PMAX);
        int*           bsum = (int*)   (ws + OFF_BS);
        int*           bbas = (int*)   (ws + OFF_BB);

        hipMemsetAsync(pmax, 0, 384 * sizeof(unsigned int), stream);
        hipMemsetAsync(deg, 0, NCH * sizeof(int), stream);

        k_childhist<<<2048, 256, 0, stream>>>(cf, ex, Wc, bc, xA, pmax, eidx, deg);
        k_scan1  <<<256,  256, 0, stream>>>(deg, bsum);
        k_scan2  <<<1,    256, 0, stream>>>(bsum, bbas);
        k_scan3  <<<256,  256, 0, stream>>>(deg, bbas, offs, cur);
        k_scatter<<<4096, 256, 0, stream>>>(eidx, cur, ef, dsts, efs8);

        k_src    <<<1024, 256, 0, stream>>>(xA, We, be, St2, Dq);
        k_edge2  <<<4096, 256, 0, stream>>>(Dq, offs, dsts, efs8, St2, We, xB, pmax, 1);
        k_src    <<<1024, 256, 0, stream>>>(xB, We + 264 * HID, be + HID, St2, Dq);
        k_edge2  <<<4096, 256, 0, stream>>>(Dq, offs, dsts, efs8, St2, We + 264 * HID, xA, pmax, 2);
        k_parent <<<1,    128, 0, stream>>>(pmax, Wp, bp, out);
    } else {
        // fallback: R1 atomic path (48 MB)
        float*        xNew = (float*)ws;
        __bf16*       xA   = (__bf16*)(ws + (size_t)NCH * HID * 4);
        unsigned int* pmax = (unsigned int*)(ws + (size_t)NCH * HID * 6);

        hipMemsetAsync(pmax, 0, 384 * sizeof(unsigned int), stream);
        hipMemsetAsync(xNew, 0, (size_t)NCH * HID * 4, stream);

        k_childhist<<<1024, 256, 0, stream>>>(cf, ex, Wc, bc, xA, pmax, eidx, (int*)nullptr);
        k_edge_at<<<2048, 256, 0, stream>>>(xA, eidx, ef, We,             be,       xNew);
        k_fin    <<<512,  256, 0, stream>>>(xNew, xA, pmax, 1, 3);
        k_edge_at<<<2048, 256, 0, stream>>>(xA, eidx, ef, We + 264 * HID, be + HID, xNew);
        k_fin    <<<512,  256, 0, stream>>>(xNew, xA, pmax, 2, 0);
        k_parent <<<1,    128, 0, stream>>>(pmax, Wp, bp, out);
    }
}

// Round 8
// 518.809 us; speedup vs baseline: 1.8304x; 1.0382x over previous
//
#include <hip/hip_runtime.h>
#include <hip/hip_bf16.h>

#define HID 128
#define DIN 192      // N_FEAT + NUM_SEM
#define NCH 65536
#define NE  1048576

typedef __bf16 bfrag __attribute__((ext_vector_type(8)));
typedef float  ffrag __attribute__((ext_vector_type(4)));
typedef long   lfrag2 __attribute__((ext_vector_type(2)));

static __device__ __forceinline__ __bf16 f2bf(float x) { return (__bf16)x; }
static __device__ __forceinline__ unsigned pk2(float a, float b) {
    __bf16 b0 = f2bf(a), b1 = f2bf(b);
    return (unsigned)*(unsigned short*)&b0 | ((unsigned)*(unsigned short*)&b1 << 16);
}
// f32 -> OCP e4m3 byte (gfx950 hw cvt)
static __device__ __forceinline__ unsigned char f2q(float x) {
    return (unsigned char)(__builtin_amdgcn_cvt_pk_fp8_f32(x, x, 0, false) & 0xff);
}

struct FragsQ { long d[4]; long ef; };

// Vectorized B-fragment staging: chunk c = ((kt*8+u)*64+lane); 8 strided
// (L2-hot) fp32 loads -> one ds_write_b128.  Replaces per-element scattered
// ds_write_b16 (8x fewer LDS ops, ~4x less staging VALU).
static __device__ __forceinline__ void stage_wfrag(
    __bf16* Wl, const float* W, int rowoff, int chunks, int t)
{
    for (int c = t; c < chunks; c += 256) {
        int lane = c & 63, u = (c >> 6) & 7, kt = c >> 9;
        int k0 = kt * 32 + ((lane >> 4) << 3), h = u * 16 + (lane & 15);
        const float* src = W + (size_t)(rowoff + k0) * 128 + h;
        bfrag f;
        #pragma unroll
        for (int j = 0; j < 8; ++j) f[j] = f2bf(src[(size_t)j * 128]);
        *(bfrag*)(&Wl[(size_t)c << 3]) = f;
    }
}

// ---------------------------------------------------------------------------
// Child encoder FUSED with edge histogram (R6), vectorized staging (R8).
// ---------------------------------------------------------------------------
__global__ __launch_bounds__(256) void k_childhist(
    const float* __restrict__ cf, const float* __restrict__ exists,
    const float* __restrict__ Wc, const float* __restrict__ bc,
    __bf16* __restrict__ xA, unsigned int* __restrict__ pmax,
    const int* __restrict__ eidx, int* __restrict__ deg)
{
    if (blockIdx.x >= 1024) {
        const int base = (blockIdx.x - 1024) * 1024 + threadIdx.x;
        #pragma unroll
        for (int k = 0; k < 4; ++k)
            atomicAdd(&deg[eidx[2 * (base + k * 256)]], 1);
        return;
    }

    __shared__ __bf16 Wl[6 * 8 * 64 * 8];   // 48 KB, B-fragment-swizzled
    __shared__ float  bl[HID];
    __shared__ unsigned int cm[HID];
    const int t = threadIdx.x;

    stage_wfrag(Wl, Wc, 0, 3072, t);        // DIN*HID/8 chunks
    for (int idx = t; idx < HID; idx += 256) { bl[idx] = bc[idx]; cm[idx] = 0u; }
    __syncthreads();

    const int wave = t >> 6, lane = t & 63;
    const int m = lane & 15, quad = lane >> 4;

    const int tile = blockIdx.x * 4 + wave;   // 1024 blocks -> 4096 tiles
    const int r0 = tile << 4;
    const int row = r0 + m;

    ffrag acc[8];
    #pragma unroll
    for (int u = 0; u < 8; ++u)
        #pragma unroll
        for (int r = 0; r < 4; ++r) acc[u][r] = 0.f;

    const float* arow = cf + (size_t)row * DIN + quad * 8;
    #pragma unroll
    for (int kt = 0; kt < 6; ++kt) {
        float4 f0 = *(const float4*)(arow + kt * 32);
        float4 f1 = *(const float4*)(arow + kt * 32 + 4);
        bfrag a;
        a[0]=f2bf(f0.x); a[1]=f2bf(f0.y); a[2]=f2bf(f0.z); a[3]=f2bf(f0.w);
        a[4]=f2bf(f1.x); a[5]=f2bf(f1.y); a[6]=f2bf(f1.z); a[7]=f2bf(f1.w);
        #pragma unroll
        for (int u = 0; u < 8; ++u) {
            bfrag b = *(const bfrag*)(&Wl[(((kt * 8 + u) * 64 + lane) << 3)]);
            acc[u] = __builtin_amdgcn_mfma_f32_16x16x32_bf16(a, b, acc[u], 0, 0, 0);
        }
    }

    float mxu[8];
    #pragma unroll
    for (int u = 0; u < 8; ++u) mxu[u] = 0.f;

    #pragma unroll
    for (int r = 0; r < 4; ++r) {
        int er = r0 + quad * 4 + r;
        float exv = exists[er];
        __bf16* orow = xA + (size_t)er * HID;
        #pragma unroll
        for (int u = 0; u < 8; ++u) {
            int col = u * 16 + m;
            float v = fmaxf(acc[u][r] + bl[col], 0.f) * exv;
            orow[col] = f2bf(v);
            mxu[u] = fmaxf(mxu[u], v);
        }
    }
    #pragma unroll
    for (int u = 0; u < 8; ++u) {
        float v = mxu[u];
        v = fmaxf(v, __shfl_xor(v, 16));
        v = fmaxf(v, __shfl_xor(v, 32));
        if (quad == 0) atomicMax(&cm[u * 16 + m], __float_as_uint(v));
    }
    __syncthreads();
    if (t < HID) atomicMax(&pmax[t], cm[t]);
}

// ---------------------------------------------------------------------------
// Scan: 2 kernels (R8).  scan1: per-block sums.  scan23: each block
// redundantly scans the 256 block-sums (cheap) + scans its own 256 degs.
// ---------------------------------------------------------------------------
__global__ __launch_bounds__(256) void k_scan1(
    const int* __restrict__ deg, int* __restrict__ bsum)
{
    const int b = blockIdx.x, t = threadIdx.x;
    int v = deg[b * 256 + t];
    #pragma unroll
    for (int o = 1; o < 64; o <<= 1) v += __shfl_xor(v, o);
    __shared__ int ws[4];
    if ((t & 63) == 0) ws[t >> 6] = v;
    __syncthreads();
    if (t == 0) bsum[b] = ws[0] + ws[1] + ws[2] + ws[3];
}

__global__ __launch_bounds__(256) void k_scan23(
    const int* __restrict__ deg, const int* __restrict__ bsum,
    int* __restrict__ off, int* __restrict__ cursor)
{
    __shared__ int sb[256], sc[256];
    const int b = blockIdx.x, t = threadIdx.x;
    int w = bsum[t];
    int v = deg[b * 256 + t];
    sb[t] = w; sc[t] = v;
    __syncthreads();
    for (int o = 1; o < 256; o <<= 1) {
        int u1 = (t >= o) ? sb[t - o] : 0;
        int u2 = (t >= o) ? sc[t - o] : 0;
        __syncthreads();
        sb[t] += u1; sc[t] += u2;
        __syncthreads();
    }
    int bbase = (b == 0) ? 0 : sb[b - 1];
    int excl = bbase + sc[t] - v;
    off[b * 256 + t] = excl;
    cursor[b * 256 + t] = excl;
    if (b == 255 && t == 255) off[NCH] = excl + v;
}

// ---------------------------------------------------------------------------
// R8 merged kernel: blocks 0..1023 = k_src (per-node projections), blocks
// 1024..5119 = k_scatter.  The two halves are data-independent and overlap
// on the CU array; saves one dispatch.
//   St2[n] = bf16( x[n] @ We[0:128] + be )    (frag-ordered)
//   Dq[n]  = fp8e4m3( x[n] @ We[128:256] )    PERMUTED layout: byte
//            [q*32 + i*8 + b] = D[i*32 + q*8 + b]  -> gather lane reads
//            one contiguous 32B span (2x16B loads, was 4x8B).
// ---------------------------------------------------------------------------
__global__ __launch_bounds__(256) void k_scsrc(
    const __bf16* __restrict__ xCur, const float* __restrict__ We,
    const float* __restrict__ be, __bf16* __restrict__ St2,
    unsigned char* __restrict__ Dq,
    const int* __restrict__ eidx, int* __restrict__ cursor,
    const float* __restrict__ ef,
    int* __restrict__ dsts, unsigned char* __restrict__ efs8)
{
    __shared__ __bf16 Wl[4 * 8 * 64 * 8];   // 32 KB, reused for src then dst
    __shared__ float  bl[HID];
    const int t = threadIdx.x;

    if (blockIdx.x >= 1024) {
        // ---- scatter ----
        int e = (blockIdx.x - 1024) * 256 + t;
        int s = eidx[2 * e], d = eidx[2 * e + 1];
        const float4* p = (const float4*)(ef + (size_t)e * 8);
        float4 f0 = p[0], f1 = p[1];
        int pos = atomicAdd(&cursor[s], 1);
        dsts[pos] = d;
        unsigned p01 = __builtin_amdgcn_cvt_pk_fp8_f32(f0.x, f0.y, 0, false) & 0xffff;
        unsigned p23 = __builtin_amdgcn_cvt_pk_fp8_f32(f0.z, f0.w, 0, false) & 0xffff;
        unsigned p45 = __builtin_amdgcn_cvt_pk_fp8_f32(f1.x, f1.y, 0, false) & 0xffff;
        unsigned p67 = __builtin_amdgcn_cvt_pk_fp8_f32(f1.z, f1.w, 0, false) & 0xffff;
        unsigned long long v = (unsigned long long)(p01 | (p23 << 16))
                             | ((unsigned long long)(p45 | (p67 << 16)) << 32);
        *(unsigned long long*)(efs8 + (size_t)pos * 8) = v;
        return;
    }

    // ---- src ----
    const int wave = t >> 6, lane = t & 63;
    const int m = lane & 15, quad = lane >> 4;
    const int tile = blockIdx.x * 4 + wave;   // 1024 blocks -> 4096 tiles
    const int r0 = tile << 4;
    const int row = r0 + m;

    // phase 1: W_src
    stage_wfrag(Wl, We, 0, 2048, t);
    for (int idx = t; idx < HID; idx += 256) bl[idx] = be[idx];
    __syncthreads();

    bfrag a[4];
    const __bf16* ar = xCur + (size_t)row * HID + quad * 8;
    #pragma unroll
    for (int kt = 0; kt < 4; ++kt) a[kt] = *(const bfrag*)(ar + kt * 32);

    ffrag acc[8];
    #pragma unroll
    for (int u = 0; u < 8; ++u)
        #pragma unroll
        for (int r = 0; r < 4; ++r) acc[u][r] = 0.f;

    #pragma unroll
    for (int kt = 0; kt < 4; ++kt)
        #pragma unroll
        for (int u = 0; u < 8; ++u) {
            bfrag b = *(const bfrag*)(&Wl[(((kt * 8 + u) * 64 + lane) << 3)]);
            acc[u] = __builtin_amdgcn_mfma_f32_16x16x32_bf16(a[kt], b, acc[u], 0, 0, 0);
        }
    #pragma unroll
    for (int r = 0; r < 4; ++r) {
        int node = r0 + quad * 4 + r;
        bfrag pk;
        #pragma unroll
        for (int u = 0; u < 8; ++u) pk[u] = f2bf(acc[u][r] + bl[u * 16 + m]);
        *(bfrag*)(St2 + ((size_t)node * 16 + m) * 8) = pk;   // 16B coalesced
    }
    __syncthreads();   // all waves done reading Wl(src)

    // phase 2: W_dst (rows 128..255)
    stage_wfrag(Wl, We, 128, 2048, t);
    __syncthreads();

    #pragma unroll
    for (int u = 0; u < 8; ++u)
        #pragma unroll
        for (int r = 0; r < 4; ++r) acc[u][r] = 0.f;

    #pragma unroll
    for (int kt = 0; kt < 4; ++kt)
        #pragma unroll
        for (int u = 0; u < 8; ++u) {
            bfrag b = *(const bfrag*)(&Wl[(((kt * 8 + u) * 64 + lane) << 3)]);
            acc[u] = __builtin_amdgcn_mfma_f32_16x16x32_bf16(a[kt], b, acc[u], 0, 0, 0);
        }
    // D written PERMUTED compact fp8 (see header), NO bias
    #pragma unroll
    for (int r = 0; r < 4; ++r) {
        int node = r0 + quad * 4 + r;
        unsigned char* orow = Dq + (size_t)node * 128;
        #pragma unroll
        for (int u = 0; u < 8; ++u)
            orow[((u & 1) * 2 + (m >> 3)) * 32 + (u >> 1) * 8 + (m & 7)] = f2q(acc[u][r]);
    }
}

// ---------------------------------------------------------------------------
// Fused edge pass + segment_sum + col-max.  R8: permuted-Dq gather = 2x16B
// contiguous loads per lane (was 4x8B) -> half the gather load instructions.
// ---------------------------------------------------------------------------
__global__ __launch_bounds__(256) void k_edge2(
    const unsigned char* __restrict__ Dq,    // fp8 D rows, permuted, 128 B each
    const int*    __restrict__ offs,
    const int*    __restrict__ dsts,
    const unsigned char* __restrict__ efs8,  // fp8 ef, 8 B per edge
    const __bf16* __restrict__ St2,
    const float*  __restrict__ We,    // 264x128 slice; rows 256..263 used
    __bf16* __restrict__ xNext,
    unsigned int* __restrict__ pmax, int stage)
{
    __shared__ unsigned char Wf[8 * 16 * 8];   // 1 KB: compact fp8 ef weights
    __shared__ unsigned int cm[HID];
    const int t = threadIdx.x;

    if (t < HID) cm[t] = 0u;
    // ef rows 256..263, compact fp8: [u][ln<16][j]
    for (int idx = t; idx < 8 * HID; idx += 256) {
        int k2 = idx >> 7, h = idx & 127;
        Wf[((((h >> 4) * 16) + (h & 15)) << 3) + k2] = f2q(We[(size_t)(256 + k2) * HID + h]);
    }
    __syncthreads();

    const int wave = t >> 6, lane = t & 63;
    const int m = lane & 15, quad = lane >> 4;
    const int gw = blockIdx.x * 4 + wave;    // grid 4096 -> 16384 waves
    const int n0 = gw * 4;                   // 4 nodes per wave, consecutive

    // fp8 one-hot identity B-fragments (e4m3 1.0 = 0x38)
    const long BevQ = (quad == (m >> 3))     ? ((long)0x38 << (8 * (m & 7))) : 0L;
    const long BodQ = (quad == 2 + (m >> 3)) ? ((long)0x38 << (8 * (m & 7))) : 0L;

    const int o0 = offs[n0],     o1 = offs[n0 + 1], o2 = offs[n0 + 2];
    const int o3 = offs[n0 + 3], o4 = offs[n0 + 4];

    auto selo = [&](int q) -> int {
        return (q <= 0) ? o0 : (q == 1) ? o1 : (q == 2) ? o2 : (q == 3) ? o3 : o4;
    };

    float mxu[8];
    #pragma unroll
    for (int u = 0; u < 8; ++u) mxu[u] = 0.f;

    if (o0 < o4) {
        const int dvA = dsts[min(o0 + lane, o4 - 1)];
        const int dvB = dsts[min(o0 + 64 + lane, o4 - 1)];

        auto LOADT = [&](int j) -> FragsQ {
            FragsQ f;
            int jl = j + m; jl = (jl < o4) ? jl : (o4 - 1);
            int rel = jl - o0;
            int dA = __shfl(dvA, rel & 63);
            int dB = __shfl(dvB, rel & 63);
            int dm;
            if (rel < 64)       dm = dA;
            else if (rel < 128) dm = dB;
            else                dm = dsts[jl];      // ultra-rare fallback
            const unsigned char* rd = Dq + (size_t)dm * 128 + quad * 32;
            lfrag2 w0 = *(const lfrag2*)(rd);
            lfrag2 w1 = *(const lfrag2*)(rd + 16);
            f.d[0] = w0[0]; f.d[1] = w0[1]; f.d[2] = w1[0]; f.d[3] = w1[1];
            f.ef = (quad == 0) ? *(const long*)(efs8 + (size_t)jl * 8) : 0L;
            return f;
        };

        int ci = 0;
        while (selo(ci) == selo(ci + 1)) ++ci;   // first non-empty node (exists)
        int cj = selo(ci);

        bfrag sb = *(const bfrag*)(St2 + ((size_t)(n0 + ci) * 16 + m) * 8);
        float part[8];
        #pragma unroll
        for (int u = 0; u < 8; ++u) part[u] = 0.f;

        FragsQ aC = LOADT(cj);

        for (;;) {
            const int cEnd = selo(ci + 1);
            int ni = ci, nj = cj + 16;
            if (nj >= cEnd) {
                ni = ci + 1;
                while (ni < 4 && selo(ni) == selo(ni + 1)) ++ni;
                nj = (ni < 4) ? selo(ni) : 0;
            }
            const bool hn = (ni < 4);
            FragsQ aN;
            if (hn) aN = LOADT(nj);             // prefetch next tile

            ffrag acc[8];
            #pragma unroll
            for (int u = 0; u < 8; ++u) {
                float s = (float)sb[u];
                acc[u][0] = s; acc[u][1] = s; acc[u][2] = s; acc[u][3] = s;
            }
            // identity transpose: fp8 D rows -> C-layout
            #pragma unroll
            for (int u = 0; u < 8; ++u)
                acc[u] = __builtin_amdgcn_mfma_f32_16x16x32_fp8_fp8(
                    aC.d[u >> 1], (u & 1) ? BodQ : BevQ, acc[u], 0, 0, 0);
            // ef projection (fp8 x fp8)
            #pragma unroll
            for (int u = 0; u < 8; ++u) {
                long b = *(const long*)(&Wf[((u << 4) + m) << 3]);
                acc[u] = __builtin_amdgcn_mfma_f32_16x16x32_fp8_fp8(aC.ef, b, acc[u], 0, 0, 0);
            }

            const int rb = cj + quad * 4;
            #pragma unroll
            for (int r = 0; r < 4; ++r) {
                if (rb + r < cEnd) {
                    #pragma unroll
                    for (int u = 0; u < 8; ++u)
                        part[u] += fmaxf(acc[u][r], 0.f);
                }
            }

            if (!hn || ni != ci) {
                float tot[8];
                #pragma unroll
                for (int u = 0; u < 8; ++u) {
                    float v = part[u];
                    v += __shfl_xor(v, 16);
                    v += __shfl_xor(v, 32);
                    tot[u] = v;
                    mxu[u] = fmaxf(mxu[u], v);
                }
                // static-index selection of this quad's 2 columns (no scratch)
                float sA = (quad == 0) ? tot[0] : (quad == 1) ? tot[2] : (quad == 2) ? tot[4] : tot[6];
                float sB = (quad == 0) ? tot[1] : (quad == 1) ? tot[3] : (quad == 2) ? tot[5] : tot[7];
                const int n = n0 + ci, u0 = quad * 2;
                xNext[(size_t)n * HID + u0 * 16 + m]      = f2bf(sA);
                xNext[(size_t)n * HID + u0 * 16 + 16 + m] = f2bf(sB);
                if (hn) {
                    sb = *(const bfrag*)(St2 + ((size_t)(n0 + ni) * 16 + m) * 8);
                    #pragma unroll
                    for (int u = 0; u < 8; ++u) part[u] = 0.f;
                }
            }
            if (!hn) break;
            aC = aN; ci = ni; cj = nj;
        }
    }

    // zero rows for empty nodes
    {
        const int u0 = quad * 2;
        const __bf16 zz = (__bf16)0.f;
        if (o0 == o1) { xNext[(size_t)(n0+0)*HID + u0*16 + m] = zz; xNext[(size_t)(n0+0)*HID + u0*16 + 16 + m] = zz; }
        if (o1 == o2) { xNext[(size_t)(n0+1)*HID + u0*16 + m] = zz; xNext[(size_t)(n0+1)*HID + u0*16 + 16 + m] = zz; }
        if (o2 == o3) { xNext[(size_t)(n0+2)*HID + u0*16 + m] = zz; xNext[(size_t)(n0+2)*HID + u0*16 + 16 + m] = zz; }
        if (o3 == o4) { xNext[(size_t)(n0+3)*HID + u0*16 + m] = zz; xNext[(size_t)(n0+3)*HID + u0*16 + 16 + m] = zz; }
    }

    #pragma unroll
    for (int u = 0; u < 8; ++u) {
        float v = mxu[u];
        v = fmaxf(v, __shfl_xor(v, 16));
        v = fmaxf(v, __shfl_xor(v, 32));
        if (quad == 0) atomicMax(&cm[u * 16 + m], __float_as_uint(v));
    }
    __syncthreads();
    if (t < HID) atomicMax(&pmax[stage * HID + t], cm[t]);
}

// ---------------------------------------------------------------------------
// Fallback path kernels (R1-proven, 48 MB footprint)
// ---------------------------------------------------------------------------
__global__ __launch_bounds__(256) void k_edge_at(
    const __bf16* __restrict__ xA, const int* __restrict__ eidx,
    const float* __restrict__ ef, const float* __restrict__ We,
    const float* __restrict__ be, float* __restrict__ xNew)
{
    __shared__ __bf16 Wl[9 * 8 * 64 * 8];
    __shared__ float  bl[HID];
    const int t = threadIdx.x;
    for (int idx = t; idx < 8 * 64 * 8; idx += 256) Wl[8 * 8 * 64 * 8 + idx] = (__bf16)0.f;
    __syncthreads();
    stage_wfrag(Wl, We, 0, 4096, t);   // 256*128/8 chunks
    for (int idx = t; idx < 8 * HID; idx += 256) {
        int k2 = idx >> 7, h = idx & 127;
        Wl[((((8 * 8) + (h >> 4)) * 64 + (h & 15)) << 3) | k2] = f2bf(We[(256 + k2) * HID + h]);
    }
    for (int idx = t; idx < HID; idx += 256) bl[idx] = be[idx];
    __syncthreads();

    const int wave = t >> 6, lane = t & 63;
    const int m = lane & 15, quad = lane >> 4;
    for (int c = 0; c < 8; ++c) {
        const int e0 = blockIdx.x * 512 + c * 64 + wave * 16;
        const int e  = e0 + m;
        const int src = eidx[2 * e], dst = eidx[2 * e + 1];
        const __bf16* rs = xA + (size_t)src * HID;
        const __bf16* rd = xA + (size_t)dst * HID;
        bfrag a[9];
        #pragma unroll
        for (int kt = 0; kt < 4; ++kt) a[kt] = *(const bfrag*)(rs + kt * 32 + quad * 8);
        #pragma unroll
        for (int kt = 4; kt < 8; ++kt) a[kt] = *(const bfrag*)(rd + (kt - 4) * 32 + quad * 8);
        {
            bfrag z;
            #pragma unroll
            for (int q = 0; q < 8; ++q) z[q] = (__bf16)0.f;
            if (quad == 0) {
                const float4* p = (const float4*)(ef + (size_t)e * 8);
                float4 f0 = p[0], f1 = p[1];
                z[0]=f2bf(f0.x); z[1]=f2bf(f0.y); z[2]=f2bf(f0.z); z[3]=f2bf(f0.w);
                z[4]=f2bf(f1.x); z[5]=f2bf(f1.y); z[6]=f2bf(f1.z); z[7]=f2bf(f1.w);
            }
            a[8] = z;
        }
        ffrag acc[8];
        #pragma unroll
        for (int u = 0; u < 8; ++u)
            #pragma unroll
            for (int r = 0; r < 4; ++r) acc[u][r] = 0.f;
        #pragma unroll
        for (int kt = 0; kt < 9; ++kt)
            #pragma unroll
            for (int u = 0; u < 8; ++u) {
                bfrag b = *(const bfrag*)(&Wl[(((kt * 8 + u) * 64 + lane) << 3)]);
                acc[u] = __builtin_amdgcn_mfma_f32_16x16x32_bf16(a[kt], b, acc[u], 0, 0, 0);
            }
        #pragma unroll
        for (int r = 0; r < 4; ++r) {
            int er = e0 + quad * 4 + r;
            int sr = eidx[2 * er];
            float* outrow = xNew + (size_t)sr * HID;
            #pragma unroll
            for (int u = 0; u < 8; ++u) {
                int col = u * 16 + m;
                atomicAdd(outrow + col, fmaxf(acc[u][r] + bl[col], 0.f));
            }
        }
    }
}

__global__ __launch_bounds__(256) void k_fin(
    float* __restrict__ xNew, __bf16* __restrict__ xA,
    unsigned int* __restrict__ pmax, int stage, int flags)
{
    const int t = threadIdx.x;
    const size_t total  = (size_t)NCH * HID;
    const size_t stride = (size_t)gridDim.x * 256;
    float mx = 0.f;
    for (size_t i = (size_t)blockIdx.x * 256 + t; i < total; i += stride) {
        float v = xNew[i];
        mx = fmaxf(mx, v);
        if (flags & 1) xA[i] = f2bf(v);
        if (flags & 2) xNew[i] = 0.f;
    }
    __shared__ float red[256];
    red[t] = mx;
    __syncthreads();
    if (t < 128) {
        float v = fmaxf(red[t], red[t + 128]);
        atomicMax(&pmax[stage * HID + t], __float_as_uint(v));
    }
}

// ---------------------------------------------------------------------------
// Parent head: out = relu(pmax(384) @ Wp + bp)
// ---------------------------------------------------------------------------
__global__ __launch_bounds__(128) void k_parent(
    const unsigned int* __restrict__ pmaxU,
    const float* __restrict__ Wp, const float* __restrict__ bp,
    float* __restrict__ out)
{
    __shared__ float pl[384];
    const int t = threadIdx.x;
    for (int i = t; i < 384; i += 128) pl[i] = __uint_as_float(pmaxU[i]);
    __syncthreads();
    float acc = bp[t];
    for (int j = 0; j < 384; ++j) acc += pl[j] * Wp[j * HID + t];
    out[t] = fmaxf(acc, 0.f);
}

extern "C" void kernel_launch(void* const* d_in, const int* in_sizes, int n_in,
                              void* d_out, int out_size, void* d_ws, size_t ws_size,
                              hipStream_t stream)
{
    const float* cf   = (const float*)d_in[0];
    const float* ex   = (const float*)d_in[1];
    const float* ef   = (const float*)d_in[2];
    const int*   eidx = (const int*)d_in[3];
    const float* Wc   = (const float*)d_in[4];
    const float* bc   = (const float*)d_in[5];
    const float* We   = (const float*)d_in[6];
    const float* be   = (const float*)d_in[7];
    const float* Wp   = (const float*)d_in[8];
    const float* bp   = (const float*)d_in[9];
    float* out = (float*)d_out;

    char* ws = (char*)d_ws;

    // CSR-fused path layout (~69 MB).  deg and pmax ADJACENT -> one memset.
    const size_t OFF_XA   = 0;
    const size_t OFF_XB   = OFF_XA   + (size_t)NCH * HID * 2;   // +16 MB
    const size_t OFF_ST   = OFF_XB   + (size_t)NCH * HID * 2;   // +16 MB
    const size_t OFF_EFS  = OFF_ST   + (size_t)NCH * HID * 2;   // +16 MB
    const size_t OFF_DQ   = OFF_EFS  + (size_t)NE * 8;          // +8 MB (fp8 ef)
    const size_t OFF_DST  = OFF_DQ   + (size_t)NCH * 128;       // +8 MB (fp8 D)
    const size_t OFF_OFFS = OFF_DST  + (size_t)NE * 4;          // +4 MB
    const size_t OFF_DEG  = OFF_OFFS + 262400;
    const size_t OFF_PMAX = OFF_DEG  + 262144;                  // adjacent to deg
    const size_t OFF_CUR  = OFF_PMAX + 2048;
    const size_t OFF_BS   = OFF_CUR  + 262144;   // bsum[256]
    const size_t NEED     = OFF_BS   + 1024;

    if (ws_size >= NEED) {
        __bf16*        xA   = (__bf16*)(ws + OFF_XA);
        __bf16*        xB   = (__bf16*)(ws + OFF_XB);
        __bf16*        St2  = (__bf16*)(ws + OFF_ST);
        unsigned char* efs8 = (unsigned char*)(ws + OFF_EFS);
        unsigned char* Dq   = (unsigned char*)(ws + OFF_DQ);
        int*           dsts = (int*)   (ws + OFF_DST);
        int*           offs = (int*)   (ws + OFF_OFFS);
        int*           deg  = (int*)   (ws + OFF_DEG);
        int*           cur  = (int*)   (ws + OFF_CUR);
        unsigned int*  pmax = (unsigned int*)(ws + OFF_PMAX);
        int*           bsum = (int*)   (ws + OFF_BS);

        // one memset covers deg (256 KB) + pmax (adjacent)
        hipMemsetAsync(deg, 0, 262144 + 2048, stream);

        k_childhist<<<2048, 256, 0, stream>>>(cf, ex, Wc, bc, xA, pmax, eidx, deg);
        k_scan1  <<<256,  256, 0, stream>>>(deg, bsum);
        k_scan23 <<<256,  256, 0, stream>>>(deg, bsum, offs, cur);

        // merged: src(stage1) blocks 0..1023  ||  scatter blocks 1024..5119
        k_scsrc  <<<5120, 256, 0, stream>>>(xA, We, be, St2, Dq,
                                            eidx, cur, ef, dsts, efs8);
        k_edge2  <<<4096, 256, 0, stream>>>(Dq, offs, dsts, efs8, St2, We, xB, pmax, 1);
        k_scsrc  <<<1024, 256, 0, stream>>>(xB, We + 264 * HID, be + HID, St2, Dq,
                                            eidx, cur, ef, dsts, efs8);   // src only
        k_edge2  <<<4096, 256, 0, stream>>>(Dq, offs, dsts, efs8, St2, We + 264 * HID, xA, pmax, 2);
        k_parent <<<1,    128, 0, stream>>>(pmax, Wp, bp, out);
    } else {
        // fallback: R1 atomic path (48 MB)
        float*        xNew = (float*)ws;
        __bf16*       xA   = (__bf16*)(ws + (size_t)NCH * HID * 4);
        unsigned int* pmax = (unsigned int*)(ws + (size_t)NCH * HID * 6);

        hipMemsetAsync(pmax, 0, 384 * sizeof(unsigned int), stream);
        hipMemsetAsync(xNew, 0, (size_t)NCH * HID * 4, stream);

        k_childhist<<<1024, 256, 0, stream>>>(cf, ex, Wc, bc, xA, pmax, eidx, (int*)nullptr);
        k_edge_at<<<2048, 256, 0, stream>>>(xA, eidx, ef, We,             be,       xNew);
        k_fin    <<<512,  256, 0, stream>>>(xNew, xA, pmax, 1, 3);
        k_edge_at<<<2048, 256, 0, stream>>>(xA, eidx, ef, We + 264 * HID, be + HID, xNew);
        k_fin    <<<512,  256, 0, stream>>>(xNew, xA, pmax, 2, 0);
        k_parent <<<1,    128, 0, stream>>>(pmax, Wp, bp, out);
    }
}